// Round 1
// baseline (1090.810 us; speedup 1.0000x reference)
//
#include <hip/hip_runtime.h>
#include <math.h>

#define HWSZ 16384

__device__ __forceinline__ float gelu_f(float v) {
    return 0.5f * v * (1.0f + erff(v * 0.70710678118654752f));
}
__device__ __forceinline__ float splus_f(float v) {
    return (v > 20.f) ? v : log1pf(expf(v));
}

__device__ __forceinline__ float dot16_lds(const float* q, const float* kt, int j) {
    float4 k0 = *(const float4*)&kt[j*16];
    float4 k1 = *(const float4*)&kt[j*16+4];
    float4 k2 = *(const float4*)&kt[j*16+8];
    float4 k3 = *(const float4*)&kt[j*16+12];
    return q[0]*k0.x + q[1]*k0.y + q[2]*k0.z + q[3]*k0.w
         + q[4]*k1.x + q[5]*k1.y + q[6]*k1.z + q[7]*k1.w
         + q[8]*k2.x + q[9]*k2.y + q[10]*k2.z + q[11]*k2.w
         + q[12]*k3.x + q[13]*k3.y + q[14]*k3.z + q[15]*k3.w;
}

__device__ __forceinline__ void acc16(float* acc, float e, const float* vt, int j) {
    float4 v0 = *(const float4*)&vt[j*16];
    float4 v1 = *(const float4*)&vt[j*16+4];
    float4 v2 = *(const float4*)&vt[j*16+8];
    float4 v3 = *(const float4*)&vt[j*16+12];
    acc[0]  += e*v0.x; acc[1]  += e*v0.y; acc[2]  += e*v0.z; acc[3]  += e*v0.w;
    acc[4]  += e*v1.x; acc[5]  += e*v1.y; acc[6]  += e*v1.z; acc[7]  += e*v1.w;
    acc[8]  += e*v2.x; acc[9]  += e*v2.y; acc[10] += e*v2.z; acc[11] += e*v2.w;
    acc[12] += e*v3.x; acc[13] += e*v3.y; acc[14] += e*v3.z; acc[15] += e*v3.w;
}

// ---------------- Kernel 1: fusion gate ----------------
__global__ __launch_bounds__(256) void k_fuse(
    const float* __restrict__ y, const float* __restrict__ th,
    const float* __restrict__ w1, const float* __restrict__ b1,
    const float* __restrict__ w2, const float* __restrict__ b2,
    float* __restrict__ fused)
{
    __shared__ float w1t[8192];          // [c][o], c in 0..127, o in 0..63
    int tid = threadIdx.x;
    for (int i = tid; i < 8192; i += 256) {
        int o = i >> 7, c = i & 127;
        w1t[c*64 + o] = w1[i];
    }
    __syncthreads();
    int g = blockIdx.x*256 + tid;
    int b = g >> 14;
    int p = g & 16383;
    const float* yb = y  + (size_t)b*64*HWSZ + p;
    const float* tb = th + (size_t)b*64*HWSZ + p;
    float acc[64];
    #pragma unroll
    for (int o = 0; o < 64; ++o) acc[o] = b1[o];
    for (int c = 0; c < 64; ++c) {
        float f = yb[(size_t)c*HWSZ];
        #pragma unroll
        for (int o4 = 0; o4 < 16; ++o4) {
            float4 wv = *(const float4*)&w1t[c*64 + o4*4];
            acc[o4*4+0] += wv.x*f; acc[o4*4+1] += wv.y*f;
            acc[o4*4+2] += wv.z*f; acc[o4*4+3] += wv.w*f;
        }
    }
    for (int c = 0; c < 64; ++c) {
        float f = tb[(size_t)c*HWSZ];
        #pragma unroll
        for (int o4 = 0; o4 < 16; ++o4) {
            float4 wv = *(const float4*)&w1t[(64+c)*64 + o4*4];
            acc[o4*4+0] += wv.x*f; acc[o4*4+1] += wv.y*f;
            acc[o4*4+2] += wv.z*f; acc[o4*4+3] += wv.w*f;
        }
    }
    float l0 = b2[0], l1 = b2[1];
    #pragma unroll
    for (int o = 0; o < 64; ++o) {
        float hh = fmaxf(acc[o], 0.f);
        l0 += w2[o]*hh;
        l1 += w2[64+o]*hh;
    }
    float m = fmaxf(l0, l1);
    float e0 = expf(l0 - m), e1 = expf(l1 - m);
    float inv = 1.f/(e0 + e1);
    float wa = e0*inv, wb = e1*inv;
    float* fb = fused + (size_t)b*64*HWSZ + p;
    for (int c = 0; c < 64; ++c)
        fb[(size_t)c*HWSZ] = yb[(size_t)c*HWSZ]*wa + tb[(size_t)c*HWSZ]*wb;
}

// ---------------- Kernel 2: QKV + RoPE + dt ----------------
// grid 1024, block 256: 64 positions/block, thread = (lane=pos, n=head)
__global__ __launch_bounds__(256) void k_qkv(
    const float* __restrict__ x, const float* __restrict__ fused,
    const float* __restrict__ qw, const float* __restrict__ qb,
    const float* __restrict__ kw, const float* __restrict__ kb,
    const float* __restrict__ vw, const float* __restrict__ vb,
    const float* __restrict__ dtw, const float* __restrict__ dtb,
    const float* __restrict__ alog,
    float* __restrict__ qr, float* __restrict__ kr, float* __restrict__ v5,
    float* __restrict__ da, float* __restrict__ db)
{
    __shared__ float sw[12288];          // qw | kw | vw, each [c][o]
    __shared__ float sx[4096];           // [c][pos], 64x64
    int tid = threadIdx.x;
    for (int i = tid*4; i < 4096; i += 1024) {
        *(float4*)&sw[i]      = *(const float4*)&qw[i];
        *(float4*)&sw[4096+i] = *(const float4*)&kw[i];
        *(float4*)&sw[8192+i] = *(const float4*)&vw[i];
    }
    int b  = blockIdx.x >> 8;
    int p0 = (blockIdx.x & 255)*64;
    for (int vi = tid; vi < 1024; vi += 256) {
        int c = vi >> 4, p4 = (vi & 15)*4;
        *(float4*)&sx[c*64 + p4] = *(const float4*)&x[((size_t)(b*64+c))*HWSZ + p0 + p4];
    }
    __syncthreads();
    int lane = tid & 63;
    int n = tid >> 6;
    int p = p0 + lane;
    int h = p >> 7, w = p & 127;
    float sn[8], cn[8];
    #pragma unroll
    for (int t = 0; t < 8; ++t) {
        float ang = exp2f(-1.89824462565f * (float)t);   // 10000^(-t/7)
        sincosf((float)p * ang, &sn[t], &cn[t]);
    }
    float a[16];
    // ---- Q head n ----
    #pragma unroll
    for (int d = 0; d < 16; ++d) a[d] = qb[n*16+d];
    for (int c = 0; c < 64; ++c) {
        float xc = sx[c*64 + lane];
        #pragma unroll
        for (int d4 = 0; d4 < 4; ++d4) {
            float4 wv = *(const float4*)&sw[c*64 + n*16 + d4*4];
            a[d4*4+0] += wv.x*xc; a[d4*4+1] += wv.y*xc;
            a[d4*4+2] += wv.z*xc; a[d4*4+3] += wv.w*xc;
        }
    }
    {
        float r[16];
        #pragma unroll
        for (int t = 0; t < 8; ++t) {
            r[2*t]   = a[2*t]*cn[t]   - a[2*t+1]*sn[t];
            r[2*t+1] = a[2*t+1]*cn[t] + a[2*t]*sn[t];
        }
        float* dst = qr + (((size_t)(b*4+n))*HWSZ + p)*16;
        #pragma unroll
        for (int d4 = 0; d4 < 4; ++d4)
            *(float4*)&dst[d4*4] = make_float4(r[d4*4],r[d4*4+1],r[d4*4+2],r[d4*4+3]);
    }
    // ---- dt / da / db ----
    {
        float dt0 = 0.f, dt1 = 0.f;
        #pragma unroll
        for (int d = 0; d < 16; ++d) {
            float xv = sx[(n*16+d)*64 + lane];
            dt0 += xv*dtw[2*d];
            dt1 += xv*dtw[2*d+1];
        }
        float A  = -expf(alog[n]);
        float bb = dtb[n];
        da[((b*128+h)*4+n)*128 + w] = splus_f(dt0+bb)*A;
        db[((b*128+w)*4+n)*128 + h] = splus_f(dt1+bb)*A;
    }
    __syncthreads();
    for (int vi = tid; vi < 1024; vi += 256) {
        int c = vi >> 4, p4 = (vi & 15)*4;
        *(float4*)&sx[c*64 + p4] = *(const float4*)&fused[((size_t)(b*64+c))*HWSZ + p0 + p4];
    }
    __syncthreads();
    // ---- K head n (scaled 0.25, RoPE) ----
    #pragma unroll
    for (int d = 0; d < 16; ++d) a[d] = kb[n*16+d];
    for (int c = 0; c < 64; ++c) {
        float xc = sx[c*64 + lane];
        #pragma unroll
        for (int d4 = 0; d4 < 4; ++d4) {
            float4 wv = *(const float4*)&sw[4096 + c*64 + n*16 + d4*4];
            a[d4*4+0] += wv.x*xc; a[d4*4+1] += wv.y*xc;
            a[d4*4+2] += wv.z*xc; a[d4*4+3] += wv.w*xc;
        }
    }
    {
        float r[16];
        #pragma unroll
        for (int t = 0; t < 8; ++t) {
            float e = a[2*t]*0.25f, o = a[2*t+1]*0.25f;
            r[2*t]   = e*cn[t] - o*sn[t];
            r[2*t+1] = o*cn[t] + e*sn[t];
        }
        float* dst = kr + (((size_t)(b*4+n))*HWSZ + p)*16;
        #pragma unroll
        for (int d4 = 0; d4 < 4; ++d4)
            *(float4*)&dst[d4*4] = make_float4(r[d4*4],r[d4*4+1],r[d4*4+2],r[d4*4+3]);
    }
    // ---- V head n ----
    #pragma unroll
    for (int d = 0; d < 16; ++d) a[d] = vb[n*16+d];
    for (int c = 0; c < 64; ++c) {
        float xc = sx[c*64 + lane];
        #pragma unroll
        for (int d4 = 0; d4 < 4; ++d4) {
            float4 wv = *(const float4*)&sw[8192 + c*64 + n*16 + d4*4];
            a[d4*4+0] += wv.x*xc; a[d4*4+1] += wv.y*xc;
            a[d4*4+2] += wv.z*xc; a[d4*4+3] += wv.w*xc;
        }
    }
    {
        float* dst = v5 + (((size_t)(b*4+n))*HWSZ + p)*16;
        #pragma unroll
        for (int d4 = 0; d4 < 4; ++d4)
            *(float4*)&dst[d4*4] = make_float4(a[d4*4],a[d4*4+1],a[d4*4+2],a[d4*4+3]);
    }
}

// ---------------- Kernel 2b: cumsums (wave-scan, rows of 128) ----------------
__global__ __launch_bounds__(256) void k_cumsum(float* __restrict__ da, float* __restrict__ db)
{
    int gw = (blockIdx.x*256 + threadIdx.x) >> 6;   // 0..4095
    int lane = threadIdx.x & 63;
    float* base = (gw < 2048) ? (da + (size_t)gw*128) : (db + (size_t)(gw-2048)*128);
    float2 e = *(float2*)&base[lane*2];
    float s = e.x + e.y;
    #pragma unroll
    for (int d = 1; d < 64; d <<= 1) {
        float t = __shfl_up(s, d, 64);
        if (lane >= d) s += t;
    }
    float excl = s - (e.x + e.y);
    float2 o;
    o.x = excl + e.x;
    o.y = excl + e.x + e.y;
    *(float2*)&base[lane*2] = o;
}

// ---------------- Kernel 3: LePE depthwise 5x5 conv ----------------
__global__ __launch_bounds__(256) void k_lepe(
    const float* __restrict__ v5, const float* __restrict__ lw,
    const float* __restrict__ lb, float* __restrict__ lepe)
{
    int g = blockIdx.x*256 + threadIdx.x;
    int c = g & 63;
    int p = g >> 6;
    int w = p & 127, h = (p >> 7) & 127, b = p >> 14;
    int n = c >> 4, d = c & 15;
    const float* vpl = v5 + ((size_t)(b*4+n))*HWSZ*16 + d;
    float acc = lb[c];
    #pragma unroll
    for (int ky = 0; ky < 5; ++ky) {
        int hy = h + ky - 2;
        if (hy < 0 || hy > 127) continue;
        #pragma unroll
        for (int kx = 0; kx < 5; ++kx) {
            int wx = w + kx - 2;
            if (wx < 0 || wx > 127) continue;
            acc += vpl[((size_t)(hy*128 + wx))*16] * lw[(ky*5+kx)*64 + c];
        }
    }
    lepe[g] = acc;
}

// ---------------- Kernel 4: row attention pass 1 -> v_w ----------------
// grid (b,n,h) = 2048; lane pair splits j-range; streaming exp (no max needed: scores tiny, mask<=0)
__global__ __launch_bounds__(256) void k_attn_w1(
    const float* __restrict__ qr, const float* __restrict__ kr,
    const float* __restrict__ v5, const float* __restrict__ dacs,
    float* __restrict__ vwb)
{
    __shared__ float qt[2048], kt[2048], vt[2048], csr[128];
    int tid = threadIdx.x, bid = blockIdx.x;
    int h = bid & 127, n = (bid >> 7) & 3, b = bid >> 9;
    size_t rowoff = ((size_t)((b*4+n)*128 + h)) * 2048;
    for (int i = tid*4; i < 2048; i += 1024) {
        *(float4*)&qt[i] = *(const float4*)&qr[rowoff + i];
        *(float4*)&kt[i] = *(const float4*)&kr[rowoff + i];
        *(float4*)&vt[i] = *(const float4*)&v5[rowoff + i];
    }
    if (tid < 128) csr[tid] = dacs[((b*128+h)*4+n)*128 + tid];
    __syncthreads();
    int i = tid >> 1, dh = tid & 1, jb = dh*64;
    float q[16];
    #pragma unroll
    for (int d4 = 0; d4 < 4; ++d4) {
        float4 t = *(const float4*)&qt[i*16 + d4*4];
        q[d4*4+0]=t.x; q[d4*4+1]=t.y; q[d4*4+2]=t.z; q[d4*4+3]=t.w;
    }
    float ci = csr[i];
    float l = 0.f;
    float acc[16];
    #pragma unroll
    for (int d = 0; d < 16; ++d) acc[d] = 0.f;
    for (int jj = 0; jj < 64; ++jj) {
        int j = jb + jj;
        float s = dot16_lds(q, kt, j) - fabsf(ci - csr[j]);
        float e = expf(s);
        l += e;
        acc16(acc, e, vt, j);
    }
    l += __shfl_xor(l, 1, 64);
    #pragma unroll
    for (int d = 0; d < 16; ++d) acc[d] += __shfl_xor(acc[d], 1, 64);
    float inv = 1.f/l;
    float o[8];
    #pragma unroll
    for (int u = 0; u < 8; ++u) o[u] = (dh ? acc[8+u] : acc[u])*inv;
    float* dst = vwb + rowoff + (size_t)i*16 + dh*8;
    *(float4*)&dst[0] = make_float4(o[0],o[1],o[2],o[3]);
    *(float4*)&dst[4] = make_float4(o[4],o[5],o[6],o[7]);
}

// ---------------- Kernel 5: column attention -> v_h and out1 ----------------
__global__ __launch_bounds__(256) void k_attn_h(
    const float* __restrict__ qr, const float* __restrict__ kr,
    const float* __restrict__ v5, const float* __restrict__ vwb,
    const float* __restrict__ dbcs,
    float* __restrict__ vhb, float* __restrict__ o1b)
{
    __shared__ float qt[2048], kt[2048], vt[2048], wt[2048], csr[128];
    int tid = threadIdx.x, bid = blockIdx.x;
    int w = bid & 127, n = (bid >> 7) & 3, b = bid >> 9;
    size_t base = ((size_t)(b*4+n)*16384 + w)*16;
    for (int vi = tid; vi < 512; vi += 256) {
        int hh = vi >> 2, dd = (vi & 3)*4;
        size_t src = base + (size_t)hh*2048 + dd;
        int di = hh*16 + dd;
        *(float4*)&qt[di] = *(const float4*)&qr[src];
        *(float4*)&kt[di] = *(const float4*)&kr[src];
        *(float4*)&vt[di] = *(const float4*)&v5[src];
        *(float4*)&wt[di] = *(const float4*)&vwb[src];
    }
    if (tid < 128) csr[tid] = dbcs[((b*128+w)*4+n)*128 + tid];
    __syncthreads();
    int i = tid >> 1, dh = tid & 1, jb = dh*64;   // i = h(out row), j = g
    float q[16];
    #pragma unroll
    for (int d4 = 0; d4 < 4; ++d4) {
        float4 t = *(const float4*)&qt[i*16 + d4*4];
        q[d4*4+0]=t.x; q[d4*4+1]=t.y; q[d4*4+2]=t.z; q[d4*4+3]=t.w;
    }
    float ci = csr[i];
    float l = 0.f;
    float a1[16], a2[16];
    #pragma unroll
    for (int d = 0; d < 16; ++d) { a1[d] = 0.f; a2[d] = 0.f; }
    for (int jj = 0; jj < 64; ++jj) {
        int j = jb + jj;
        float s = dot16_lds(q, kt, j) - fabsf(ci - csr[j]);
        float e = expf(s);
        l += e;
        acc16(a1, e, wt, j);   // out1 = P @ v_w
        acc16(a2, e, vt, j);   // v_h  = P @ v
    }
    l += __shfl_xor(l, 1, 64);
    #pragma unroll
    for (int d = 0; d < 16; ++d) {
        a1[d] += __shfl_xor(a1[d], 1, 64);
        a2[d] += __shfl_xor(a2[d], 1, 64);
    }
    float inv = 1.f/l;
    size_t dsto = (((size_t)(b*4+n)*128 + i)*128 + w)*16 + dh*8;
    float o[8];
    #pragma unroll
    for (int u = 0; u < 8; ++u) o[u] = (dh ? a1[8+u] : a1[u])*inv;
    *(float4*)&o1b[dsto]   = make_float4(o[0],o[1],o[2],o[3]);
    *(float4*)&o1b[dsto+4] = make_float4(o[4],o[5],o[6],o[7]);
    #pragma unroll
    for (int u = 0; u < 8; ++u) o[u] = (dh ? a2[8+u] : a2[u])*inv;
    *(float4*)&vhb[dsto]   = make_float4(o[0],o[1],o[2],o[3]);
    *(float4*)&vhb[dsto+4] = make_float4(o[4],o[5],o[6],o[7]);
}

// ---------------- Kernel 6: row attention pass 2 -> out2, combine + lepe ----------------
__global__ __launch_bounds__(256) void k_attn_w2(
    const float* __restrict__ qr, const float* __restrict__ kr,
    const float* __restrict__ vhb, const float* __restrict__ o1b,
    const float* __restrict__ dacs, const float* __restrict__ lepe,
    float* __restrict__ attn)
{
    __shared__ float qt[2048], kt[2048], vt[2048], ot[2048], csr[128];
    int tid = threadIdx.x, bid = blockIdx.x;
    int h = bid & 127, n = (bid >> 7) & 3, b = bid >> 9;
    size_t rowoff = ((size_t)((b*4+n)*128 + h)) * 2048;
    for (int i = tid*4; i < 2048; i += 1024) {
        *(float4*)&qt[i] = *(const float4*)&qr[rowoff + i];
        *(float4*)&kt[i] = *(const float4*)&kr[rowoff + i];
        *(float4*)&vt[i] = *(const float4*)&vhb[rowoff + i];
        *(float4*)&ot[i] = *(const float4*)&o1b[rowoff + i];
    }
    if (tid < 128) csr[tid] = dacs[((b*128+h)*4+n)*128 + tid];
    __syncthreads();
    int i = tid >> 1, dh = tid & 1, jb = dh*64;
    float q[16];
    #pragma unroll
    for (int d4 = 0; d4 < 4; ++d4) {
        float4 t = *(const float4*)&qt[i*16 + d4*4];
        q[d4*4+0]=t.x; q[d4*4+1]=t.y; q[d4*4+2]=t.z; q[d4*4+3]=t.w;
    }
    float ci = csr[i];
    float l = 0.f;
    float acc[16];
    #pragma unroll
    for (int d = 0; d < 16; ++d) acc[d] = 0.f;
    for (int jj = 0; jj < 64; ++jj) {
        int j = jb + jj;
        float s = dot16_lds(q, kt, j) - fabsf(ci - csr[j]);
        float e = expf(s);
        l += e;
        acc16(acc, e, vt, j);
    }
    l += __shfl_xor(l, 1, 64);
    #pragma unroll
    for (int d = 0; d < 16; ++d) acc[d] += __shfl_xor(acc[d], 1, 64);
    float inv = 1.f/l;
    int p = h*128 + i;
    size_t obase = ((size_t)(b*16384 + p))*64 + n*16 + dh*8;
    float4 lp0 = *(const float4*)&lepe[obase];
    float4 lp1 = *(const float4*)&lepe[obase+4];
    float lpv[8] = {lp0.x,lp0.y,lp0.z,lp0.w,lp1.x,lp1.y,lp1.z,lp1.w};
    float o[8];
    #pragma unroll
    for (int u = 0; u < 8; ++u) {
        float o2 = (dh ? acc[8+u] : acc[u])*inv;
        o[u] = 0.5f*(ot[i*16 + dh*8 + u] + o2) + lpv[u];
    }
    *(float4*)&attn[obase]   = make_float4(o[0],o[1],o[2],o[3]);
    *(float4*)&attn[obase+4] = make_float4(o[4],o[5],o[6],o[7]);
}

// ---------------- Kernel 7: out-proj + residual + LN1 ----------------
__global__ __launch_bounds__(256) void k_proj_ln(
    const float* __restrict__ attn, const float* __restrict__ x,
    const float* __restrict__ ow, const float* __restrict__ ob,
    const float* __restrict__ g1, const float* __restrict__ b1,
    float* __restrict__ t1)
{
    __shared__ float sw[4096];
    int tid = threadIdx.x;
    for (int i = tid*4; i < 4096; i += 1024)
        *(float4*)&sw[i] = *(const float4*)&ow[i];
    __syncthreads();
    int lane = tid & 63, wv = tid >> 6;
    int Pb = blockIdx.x*64 + wv*16;
    float gg = g1[lane], bb = b1[lane], obv = ob[lane];
    for (int it = 0; it < 16; ++it) {
        int P = Pb + it;
        int b = P >> 14, p = P & 16383;
        float a = attn[(size_t)P*64 + lane];
        float o = obv;
        #pragma unroll
        for (int k = 0; k < 64; ++k)
            o += sw[k*64 + lane]*__shfl(a, k, 64);
        float r = x[((size_t)(b*64 + lane))*HWSZ + p] + o;
        float s = r;
        #pragma unroll
        for (int d = 1; d < 64; d <<= 1) s += __shfl_xor(s, d, 64);
        float mean = s*(1.f/64.f);
        float df = r - mean;
        float vv = df*df;
        #pragma unroll
        for (int d = 1; d < 64; d <<= 1) vv += __shfl_xor(vv, d, 64);
        float res = df*rsqrtf(vv*(1.f/64.f) + 1e-5f)*gg + bb;
        t1[(size_t)P*64 + lane] = res;
    }
}

// ---------------- Kernel 8a: FFN up (gelu) ----------------
// grid 4096: bid = (posgroup<<1)|jhalf; block computes 32 pos x 128 hid
__global__ __launch_bounds__(256) void k_ffn1(
    const float* __restrict__ t1, const float* __restrict__ w1,
    const float* __restrict__ b1, float* __restrict__ hid)
{
    __shared__ float swl[8192];      // [k][j] 64x128
    __shared__ float st[2304];       // t1T [k][pos] stride 36
    int tid = threadIdx.x;
    int jh = blockIdx.x & 1;
    int pbase = (blockIdx.x >> 1)*32;
    for (int vi = tid; vi < 2048; vi += 256) {
        int k = vi >> 5, j4 = (vi & 31)*4;
        *(float4*)&swl[k*128 + j4] = *(const float4*)&w1[k*256 + jh*128 + j4];
    }
    for (int vi = tid; vi < 512; vi += 256) {
        int pi = vi >> 4, c4 = (vi & 15)*4;
        float4 tv = *(const float4*)&t1[((size_t)(pbase+pi))*64 + c4];
        st[(c4+0)*36 + pi] = tv.x;
        st[(c4+1)*36 + pi] = tv.y;
        st[(c4+2)*36 + pi] = tv.z;
        st[(c4+3)*36 + pi] = tv.w;
    }
    __syncthreads();
    int tj = tid & 31, tp = tid >> 5;
    float acc[4][4];
    #pragma unroll
    for (int pp = 0; pp < 4; ++pp)
        #pragma unroll
        for (int u = 0; u < 4; ++u) acc[pp][u] = 0.f;
    for (int k = 0; k < 64; ++k) {
        float4 tv = *(const float4*)&st[k*36 + tp*4];
        float4 wv = *(const float4*)&swl[k*128 + tj*4];
        float tvv[4] = {tv.x,tv.y,tv.z,tv.w};
        float wvv[4] = {wv.x,wv.y,wv.z,wv.w};
        #pragma unroll
        for (int pp = 0; pp < 4; ++pp)
            #pragma unroll
            for (int u = 0; u < 4; ++u)
                acc[pp][u] += tvv[pp]*wvv[u];
    }
    float bb[4];
    #pragma unroll
    for (int u = 0; u < 4; ++u) bb[u] = b1[jh*128 + tj*4 + u];
    #pragma unroll
    for (int pp = 0; pp < 4; ++pp) {
        float4 o;
        o.x = gelu_f(acc[pp][0] + bb[0]);
        o.y = gelu_f(acc[pp][1] + bb[1]);
        o.z = gelu_f(acc[pp][2] + bb[2]);
        o.w = gelu_f(acc[pp][3] + bb[3]);
        *(float4*)&hid[((size_t)(pbase + tp*4 + pp))*256 + jh*128 + tj*4] = o;
    }
}

// ---------------- Kernel 8b: FFN down + residual + LN2 + transpose ----------------
// grid 2048: 32 positions/block; wave-per-position, W2 staged in 2 halves
__global__ __launch_bounds__(256) void k_ffn2(
    const float* __restrict__ hid, const float* __restrict__ t1,
    const float* __restrict__ w2, const float* __restrict__ b2,
    const float* __restrict__ g2, const float* __restrict__ bb2,
    float* __restrict__ outp)
{
    __shared__ float swl[8192];      // [j][c] 128x64 (half of W2)
    __shared__ float tile[2304];     // [c][pos] stride 36
    int tid = threadIdx.x;
    int lane = tid & 63, wv = tid >> 6;
    int pbase = blockIdx.x*32;
    int b = pbase >> 14, p0 = pbase & 16383;
    for (int i = tid; i < 2304; i += 256) tile[i] = 0.f;
    for (int ph = 0; ph < 2; ++ph) {
        __syncthreads();
        for (int i = tid*4; i < 8192; i += 1024)
            *(float4*)&swl[i] = *(const float4*)&w2[ph*8192 + i];
        __syncthreads();
        for (int it = 0; it < 8; ++it) {
            int pos = wv*8 + it;
            int P = pbase + pos;
            float h0 = hid[(size_t)P*256 + ph*128 + lane];
            float h1 = hid[(size_t)P*256 + ph*128 + 64 + lane];
            float o = 0.f;
            #pragma unroll
            for (int jl = 0; jl < 64; ++jl)
                o += swl[jl*64 + lane]*__shfl(h0, jl, 64);
            #pragma unroll
            for (int jl = 0; jl < 64; ++jl)
                o += swl[(64+jl)*64 + lane]*__shfl(h1, jl, 64);
            tile[lane*36 + pos] += o;
        }
    }
    __syncthreads();
    {
        float gg = g2[lane], bbv = bb2[lane], bias2 = b2[lane];
        for (int it = 0; it < 8; ++it) {
            int pos = wv*8 + it;
            int P = pbase + pos;
            float r = t1[(size_t)P*64 + lane] + tile[lane*36 + pos] + bias2;
            float s = r;
            #pragma unroll
            for (int d = 1; d < 64; d <<= 1) s += __shfl_xor(s, d, 64);
            float mean = s*(1.f/64.f);
            float df = r - mean;
            float vv = df*df;
            #pragma unroll
            for (int d = 1; d < 64; d <<= 1) vv += __shfl_xor(vv, d, 64);
            float res = df*rsqrtf(vv*(1.f/64.f) + 1e-5f)*gg + bbv;
            tile[lane*36 + pos] = res;
        }
    }
    __syncthreads();
    for (int vi = tid; vi < 512; vi += 256) {
        int c = vi >> 3, p4 = (vi & 7)*4;
        float4 ov = *(const float4*)&tile[c*36 + p4];
        *(float4*)&outp[((size_t)(b*64 + c))*HWSZ + p0 + p4] = ov;
    }
}

extern "C" void kernel_launch(void* const* d_in, const int* in_sizes, int n_in,
                              void* d_out, int out_size, void* d_ws, size_t ws_size,
                              hipStream_t stream) {
    const float* x      = (const float*)d_in[0];
    const float* y      = (const float*)d_in[1];
    const float* th     = (const float*)d_in[2];
    const float* dw1_w  = (const float*)d_in[3];
    const float* dw1_b  = (const float*)d_in[4];
    const float* dw2_w  = (const float*)d_in[5];
    const float* dw2_b  = (const float*)d_in[6];
    const float* qw     = (const float*)d_in[7];
    const float* qb     = (const float*)d_in[8];
    const float* kw     = (const float*)d_in[9];
    const float* kb     = (const float*)d_in[10];
    const float* vw     = (const float*)d_in[11];
    const float* vb     = (const float*)d_in[12];
    const float* lepe_w = (const float*)d_in[13];
    const float* lepe_b = (const float*)d_in[14];
    const float* dt_w   = (const float*)d_in[15];
    const float* dt_bias= (const float*)d_in[16];
    const float* A_log  = (const float*)d_in[17];
    const float* ow     = (const float*)d_in[18];
    const float* ob     = (const float*)d_in[19];
    const float* n1_g   = (const float*)d_in[20];
    const float* n1_b   = (const float*)d_in[21];
    const float* ffn_w1 = (const float*)d_in[22];
    const float* ffn_b1 = (const float*)d_in[23];
    const float* ffn_w2 = (const float*)d_in[24];
    const float* ffn_b2 = (const float*)d_in[25];
    const float* n2_g   = (const float*)d_in[26];
    const float* n2_b   = (const float*)d_in[27];
    float* out = (float*)d_out;

    const size_t SZ = 4194304;   // B*C*H*W elements
    float* ws    = (float*)d_ws;
    float* fused = ws + 0*SZ;    // reused as v_w after kernel 4
    float* qrb   = ws + 1*SZ;
    float* krb   = ws + 2*SZ;
    float* v5b   = ws + 3*SZ;
    float* lepeb = ws + 4*SZ;
    float* vhb   = ws + 5*SZ;
    float* o1b   = ws + 6*SZ;
    float* attnb = ws + 7*SZ;
    float* t1b   = ws + 8*SZ;
    float* dacs  = ws + 9*SZ;               // 262144
    float* dbcs  = ws + 9*SZ + 262144;      // 262144
    float* hidb  = ws + 1*SZ;               // reuse qr..lepe region (4*SZ)

    k_fuse<<<256, 256, 0, stream>>>(y, th, dw1_w, dw1_b, dw2_w, dw2_b, fused);
    k_qkv<<<1024, 256, 0, stream>>>(x, fused, qw, qb, kw, kb, vw, vb,
                                    dt_w, dt_bias, A_log, qrb, krb, v5b, dacs, dbcs);
    k_cumsum<<<1024, 256, 0, stream>>>(dacs, dbcs);
    k_lepe<<<65536, 256, 0, stream>>>(v5b, lepe_w, lepe_b, lepeb);
    k_attn_w1<<<2048, 256, 0, stream>>>(qrb, krb, v5b, dacs, fused);
    k_attn_h<<<2048, 256, 0, stream>>>(qrb, krb, v5b, fused, dbcs, vhb, o1b);
    k_attn_w2<<<2048, 256, 0, stream>>>(qrb, krb, vhb, o1b, dacs, lepeb, attnb);
    k_proj_ln<<<1024, 256, 0, stream>>>(attnb, x, ow, ob, n1_g, n1_b, t1b);
    k_ffn1<<<4096, 256, 0, stream>>>(t1b, ffn_w1, ffn_b1, hidb);
    k_ffn2<<<2048, 256, 0, stream>>>(hidb, t1b, ffn_w2, ffn_b2, n2_g, n2_b, out);
}

// Round 2
// 824.560 us; speedup vs baseline: 1.3229x; 1.3229x over previous
//
#include <hip/hip_runtime.h>
#include <math.h>

#define HWSZ 16384

__device__ __forceinline__ float gelu_f(float v) {
    return 0.5f * v * (1.0f + erff(v * 0.70710678118654752f));
}
__device__ __forceinline__ float splus_f(float v) {
    return (v > 20.f) ? v : log1pf(expf(v));
}

__device__ __forceinline__ float dot16_lds(const float* q, const float* kt, int j) {
    float4 k0 = *(const float4*)&kt[j*16];
    float4 k1 = *(const float4*)&kt[j*16+4];
    float4 k2 = *(const float4*)&kt[j*16+8];
    float4 k3 = *(const float4*)&kt[j*16+12];
    return q[0]*k0.x + q[1]*k0.y + q[2]*k0.z + q[3]*k0.w
         + q[4]*k1.x + q[5]*k1.y + q[6]*k1.z + q[7]*k1.w
         + q[8]*k2.x + q[9]*k2.y + q[10]*k2.z + q[11]*k2.w
         + q[12]*k3.x + q[13]*k3.y + q[14]*k3.z + q[15]*k3.w;
}

__device__ __forceinline__ void acc16(float* acc, float e, const float* vt, int j) {
    float4 v0 = *(const float4*)&vt[j*16];
    float4 v1 = *(const float4*)&vt[j*16+4];
    float4 v2 = *(const float4*)&vt[j*16+8];
    float4 v3 = *(const float4*)&vt[j*16+12];
    acc[0]  += e*v0.x; acc[1]  += e*v0.y; acc[2]  += e*v0.z; acc[3]  += e*v0.w;
    acc[4]  += e*v1.x; acc[5]  += e*v1.y; acc[6]  += e*v1.z; acc[7]  += e*v1.w;
    acc[8]  += e*v2.x; acc[9]  += e*v2.y; acc[10] += e*v2.z; acc[11] += e*v2.w;
    acc[12] += e*v3.x; acc[13] += e*v3.y; acc[14] += e*v3.z; acc[15] += e*v3.w;
}

// ---------------- Kernel 1: fusion gate ----------------
__global__ __launch_bounds__(256) void k_fuse(
    const float* __restrict__ y, const float* __restrict__ th,
    const float* __restrict__ w1, const float* __restrict__ b1,
    const float* __restrict__ w2, const float* __restrict__ b2,
    float* __restrict__ fused)
{
    __shared__ float w1t[8192];          // [c][o], c in 0..127, o in 0..63
    int tid = threadIdx.x;
    for (int i = tid; i < 8192; i += 256) {
        int o = i >> 7, c = i & 127;
        w1t[c*64 + o] = w1[i];
    }
    __syncthreads();
    int g = blockIdx.x*256 + tid;
    int b = g >> 14;
    int p = g & 16383;
    const float* yb = y  + (size_t)b*64*HWSZ + p;
    const float* tb = th + (size_t)b*64*HWSZ + p;
    float acc[64];
    #pragma unroll
    for (int o = 0; o < 64; ++o) acc[o] = b1[o];
    for (int c = 0; c < 64; ++c) {
        float f = yb[(size_t)c*HWSZ];
        #pragma unroll
        for (int o4 = 0; o4 < 16; ++o4) {
            float4 wv = *(const float4*)&w1t[c*64 + o4*4];
            acc[o4*4+0] += wv.x*f; acc[o4*4+1] += wv.y*f;
            acc[o4*4+2] += wv.z*f; acc[o4*4+3] += wv.w*f;
        }
    }
    for (int c = 0; c < 64; ++c) {
        float f = tb[(size_t)c*HWSZ];
        #pragma unroll
        for (int o4 = 0; o4 < 16; ++o4) {
            float4 wv = *(const float4*)&w1t[(64+c)*64 + o4*4];
            acc[o4*4+0] += wv.x*f; acc[o4*4+1] += wv.y*f;
            acc[o4*4+2] += wv.z*f; acc[o4*4+3] += wv.w*f;
        }
    }
    float l0 = b2[0], l1 = b2[1];
    #pragma unroll
    for (int o = 0; o < 64; ++o) {
        float hh = fmaxf(acc[o], 0.f);
        l0 += w2[o]*hh;
        l1 += w2[64+o]*hh;
    }
    float m = fmaxf(l0, l1);
    float e0 = expf(l0 - m), e1 = expf(l1 - m);
    float inv = 1.f/(e0 + e1);
    float wa = e0*inv, wb = e1*inv;
    float* fb = fused + (size_t)b*64*HWSZ + p;
    for (int c = 0; c < 64; ++c)
        fb[(size_t)c*HWSZ] = yb[(size_t)c*HWSZ]*wa + tb[(size_t)c*HWSZ]*wb;
}

// ---------------- Kernel 2: QKV + RoPE + dt ----------------
__global__ __launch_bounds__(256) void k_qkv(
    const float* __restrict__ x, const float* __restrict__ fused,
    const float* __restrict__ qw, const float* __restrict__ qb,
    const float* __restrict__ kw, const float* __restrict__ kb,
    const float* __restrict__ vw, const float* __restrict__ vb,
    const float* __restrict__ dtw, const float* __restrict__ dtb,
    const float* __restrict__ alog,
    float* __restrict__ qr, float* __restrict__ kr, float* __restrict__ v5,
    float* __restrict__ da, float* __restrict__ db)
{
    __shared__ float sw[12288];          // qw | kw | vw, each [c][o]
    __shared__ float sx[4096];           // [c][pos], 64x64
    int tid = threadIdx.x;
    for (int i = tid*4; i < 4096; i += 1024) {
        *(float4*)&sw[i]      = *(const float4*)&qw[i];
        *(float4*)&sw[4096+i] = *(const float4*)&kw[i];
        *(float4*)&sw[8192+i] = *(const float4*)&vw[i];
    }
    int b  = blockIdx.x >> 8;
    int p0 = (blockIdx.x & 255)*64;
    for (int vi = tid; vi < 1024; vi += 256) {
        int c = vi >> 4, p4 = (vi & 15)*4;
        *(float4*)&sx[c*64 + p4] = *(const float4*)&x[((size_t)(b*64+c))*HWSZ + p0 + p4];
    }
    __syncthreads();
    int lane = tid & 63;
    int n = tid >> 6;
    int p = p0 + lane;
    int h = p >> 7, w = p & 127;
    float sn[8], cn[8];
    #pragma unroll
    for (int t = 0; t < 8; ++t) {
        float ang = exp2f(-1.89824462565f * (float)t);   // 10000^(-t/7)
        sincosf((float)p * ang, &sn[t], &cn[t]);
    }
    float a[16];
    // ---- Q head n ----
    #pragma unroll
    for (int d = 0; d < 16; ++d) a[d] = qb[n*16+d];
    for (int c = 0; c < 64; ++c) {
        float xc = sx[c*64 + lane];
        #pragma unroll
        for (int d4 = 0; d4 < 4; ++d4) {
            float4 wv = *(const float4*)&sw[c*64 + n*16 + d4*4];
            a[d4*4+0] += wv.x*xc; a[d4*4+1] += wv.y*xc;
            a[d4*4+2] += wv.z*xc; a[d4*4+3] += wv.w*xc;
        }
    }
    {
        float r[16];
        #pragma unroll
        for (int t = 0; t < 8; ++t) {
            r[2*t]   = a[2*t]*cn[t]   - a[2*t+1]*sn[t];
            r[2*t+1] = a[2*t+1]*cn[t] + a[2*t]*sn[t];
        }
        float* dst = qr + (((size_t)(b*4+n))*HWSZ + p)*16;
        #pragma unroll
        for (int d4 = 0; d4 < 4; ++d4)
            *(float4*)&dst[d4*4] = make_float4(r[d4*4],r[d4*4+1],r[d4*4+2],r[d4*4+3]);
    }
    // ---- dt / da / db ----
    {
        float dt0 = 0.f, dt1 = 0.f;
        #pragma unroll
        for (int d = 0; d < 16; ++d) {
            float xv = sx[(n*16+d)*64 + lane];
            dt0 += xv*dtw[2*d];
            dt1 += xv*dtw[2*d+1];
        }
        float A  = -expf(alog[n]);
        float bb = dtb[n];
        da[((b*128+h)*4+n)*128 + w] = splus_f(dt0+bb)*A;
        db[((b*128+w)*4+n)*128 + h] = splus_f(dt1+bb)*A;
    }
    __syncthreads();
    for (int vi = tid; vi < 1024; vi += 256) {
        int c = vi >> 4, p4 = (vi & 15)*4;
        *(float4*)&sx[c*64 + p4] = *(const float4*)&fused[((size_t)(b*64+c))*HWSZ + p0 + p4];
    }
    __syncthreads();
    // ---- K head n (scaled 0.25, RoPE) ----
    #pragma unroll
    for (int d = 0; d < 16; ++d) a[d] = kb[n*16+d];
    for (int c = 0; c < 64; ++c) {
        float xc = sx[c*64 + lane];
        #pragma unroll
        for (int d4 = 0; d4 < 4; ++d4) {
            float4 wv = *(const float4*)&sw[4096 + c*64 + n*16 + d4*4];
            a[d4*4+0] += wv.x*xc; a[d4*4+1] += wv.y*xc;
            a[d4*4+2] += wv.z*xc; a[d4*4+3] += wv.w*xc;
        }
    }
    {
        float r[16];
        #pragma unroll
        for (int t = 0; t < 8; ++t) {
            float e = a[2*t]*0.25f, o = a[2*t+1]*0.25f;
            r[2*t]   = e*cn[t] - o*sn[t];
            r[2*t+1] = o*cn[t] + e*sn[t];
        }
        float* dst = kr + (((size_t)(b*4+n))*HWSZ + p)*16;
        #pragma unroll
        for (int d4 = 0; d4 < 4; ++d4)
            *(float4*)&dst[d4*4] = make_float4(r[d4*4],r[d4*4+1],r[d4*4+2],r[d4*4+3]);
    }
    // ---- V head n ----
    #pragma unroll
    for (int d = 0; d < 16; ++d) a[d] = vb[n*16+d];
    for (int c = 0; c < 64; ++c) {
        float xc = sx[c*64 + lane];
        #pragma unroll
        for (int d4 = 0; d4 < 4; ++d4) {
            float4 wv = *(const float4*)&sw[8192 + c*64 + n*16 + d4*4];
            a[d4*4+0] += wv.x*xc; a[d4*4+1] += wv.y*xc;
            a[d4*4+2] += wv.z*xc; a[d4*4+3] += wv.w*xc;
        }
    }
    {
        float* dst = v5 + (((size_t)(b*4+n))*HWSZ + p)*16;
        #pragma unroll
        for (int d4 = 0; d4 < 4; ++d4)
            *(float4*)&dst[d4*4] = make_float4(a[d4*4],a[d4*4+1],a[d4*4+2],a[d4*4+3]);
    }
}

// ---------------- Kernel 2b: cumsums ----------------
__global__ __launch_bounds__(256) void k_cumsum(float* __restrict__ da, float* __restrict__ db)
{
    int gw = (blockIdx.x*256 + threadIdx.x) >> 6;   // 0..4095
    int lane = threadIdx.x & 63;
    float* base = (gw < 2048) ? (da + (size_t)gw*128) : (db + (size_t)(gw-2048)*128);
    float2 e = *(float2*)&base[lane*2];
    float s = e.x + e.y;
    #pragma unroll
    for (int d = 1; d < 64; d <<= 1) {
        float t = __shfl_up(s, d, 64);
        if (lane >= d) s += t;
    }
    float excl = s - (e.x + e.y);
    float2 o;
    o.x = excl + e.x;
    o.y = excl + e.x + e.y;
    *(float2*)&base[lane*2] = o;
}

// ---------------- Kernel 3: LePE depthwise 5x5 conv ----------------
__global__ __launch_bounds__(256) void k_lepe(
    const float* __restrict__ v5, const float* __restrict__ lw,
    const float* __restrict__ lb, float* __restrict__ lepe)
{
    int g = blockIdx.x*256 + threadIdx.x;
    int c = g & 63;
    int p = g >> 6;
    int w = p & 127, h = (p >> 7) & 127, b = p >> 14;
    int n = c >> 4, d = c & 15;
    const float* vpl = v5 + ((size_t)(b*4+n))*HWSZ*16 + d;
    float acc = lb[c];
    #pragma unroll
    for (int ky = 0; ky < 5; ++ky) {
        int hy = h + ky - 2;
        if (hy < 0 || hy > 127) continue;
        #pragma unroll
        for (int kx = 0; kx < 5; ++kx) {
            int wx = w + kx - 2;
            if (wx < 0 || wx > 127) continue;
            acc += vpl[((size_t)(hy*128 + wx))*16] * lw[(ky*5+kx)*64 + c];
        }
    }
    lepe[g] = acc;
}

// ---------------- Kernel 4: row attention pass 1 -> v_w ----------------
__global__ __launch_bounds__(256) void k_attn_w1(
    const float* __restrict__ qr, const float* __restrict__ kr,
    const float* __restrict__ v5, const float* __restrict__ dacs,
    float* __restrict__ vwb)
{
    __shared__ float qt[2048], kt[2048], vt[2048], csr[128];
    int tid = threadIdx.x, bid = blockIdx.x;
    int h = bid & 127, n = (bid >> 7) & 3, b = bid >> 9;
    size_t rowoff = ((size_t)((b*4+n)*128 + h)) * 2048;
    for (int i = tid*4; i < 2048; i += 1024) {
        *(float4*)&qt[i] = *(const float4*)&qr[rowoff + i];
        *(float4*)&kt[i] = *(const float4*)&kr[rowoff + i];
        *(float4*)&vt[i] = *(const float4*)&v5[rowoff + i];
    }
    if (tid < 128) csr[tid] = dacs[((b*128+h)*4+n)*128 + tid];
    __syncthreads();
    int i = tid >> 1, dh = tid & 1, jb = dh*64;
    float q[16];
    #pragma unroll
    for (int d4 = 0; d4 < 4; ++d4) {
        float4 t = *(const float4*)&qt[i*16 + d4*4];
        q[d4*4+0]=t.x; q[d4*4+1]=t.y; q[d4*4+2]=t.z; q[d4*4+3]=t.w;
    }
    float ci = csr[i];
    float l = 0.f;
    float acc[16];
    #pragma unroll
    for (int d = 0; d < 16; ++d) acc[d] = 0.f;
    for (int jj = 0; jj < 64; ++jj) {
        int j = jb + jj;
        float s = dot16_lds(q, kt, j) - fabsf(ci - csr[j]);
        float e = expf(s);
        l += e;
        acc16(acc, e, vt, j);
    }
    l += __shfl_xor(l, 1, 64);
    #pragma unroll
    for (int d = 0; d < 16; ++d) acc[d] += __shfl_xor(acc[d], 1, 64);
    float inv = 1.f/l;
    float o[8];
    #pragma unroll
    for (int u = 0; u < 8; ++u) o[u] = (dh ? acc[8+u] : acc[u])*inv;
    float* dst = vwb + rowoff + (size_t)i*16 + dh*8;
    *(float4*)&dst[0] = make_float4(o[0],o[1],o[2],o[3]);
    *(float4*)&dst[4] = make_float4(o[4],o[5],o[6],o[7]);
}

// ---------------- Kernel 5: column attention -> v_h and out1 ----------------
__global__ __launch_bounds__(256) void k_attn_h(
    const float* __restrict__ qr, const float* __restrict__ kr,
    const float* __restrict__ v5, const float* __restrict__ vwb,
    const float* __restrict__ dbcs,
    float* __restrict__ vhb, float* __restrict__ o1b)
{
    __shared__ float qt[2048], kt[2048], vt[2048], wt[2048], csr[128];
    int tid = threadIdx.x, bid = blockIdx.x;
    int w = bid & 127, n = (bid >> 7) & 3, b = bid >> 9;
    size_t base = ((size_t)(b*4+n)*16384 + w)*16;
    for (int vi = tid; vi < 512; vi += 256) {
        int hh = vi >> 2, dd = (vi & 3)*4;
        size_t src = base + (size_t)hh*2048 + dd;
        int di = hh*16 + dd;
        *(float4*)&qt[di] = *(const float4*)&qr[src];
        *(float4*)&kt[di] = *(const float4*)&kr[src];
        *(float4*)&vt[di] = *(const float4*)&v5[src];
        *(float4*)&wt[di] = *(const float4*)&vwb[src];
    }
    if (tid < 128) csr[tid] = dbcs[((b*128+w)*4+n)*128 + tid];
    __syncthreads();
    int i = tid >> 1, dh = tid & 1, jb = dh*64;
    float q[16];
    #pragma unroll
    for (int d4 = 0; d4 < 4; ++d4) {
        float4 t = *(const float4*)&qt[i*16 + d4*4];
        q[d4*4+0]=t.x; q[d4*4+1]=t.y; q[d4*4+2]=t.z; q[d4*4+3]=t.w;
    }
    float ci = csr[i];
    float l = 0.f;
    float a1[16], a2[16];
    #pragma unroll
    for (int d = 0; d < 16; ++d) { a1[d] = 0.f; a2[d] = 0.f; }
    for (int jj = 0; jj < 64; ++jj) {
        int j = jb + jj;
        float s = dot16_lds(q, kt, j) - fabsf(ci - csr[j]);
        float e = expf(s);
        l += e;
        acc16(a1, e, wt, j);   // out1 = P @ v_w
        acc16(a2, e, vt, j);   // v_h  = P @ v
    }
    l += __shfl_xor(l, 1, 64);
    #pragma unroll
    for (int d = 0; d < 16; ++d) {
        a1[d] += __shfl_xor(a1[d], 1, 64);
        a2[d] += __shfl_xor(a2[d], 1, 64);
    }
    float inv = 1.f/l;
    size_t dsto = (((size_t)(b*4+n)*128 + i)*128 + w)*16 + dh*8;
    float o[8];
    #pragma unroll
    for (int u = 0; u < 8; ++u) o[u] = (dh ? a1[8+u] : a1[u])*inv;
    *(float4*)&o1b[dsto]   = make_float4(o[0],o[1],o[2],o[3]);
    *(float4*)&o1b[dsto+4] = make_float4(o[4],o[5],o[6],o[7]);
    #pragma unroll
    for (int u = 0; u < 8; ++u) o[u] = (dh ? a2[8+u] : a2[u])*inv;
    *(float4*)&vhb[dsto]   = make_float4(o[0],o[1],o[2],o[3]);
    *(float4*)&vhb[dsto+4] = make_float4(o[4],o[5],o[6],o[7]);
}

// ---------------- Kernel 6: row attention pass 2 -> out2, combine + lepe ----------------
__global__ __launch_bounds__(256) void k_attn_w2(
    const float* __restrict__ qr, const float* __restrict__ kr,
    const float* __restrict__ vhb, const float* __restrict__ o1b,
    const float* __restrict__ dacs, const float* __restrict__ lepe,
    float* __restrict__ attn)
{
    __shared__ float qt[2048], kt[2048], vt[2048], ot[2048], csr[128];
    int tid = threadIdx.x, bid = blockIdx.x;
    int h = bid & 127, n = (bid >> 7) & 3, b = bid >> 9;
    size_t rowoff = ((size_t)((b*4+n)*128 + h)) * 2048;
    for (int i = tid*4; i < 2048; i += 1024) {
        *(float4*)&qt[i] = *(const float4*)&qr[rowoff + i];
        *(float4*)&kt[i] = *(const float4*)&kr[rowoff + i];
        *(float4*)&vt[i] = *(const float4*)&vhb[rowoff + i];
        *(float4*)&ot[i] = *(const float4*)&o1b[rowoff + i];
    }
    if (tid < 128) csr[tid] = dacs[((b*128+h)*4+n)*128 + tid];
    __syncthreads();
    int i = tid >> 1, dh = tid & 1, jb = dh*64;
    float q[16];
    #pragma unroll
    for (int d4 = 0; d4 < 4; ++d4) {
        float4 t = *(const float4*)&qt[i*16 + d4*4];
        q[d4*4+0]=t.x; q[d4*4+1]=t.y; q[d4*4+2]=t.z; q[d4*4+3]=t.w;
    }
    float ci = csr[i];
    float l = 0.f;
    float acc[16];
    #pragma unroll
    for (int d = 0; d < 16; ++d) acc[d] = 0.f;
    for (int jj = 0; jj < 64; ++jj) {
        int j = jb + jj;
        float s = dot16_lds(q, kt, j) - fabsf(ci - csr[j]);
        float e = expf(s);
        l += e;
        acc16(acc, e, vt, j);
    }
    l += __shfl_xor(l, 1, 64);
    #pragma unroll
    for (int d = 0; d < 16; ++d) acc[d] += __shfl_xor(acc[d], 1, 64);
    float inv = 1.f/l;
    int p = h*128 + i;
    size_t obase = ((size_t)(b*16384 + p))*64 + n*16 + dh*8;
    float4 lp0 = *(const float4*)&lepe[obase];
    float4 lp1 = *(const float4*)&lepe[obase+4];
    float lpv[8] = {lp0.x,lp0.y,lp0.z,lp0.w,lp1.x,lp1.y,lp1.z,lp1.w};
    float o[8];
    #pragma unroll
    for (int u = 0; u < 8; ++u) {
        float o2 = (dh ? acc[8+u] : acc[u])*inv;
        o[u] = 0.5f*(ot[i*16 + dh*8 + u] + o2) + lpv[u];
    }
    *(float4*)&attn[obase]   = make_float4(o[0],o[1],o[2],o[3]);
    *(float4*)&attn[obase+4] = make_float4(o[4],o[5],o[6],o[7]);
}

// ---------------- Kernel 7: out-proj + residual + LN1 (register-tiled) ----------------
// block: 128 pos x 64 out-ch, K=64. grid 512.
__global__ __launch_bounds__(256) void k_proj_ln(
    const float* __restrict__ attn, const float* __restrict__ x,
    const float* __restrict__ ow, const float* __restrict__ ob,
    const float* __restrict__ g1, const float* __restrict__ b1,
    float* __restrict__ t1)
{
    __shared__ float As[64*132];     // [k][p], reused as outT [c][p] after compute
    __shared__ float Bs[4096];       // ow [k][c]
    int tid = threadIdx.x;
    int pbase = blockIdx.x*128;
    int b = pbase >> 14, p0 = pbase & 16383;
    for (int i = tid*4; i < 4096; i += 1024)
        *(float4*)&Bs[i] = *(const float4*)&ow[i];
    for (int vi = tid; vi < 2048; vi += 256) {
        int kk = vi & 15, p = vi >> 4;
        float4 av = *(const float4*)&attn[((size_t)(pbase+p))*64 + kk*4];
        As[(kk*4+0)*132 + p] = av.x;
        As[(kk*4+1)*132 + p] = av.y;
        As[(kk*4+2)*132 + p] = av.z;
        As[(kk*4+3)*132 + p] = av.w;
    }
    __syncthreads();
    int tc = tid & 15, tp = tid >> 4;
    float acc[8][4];
    #pragma unroll
    for (int pp = 0; pp < 8; ++pp)
        #pragma unroll
        for (int u = 0; u < 4; ++u) acc[pp][u] = 0.f;
    #pragma unroll 4
    for (int k = 0; k < 64; ++k) {
        float4 a0 = *(const float4*)&As[k*132 + tp*8];
        float4 a1 = *(const float4*)&As[k*132 + tp*8 + 4];
        float4 bv = *(const float4*)&Bs[k*64 + tc*4];
        float av8[8] = {a0.x,a0.y,a0.z,a0.w,a1.x,a1.y,a1.z,a1.w};
        float bv4[4] = {bv.x,bv.y,bv.z,bv.w};
        #pragma unroll
        for (int pp = 0; pp < 8; ++pp)
            #pragma unroll
            for (int u = 0; u < 4; ++u)
                acc[pp][u] += av8[pp]*bv4[u];
    }
    __syncthreads();
    float* outT = As;   // reuse
    #pragma unroll
    for (int u = 0; u < 4; ++u)
        #pragma unroll
        for (int pp = 0; pp < 8; ++pp)
            outT[(tc*4+u)*132 + tp*8 + pp] = acc[pp][u] + ob[tc*4+u];
    __syncthreads();
    int lane = tid & 63, wv = tid >> 6;
    float gg = g1[lane], bbv = b1[lane];
    for (int it = 0; it < 32; ++it) {
        int pos = wv*32 + it;
        int P = pbase + pos;
        float r = x[((size_t)(b*64 + lane))*HWSZ + p0 + pos] + outT[lane*132 + pos];
        float s = r;
        #pragma unroll
        for (int d = 1; d < 64; d <<= 1) s += __shfl_xor(s, d, 64);
        float mean = s*(1.f/64.f);
        float df = r - mean;
        float vv = df*df;
        #pragma unroll
        for (int d = 1; d < 64; d <<= 1) vv += __shfl_xor(vv, d, 64);
        float res = df*rsqrtf(vv*(1.f/64.f) + 1e-5f)*gg + bbv;
        t1[(size_t)P*64 + lane] = res;
    }
}

// ---------------- Kernel 8a: FFN up (gelu), register-tiled ----------------
// block: 128 pos x 64 hid (quarter of 256). grid 2048 (= 512 posgroups x 4 jq).
__global__ __launch_bounds__(256) void k_ffn1(
    const float* __restrict__ t1, const float* __restrict__ w1,
    const float* __restrict__ b1, float* __restrict__ hid)
{
    __shared__ float As[64*132];     // t1 tile [k][p]
    __shared__ float Bs[4096];       // w1 chunk [k][j] (64x64)
    int tid = threadIdx.x;
    int jq = blockIdx.x & 3;
    int pbase = (blockIdx.x >> 2)*128;
    for (int i = tid*4; i < 4096; i += 1024) {
        int k = i >> 6, j4 = i & 63;
        *(float4*)&Bs[i] = *(const float4*)&w1[k*256 + jq*64 + j4];
    }
    for (int vi = tid; vi < 2048; vi += 256) {
        int kk = vi & 15, p = vi >> 4;
        float4 av = *(const float4*)&t1[((size_t)(pbase+p))*64 + kk*4];
        As[(kk*4+0)*132 + p] = av.x;
        As[(kk*4+1)*132 + p] = av.y;
        As[(kk*4+2)*132 + p] = av.z;
        As[(kk*4+3)*132 + p] = av.w;
    }
    __syncthreads();
    int tc = tid & 15, tp = tid >> 4;
    float acc[8][4];
    #pragma unroll
    for (int pp = 0; pp < 8; ++pp)
        #pragma unroll
        for (int u = 0; u < 4; ++u) acc[pp][u] = 0.f;
    #pragma unroll 4
    for (int k = 0; k < 64; ++k) {
        float4 a0 = *(const float4*)&As[k*132 + tp*8];
        float4 a1 = *(const float4*)&As[k*132 + tp*8 + 4];
        float4 bv = *(const float4*)&Bs[k*64 + tc*4];
        float av8[8] = {a0.x,a0.y,a0.z,a0.w,a1.x,a1.y,a1.z,a1.w};
        float bv4[4] = {bv.x,bv.y,bv.z,bv.w};
        #pragma unroll
        for (int pp = 0; pp < 8; ++pp)
            #pragma unroll
            for (int u = 0; u < 4; ++u)
                acc[pp][u] += av8[pp]*bv4[u];
    }
    float bb[4];
    #pragma unroll
    for (int u = 0; u < 4; ++u) bb[u] = b1[jq*64 + tc*4 + u];
    #pragma unroll
    for (int pp = 0; pp < 8; ++pp) {
        float4 o;
        o.x = gelu_f(acc[pp][0] + bb[0]);
        o.y = gelu_f(acc[pp][1] + bb[1]);
        o.z = gelu_f(acc[pp][2] + bb[2]);
        o.w = gelu_f(acc[pp][3] + bb[3]);
        *(float4*)&hid[((size_t)(pbase + tp*8 + pp))*256 + jq*64 + tc*4] = o;
    }
}

// ---------------- Kernel 8b: FFN down + residual + LN2 + transpose, register-tiled ----------------
// block: 128 pos x 64 out-ch, K=256 in 4 chunks. grid 512.
__global__ __launch_bounds__(256) void k_ffn2(
    const float* __restrict__ hid, const float* __restrict__ t1,
    const float* __restrict__ w2, const float* __restrict__ b2,
    const float* __restrict__ g2, const float* __restrict__ bb2,
    float* __restrict__ outp)
{
    __shared__ float As[64*132];     // hid chunk [k][p], reused as outT [c][p]
    __shared__ float Bs[4096];       // w2 chunk [k][c]
    int tid = threadIdx.x;
    int pbase = blockIdx.x*128;
    int b = pbase >> 14, p0 = pbase & 16383;
    int tc = tid & 15, tp = tid >> 4;
    float acc[8][4];
    #pragma unroll
    for (int pp = 0; pp < 8; ++pp)
        #pragma unroll
        for (int u = 0; u < 4; ++u) acc[pp][u] = 0.f;
    for (int kc = 0; kc < 4; ++kc) {
        __syncthreads();
        for (int i = tid*4; i < 4096; i += 1024)
            *(float4*)&Bs[i] = *(const float4*)&w2[kc*4096 + i];
        for (int vi = tid; vi < 2048; vi += 256) {
            int kk = vi & 15, p = vi >> 4;
            float4 av = *(const float4*)&hid[((size_t)(pbase+p))*256 + kc*64 + kk*4];
            As[(kk*4+0)*132 + p] = av.x;
            As[(kk*4+1)*132 + p] = av.y;
            As[(kk*4+2)*132 + p] = av.z;
            As[(kk*4+3)*132 + p] = av.w;
        }
        __syncthreads();
        #pragma unroll 4
        for (int k = 0; k < 64; ++k) {
            float4 a0 = *(const float4*)&As[k*132 + tp*8];
            float4 a1 = *(const float4*)&As[k*132 + tp*8 + 4];
            float4 bv = *(const float4*)&Bs[k*64 + tc*4];
            float av8[8] = {a0.x,a0.y,a0.z,a0.w,a1.x,a1.y,a1.z,a1.w};
            float bv4[4] = {bv.x,bv.y,bv.z,bv.w};
            #pragma unroll
            for (int pp = 0; pp < 8; ++pp)
                #pragma unroll
                for (int u = 0; u < 4; ++u)
                    acc[pp][u] += av8[pp]*bv4[u];
        }
    }
    __syncthreads();
    float* outT = As;
    #pragma unroll
    for (int u = 0; u < 4; ++u)
        #pragma unroll
        for (int pp = 0; pp < 8; ++pp)
            outT[(tc*4+u)*132 + tp*8 + pp] = acc[pp][u] + b2[tc*4+u];
    __syncthreads();
    int lane = tid & 63, wv = tid >> 6;
    {
        float gg = g2[lane], bbv = bb2[lane];
        for (int it = 0; it < 32; ++it) {
            int pos = wv*32 + it;
            int P = pbase + pos;
            float r = t1[(size_t)P*64 + lane] + outT[lane*132 + pos];
            float s = r;
            #pragma unroll
            for (int d = 1; d < 64; d <<= 1) s += __shfl_xor(s, d, 64);
            float mean = s*(1.f/64.f);
            float df = r - mean;
            float vv = df*df;
            #pragma unroll
            for (int d = 1; d < 64; d <<= 1) vv += __shfl_xor(vv, d, 64);
            float res = df*rsqrtf(vv*(1.f/64.f) + 1e-5f)*gg + bbv;
            outT[lane*132 + pos] = res;
        }
    }
    __syncthreads();
    for (int vi = tid; vi < 2048; vi += 256) {
        int c = vi >> 5, p4 = (vi & 31)*4;
        float4 ov = *(const float4*)&outT[c*132 + p4];
        *(float4*)&outp[((size_t)(b*64 + c))*HWSZ + p0 + p4] = ov;
    }
}

extern "C" void kernel_launch(void* const* d_in, const int* in_sizes, int n_in,
                              void* d_out, int out_size, void* d_ws, size_t ws_size,
                              hipStream_t stream) {
    const float* x      = (const float*)d_in[0];
    const float* y      = (const float*)d_in[1];
    const float* th     = (const float*)d_in[2];
    const float* dw1_w  = (const float*)d_in[3];
    const float* dw1_b  = (const float*)d_in[4];
    const float* dw2_w  = (const float*)d_in[5];
    const float* dw2_b  = (const float*)d_in[6];
    const float* qw     = (const float*)d_in[7];
    const float* qb     = (const float*)d_in[8];
    const float* kw     = (const float*)d_in[9];
    const float* kb     = (const float*)d_in[10];
    const float* vw     = (const float*)d_in[11];
    const float* vb     = (const float*)d_in[12];
    const float* lepe_w = (const float*)d_in[13];
    const float* lepe_b = (const float*)d_in[14];
    const float* dt_w   = (const float*)d_in[15];
    const float* dt_bias= (const float*)d_in[16];
    const float* A_log  = (const float*)d_in[17];
    const float* ow     = (const float*)d_in[18];
    const float* ob     = (const float*)d_in[19];
    const float* n1_g   = (const float*)d_in[20];
    const float* n1_b   = (const float*)d_in[21];
    const float* ffn_w1 = (const float*)d_in[22];
    const float* ffn_b1 = (const float*)d_in[23];
    const float* ffn_w2 = (const float*)d_in[24];
    const float* ffn_b2 = (const float*)d_in[25];
    const float* n2_g   = (const float*)d_in[26];
    const float* n2_b   = (const float*)d_in[27];
    float* out = (float*)d_out;

    const size_t SZ = 4194304;   // B*C*H*W elements
    float* ws    = (float*)d_ws;
    float* fused = ws + 0*SZ;    // reused as v_w after kernel 4
    float* qrb   = ws + 1*SZ;
    float* krb   = ws + 2*SZ;
    float* v5b   = ws + 3*SZ;
    float* lepeb = ws + 4*SZ;
    float* vhb   = ws + 5*SZ;
    float* o1b   = ws + 6*SZ;
    float* attnb = ws + 7*SZ;
    float* t1b   = ws + 8*SZ;
    float* dacs  = ws + 9*SZ;               // 262144
    float* dbcs  = ws + 9*SZ + 262144;      // 262144
    float* hidb  = ws + 1*SZ;               // reuse qr..lepe region (4*SZ)

    k_fuse<<<256, 256, 0, stream>>>(y, th, dw1_w, dw1_b, dw2_w, dw2_b, fused);
    k_qkv<<<1024, 256, 0, stream>>>(x, fused, qw, qb, kw, kb, vw, vb,
                                    dt_w, dt_bias, A_log, qrb, krb, v5b, dacs, dbcs);
    k_cumsum<<<1024, 256, 0, stream>>>(dacs, dbcs);
    k_lepe<<<65536, 256, 0, stream>>>(v5b, lepe_w, lepe_b, lepeb);
    k_attn_w1<<<2048, 256, 0, stream>>>(qrb, krb, v5b, dacs, fused);
    k_attn_h<<<2048, 256, 0, stream>>>(qrb, krb, v5b, fused, dbcs, vhb, o1b);
    k_attn_w2<<<2048, 256, 0, stream>>>(qrb, krb, vhb, o1b, dacs, lepeb, attnb);
    k_proj_ln<<<512, 256, 0, stream>>>(attnb, x, ow, ob, n1_g, n1_b, t1b);
    k_ffn1<<<2048, 256, 0, stream>>>(t1b, ffn_w1, ffn_b1, hidb);
    k_ffn2<<<512, 256, 0, stream>>>(hidb, t1b, ffn_w2, ffn_b2, n2_g, n2_b, out);
}

// Round 3
// 649.401 us; speedup vs baseline: 1.6797x; 1.2697x over previous
//
#include <hip/hip_runtime.h>
#include <math.h>

#define HWSZ 16384

__device__ __forceinline__ float gelu_f(float v) {
    return 0.5f * v * (1.0f + erff(v * 0.70710678118654752f));
}
__device__ __forceinline__ float splus_f(float v) {
    return (v > 20.f) ? v : log1pf(expf(v));
}

__device__ __forceinline__ float dot16_lds(const float* q, const float* kt, int j) {
    float4 k0 = *(const float4*)&kt[j*16];
    float4 k1 = *(const float4*)&kt[j*16+4];
    float4 k2 = *(const float4*)&kt[j*16+8];
    float4 k3 = *(const float4*)&kt[j*16+12];
    return q[0]*k0.x + q[1]*k0.y + q[2]*k0.z + q[3]*k0.w
         + q[4]*k1.x + q[5]*k1.y + q[6]*k1.z + q[7]*k1.w
         + q[8]*k2.x + q[9]*k2.y + q[10]*k2.z + q[11]*k2.w
         + q[12]*k3.x + q[13]*k3.y + q[14]*k3.z + q[15]*k3.w;
}

__device__ __forceinline__ void acc16(float* acc, float e, const float* vt, int j) {
    float4 v0 = *(const float4*)&vt[j*16];
    float4 v1 = *(const float4*)&vt[j*16+4];
    float4 v2 = *(const float4*)&vt[j*16+8];
    float4 v3 = *(const float4*)&vt[j*16+12];
    acc[0]  += e*v0.x; acc[1]  += e*v0.y; acc[2]  += e*v0.z; acc[3]  += e*v0.w;
    acc[4]  += e*v1.x; acc[5]  += e*v1.y; acc[6]  += e*v1.z; acc[7]  += e*v1.w;
    acc[8]  += e*v2.x; acc[9]  += e*v2.y; acc[10] += e*v2.z; acc[11] += e*v2.w;
    acc[12] += e*v3.x; acc[13] += e*v3.y; acc[14] += e*v3.z; acc[15] += e*v3.w;
}

// ---------------- Kernel 1: fusion gate ----------------
__global__ __launch_bounds__(256) void k_fuse(
    const float* __restrict__ y, const float* __restrict__ th,
    const float* __restrict__ w1, const float* __restrict__ b1,
    const float* __restrict__ w2, const float* __restrict__ b2,
    float* __restrict__ fused)
{
    __shared__ float w1t[8192];          // [c][o], c in 0..127, o in 0..63
    int tid = threadIdx.x;
    for (int i = tid; i < 8192; i += 256) {
        int o = i >> 7, c = i & 127;
        w1t[c*64 + o] = w1[i];
    }
    __syncthreads();
    int g = blockIdx.x*256 + tid;
    int b = g >> 14;
    int p = g & 16383;
    const float* yb = y  + (size_t)b*64*HWSZ + p;
    const float* tb = th + (size_t)b*64*HWSZ + p;
    float acc[64];
    #pragma unroll
    for (int o = 0; o < 64; ++o) acc[o] = b1[o];
    for (int c = 0; c < 64; ++c) {
        float f = yb[(size_t)c*HWSZ];
        #pragma unroll
        for (int o4 = 0; o4 < 16; ++o4) {
            float4 wv = *(const float4*)&w1t[c*64 + o4*4];
            acc[o4*4+0] += wv.x*f; acc[o4*4+1] += wv.y*f;
            acc[o4*4+2] += wv.z*f; acc[o4*4+3] += wv.w*f;
        }
    }
    for (int c = 0; c < 64; ++c) {
        float f = tb[(size_t)c*HWSZ];
        #pragma unroll
        for (int o4 = 0; o4 < 16; ++o4) {
            float4 wv = *(const float4*)&w1t[(64+c)*64 + o4*4];
            acc[o4*4+0] += wv.x*f; acc[o4*4+1] += wv.y*f;
            acc[o4*4+2] += wv.z*f; acc[o4*4+3] += wv.w*f;
        }
    }
    float l0 = b2[0], l1 = b2[1];
    #pragma unroll
    for (int o = 0; o < 64; ++o) {
        float hh = fmaxf(acc[o], 0.f);
        l0 += w2[o]*hh;
        l1 += w2[64+o]*hh;
    }
    float m = fmaxf(l0, l1);
    float e0 = expf(l0 - m), e1 = expf(l1 - m);
    float inv = 1.f/(e0 + e1);
    float wa = e0*inv, wb = e1*inv;
    float* fb = fused + (size_t)b*64*HWSZ + p;
    for (int c = 0; c < 64; ++c)
        fb[(size_t)c*HWSZ] = yb[(size_t)c*HWSZ]*wa + tb[(size_t)c*HWSZ]*wb;
}

// ---------------- Kernel 2: QKV + RoPE + dt ----------------
__global__ __launch_bounds__(256) void k_qkv(
    const float* __restrict__ x, const float* __restrict__ fused,
    const float* __restrict__ qw, const float* __restrict__ qb,
    const float* __restrict__ kw, const float* __restrict__ kb,
    const float* __restrict__ vw, const float* __restrict__ vb,
    const float* __restrict__ dtw, const float* __restrict__ dtb,
    const float* __restrict__ alog,
    float* __restrict__ qr, float* __restrict__ kr, float* __restrict__ v5,
    float* __restrict__ da, float* __restrict__ db)
{
    __shared__ float sw[12288];          // qw | kw | vw, each [c][o]
    __shared__ float sx[4096];           // [c][pos], 64x64
    int tid = threadIdx.x;
    for (int i = tid*4; i < 4096; i += 1024) {
        *(float4*)&sw[i]      = *(const float4*)&qw[i];
        *(float4*)&sw[4096+i] = *(const float4*)&kw[i];
        *(float4*)&sw[8192+i] = *(const float4*)&vw[i];
    }
    int b  = blockIdx.x >> 8;
    int p0 = (blockIdx.x & 255)*64;
    for (int vi = tid; vi < 1024; vi += 256) {
        int c = vi >> 4, p4 = (vi & 15)*4;
        *(float4*)&sx[c*64 + p4] = *(const float4*)&x[((size_t)(b*64+c))*HWSZ + p0 + p4];
    }
    __syncthreads();
    int lane = tid & 63;
    int n = tid >> 6;
    int p = p0 + lane;
    int h = p >> 7, w = p & 127;
    float sn[8], cn[8];
    #pragma unroll
    for (int t = 0; t < 8; ++t) {
        float ang = exp2f(-1.89824462565f * (float)t);   // 10000^(-t/7)
        sincosf((float)p * ang, &sn[t], &cn[t]);
    }
    float a[16];
    // ---- Q head n ----
    #pragma unroll
    for (int d = 0; d < 16; ++d) a[d] = qb[n*16+d];
    for (int c = 0; c < 64; ++c) {
        float xc = sx[c*64 + lane];
        #pragma unroll
        for (int d4 = 0; d4 < 4; ++d4) {
            float4 wv = *(const float4*)&sw[c*64 + n*16 + d4*4];
            a[d4*4+0] += wv.x*xc; a[d4*4+1] += wv.y*xc;
            a[d4*4+2] += wv.z*xc; a[d4*4+3] += wv.w*xc;
        }
    }
    {
        float r[16];
        #pragma unroll
        for (int t = 0; t < 8; ++t) {
            r[2*t]   = a[2*t]*cn[t]   - a[2*t+1]*sn[t];
            r[2*t+1] = a[2*t+1]*cn[t] + a[2*t]*sn[t];
        }
        float* dst = qr + (((size_t)(b*4+n))*HWSZ + p)*16;
        #pragma unroll
        for (int d4 = 0; d4 < 4; ++d4)
            *(float4*)&dst[d4*4] = make_float4(r[d4*4],r[d4*4+1],r[d4*4+2],r[d4*4+3]);
    }
    // ---- dt / da / db ----
    {
        float dt0 = 0.f, dt1 = 0.f;
        #pragma unroll
        for (int d = 0; d < 16; ++d) {
            float xv = sx[(n*16+d)*64 + lane];
            dt0 += xv*dtw[2*d];
            dt1 += xv*dtw[2*d+1];
        }
        float A  = -expf(alog[n]);
        float bb = dtb[n];
        da[((b*128+h)*4+n)*128 + w] = splus_f(dt0+bb)*A;
        db[((b*128+w)*4+n)*128 + h] = splus_f(dt1+bb)*A;
    }
    __syncthreads();
    for (int vi = tid; vi < 1024; vi += 256) {
        int c = vi >> 4, p4 = (vi & 15)*4;
        *(float4*)&sx[c*64 + p4] = *(const float4*)&fused[((size_t)(b*64+c))*HWSZ + p0 + p4];
    }
    __syncthreads();
    // ---- K head n (scaled 0.25, RoPE) ----
    #pragma unroll
    for (int d = 0; d < 16; ++d) a[d] = kb[n*16+d];
    for (int c = 0; c < 64; ++c) {
        float xc = sx[c*64 + lane];
        #pragma unroll
        for (int d4 = 0; d4 < 4; ++d4) {
            float4 wv = *(const float4*)&sw[4096 + c*64 + n*16 + d4*4];
            a[d4*4+0] += wv.x*xc; a[d4*4+1] += wv.y*xc;
            a[d4*4+2] += wv.z*xc; a[d4*4+3] += wv.w*xc;
        }
    }
    {
        float r[16];
        #pragma unroll
        for (int t = 0; t < 8; ++t) {
            float e = a[2*t]*0.25f, o = a[2*t+1]*0.25f;
            r[2*t]   = e*cn[t] - o*sn[t];
            r[2*t+1] = o*cn[t] + e*sn[t];
        }
        float* dst = kr + (((size_t)(b*4+n))*HWSZ + p)*16;
        #pragma unroll
        for (int d4 = 0; d4 < 4; ++d4)
            *(float4*)&dst[d4*4] = make_float4(r[d4*4],r[d4*4+1],r[d4*4+2],r[d4*4+3]);
    }
    // ---- V head n ----
    #pragma unroll
    for (int d = 0; d < 16; ++d) a[d] = vb[n*16+d];
    for (int c = 0; c < 64; ++c) {
        float xc = sx[c*64 + lane];
        #pragma unroll
        for (int d4 = 0; d4 < 4; ++d4) {
            float4 wv = *(const float4*)&sw[8192 + c*64 + n*16 + d4*4];
            a[d4*4+0] += wv.x*xc; a[d4*4+1] += wv.y*xc;
            a[d4*4+2] += wv.z*xc; a[d4*4+3] += wv.w*xc;
        }
    }
    {
        float* dst = v5 + (((size_t)(b*4+n))*HWSZ + p)*16;
        #pragma unroll
        for (int d4 = 0; d4 < 4; ++d4)
            *(float4*)&dst[d4*4] = make_float4(a[d4*4],a[d4*4+1],a[d4*4+2],a[d4*4+3]);
    }
}

// ---------------- Kernel 2b: cumsums ----------------
__global__ __launch_bounds__(256) void k_cumsum(float* __restrict__ da, float* __restrict__ db)
{
    int gw = (blockIdx.x*256 + threadIdx.x) >> 6;   // 0..4095
    int lane = threadIdx.x & 63;
    float* base = (gw < 2048) ? (da + (size_t)gw*128) : (db + (size_t)(gw-2048)*128);
    float2 e = *(float2*)&base[lane*2];
    float s = e.x + e.y;
    #pragma unroll
    for (int d = 1; d < 64; d <<= 1) {
        float t = __shfl_up(s, d, 64);
        if (lane >= d) s += t;
    }
    float excl = s - (e.x + e.y);
    float2 o;
    o.x = excl + e.x;
    o.y = excl + e.x + e.y;
    *(float2*)&base[lane*2] = o;
}

// ---------------- Kernel 3: LePE depthwise 5x5 conv, LDS-tiled ----------------
// grid 512: bid = (((b*4+n)*4 + th)*8 + tw). Tile 32h x 16w x 16d, halo 36x20.
// Output layout: head-planar (b,n,p,d) like v5.
#define LROW 328   // 20 cells * 16 floats + 8 pad (breaks bank alignment)
__global__ __launch_bounds__(256) void k_lepe(
    const float* __restrict__ v5, const float* __restrict__ lw,
    const float* __restrict__ lb, float* __restrict__ lepe)
{
    __shared__ float sv[36*LROW];    // 11808 floats = 47.2 KB
    __shared__ float swt[400];       // 25 taps x 16 d
    int tid = threadIdx.x, bid = blockIdx.x;
    int tw = bid & 7, th_ = (bid >> 3) & 3, n = (bid >> 5) & 3, b = bid >> 7;
    int bn = b*4 + n;
    int h0 = th_*32, w0 = tw*16;
    for (int i = tid; i < 400; i += 256) {
        int tap = i >> 4, d = i & 15;
        swt[i] = lw[tap*64 + n*16 + d];
    }
    const float* vb = v5 + (size_t)bn*HWSZ*16;
    for (int vi = tid; vi < 2880; vi += 256) {
        int hh = vi / 80;
        int rem = vi - hh*80;
        int ww = rem >> 2, df = (rem & 3)*4;
        int h = h0 - 2 + hh, w = w0 - 2 + ww;
        float4 val = make_float4(0.f,0.f,0.f,0.f);
        if (h >= 0 && h < 128 && w >= 0 && w < 128)
            val = *(const float4*)&vb[((size_t)(h*128+w))*16 + df];
        *(float4*)&sv[hh*LROW + ww*16 + df] = val;
    }
    __syncthreads();
    int df = (tid & 3)*4;
    int s  = tid >> 2;          // 0..63
    int ph = s >> 1;            // 0..31
    int pw = (s & 1)*8;         // 0 or 8
    float4 bv = *(const float4*)&lb[n*16 + df];
    float acc[8][4];
    #pragma unroll
    for (int ow = 0; ow < 8; ++ow) {
        acc[ow][0] = bv.x; acc[ow][1] = bv.y; acc[ow][2] = bv.z; acc[ow][3] = bv.w;
    }
    #pragma unroll
    for (int ky = 0; ky < 5; ++ky) {
        float wgt[5][4];
        #pragma unroll
        for (int kx = 0; kx < 5; ++kx) {
            float4 wv = *(const float4*)&swt[(ky*5+kx)*16 + df];
            wgt[kx][0]=wv.x; wgt[kx][1]=wv.y; wgt[kx][2]=wv.z; wgt[kx][3]=wv.w;
        }
        float dat[13][4];
        #pragma unroll
        for (int c = 0; c < 13; ++c) {
            float4 dv = *(const float4*)&sv[(ph+ky)*LROW + (pw+c)*16 + df];
            dat[c][0]=dv.x; dat[c][1]=dv.y; dat[c][2]=dv.z; dat[c][3]=dv.w;
        }
        #pragma unroll
        for (int ow = 0; ow < 8; ++ow)
            #pragma unroll
            for (int kx = 0; kx < 5; ++kx)
                #pragma unroll
                for (int u = 0; u < 4; ++u)
                    acc[ow][u] += dat[ow+kx][u]*wgt[kx][u];
    }
    float* ob = lepe + ((size_t)bn*HWSZ + (size_t)(h0+ph)*128 + w0+pw)*16 + df;
    #pragma unroll
    for (int ow = 0; ow < 8; ++ow)
        *(float4*)&ob[ow*16] = make_float4(acc[ow][0],acc[ow][1],acc[ow][2],acc[ow][3]);
}

// ---------------- Kernel 4: row attention pass 1 -> v_w ----------------
__global__ __launch_bounds__(256) void k_attn_w1(
    const float* __restrict__ qr, const float* __restrict__ kr,
    const float* __restrict__ v5, const float* __restrict__ dacs,
    float* __restrict__ vwb)
{
    __shared__ float qt[2048], kt[2048], vt[2048], csr[128];
    int tid = threadIdx.x, bid = blockIdx.x;
    int h = bid & 127, n = (bid >> 7) & 3, b = bid >> 9;
    size_t rowoff = ((size_t)((b*4+n)*128 + h)) * 2048;
    for (int i = tid*4; i < 2048; i += 1024) {
        *(float4*)&qt[i] = *(const float4*)&qr[rowoff + i];
        *(float4*)&kt[i] = *(const float4*)&kr[rowoff + i];
        *(float4*)&vt[i] = *(const float4*)&v5[rowoff + i];
    }
    if (tid < 128) csr[tid] = dacs[((b*128+h)*4+n)*128 + tid];
    __syncthreads();
    int i = tid >> 1, dh = tid & 1, jb = dh*64;
    float q[16];
    #pragma unroll
    for (int d4 = 0; d4 < 4; ++d4) {
        float4 t = *(const float4*)&qt[i*16 + d4*4];
        q[d4*4+0]=t.x; q[d4*4+1]=t.y; q[d4*4+2]=t.z; q[d4*4+3]=t.w;
    }
    float ci = csr[i];
    float l = 0.f;
    float acc[16];
    #pragma unroll
    for (int d = 0; d < 16; ++d) acc[d] = 0.f;
    for (int jj = 0; jj < 64; ++jj) {
        int j = jb + jj;
        float s = dot16_lds(q, kt, j) - fabsf(ci - csr[j]);
        float e = expf(s);
        l += e;
        acc16(acc, e, vt, j);
    }
    l += __shfl_xor(l, 1, 64);
    #pragma unroll
    for (int d = 0; d < 16; ++d) acc[d] += __shfl_xor(acc[d], 1, 64);
    float inv = 1.f/l;
    float o[8];
    #pragma unroll
    for (int u = 0; u < 8; ++u) o[u] = (dh ? acc[8+u] : acc[u])*inv;
    float* dst = vwb + rowoff + (size_t)i*16 + dh*8;
    *(float4*)&dst[0] = make_float4(o[0],o[1],o[2],o[3]);
    *(float4*)&dst[4] = make_float4(o[4],o[5],o[6],o[7]);
}

// ---------------- Kernel 5: column attention -> v_h and out1 ----------------
__global__ __launch_bounds__(256) void k_attn_h(
    const float* __restrict__ qr, const float* __restrict__ kr,
    const float* __restrict__ v5, const float* __restrict__ vwb,
    const float* __restrict__ dbcs,
    float* __restrict__ vhb, float* __restrict__ o1b)
{
    __shared__ float qt[2048], kt[2048], vt[2048], wt[2048], csr[128];
    int tid = threadIdx.x, bid = blockIdx.x;
    int w = bid & 127, n = (bid >> 7) & 3, b = bid >> 9;
    size_t base = ((size_t)(b*4+n)*16384 + w)*16;
    for (int vi = tid; vi < 512; vi += 256) {
        int hh = vi >> 2, dd = (vi & 3)*4;
        size_t src = base + (size_t)hh*2048 + dd;
        int di = hh*16 + dd;
        *(float4*)&qt[di] = *(const float4*)&qr[src];
        *(float4*)&kt[di] = *(const float4*)&kr[src];
        *(float4*)&vt[di] = *(const float4*)&v5[src];
        *(float4*)&wt[di] = *(const float4*)&vwb[src];
    }
    if (tid < 128) csr[tid] = dbcs[((b*128+w)*4+n)*128 + tid];
    __syncthreads();
    int i = tid >> 1, dh = tid & 1, jb = dh*64;
    float q[16];
    #pragma unroll
    for (int d4 = 0; d4 < 4; ++d4) {
        float4 t = *(const float4*)&qt[i*16 + d4*4];
        q[d4*4+0]=t.x; q[d4*4+1]=t.y; q[d4*4+2]=t.z; q[d4*4+3]=t.w;
    }
    float ci = csr[i];
    float l = 0.f;
    float a1[16], a2[16];
    #pragma unroll
    for (int d = 0; d < 16; ++d) { a1[d] = 0.f; a2[d] = 0.f; }
    for (int jj = 0; jj < 64; ++jj) {
        int j = jb + jj;
        float s = dot16_lds(q, kt, j) - fabsf(ci - csr[j]);
        float e = expf(s);
        l += e;
        acc16(a1, e, wt, j);   // out1 = P @ v_w
        acc16(a2, e, vt, j);   // v_h  = P @ v
    }
    l += __shfl_xor(l, 1, 64);
    #pragma unroll
    for (int d = 0; d < 16; ++d) {
        a1[d] += __shfl_xor(a1[d], 1, 64);
        a2[d] += __shfl_xor(a2[d], 1, 64);
    }
    float inv = 1.f/l;
    size_t dsto = (((size_t)(b*4+n)*128 + i)*128 + w)*16 + dh*8;
    float o[8];
    #pragma unroll
    for (int u = 0; u < 8; ++u) o[u] = (dh ? a1[8+u] : a1[u])*inv;
    *(float4*)&o1b[dsto]   = make_float4(o[0],o[1],o[2],o[3]);
    *(float4*)&o1b[dsto+4] = make_float4(o[4],o[5],o[6],o[7]);
    #pragma unroll
    for (int u = 0; u < 8; ++u) o[u] = (dh ? a2[8+u] : a2[u])*inv;
    *(float4*)&vhb[dsto]   = make_float4(o[0],o[1],o[2],o[3]);
    *(float4*)&vhb[dsto+4] = make_float4(o[4],o[5],o[6],o[7]);
}

// ---------------- Kernel 6: row attention pass 2 -> out2, combine + lepe ----------------
__global__ __launch_bounds__(256) void k_attn_w2(
    const float* __restrict__ qr, const float* __restrict__ kr,
    const float* __restrict__ vhb, const float* __restrict__ o1b,
    const float* __restrict__ dacs, const float* __restrict__ lepe,
    float* __restrict__ attn)
{
    __shared__ float qt[2048], kt[2048], vt[2048], ot[2048], csr[128];
    int tid = threadIdx.x, bid = blockIdx.x;
    int h = bid & 127, n = (bid >> 7) & 3, b = bid >> 9;
    size_t rowoff = ((size_t)((b*4+n)*128 + h)) * 2048;
    for (int i = tid*4; i < 2048; i += 1024) {
        *(float4*)&qt[i] = *(const float4*)&qr[rowoff + i];
        *(float4*)&kt[i] = *(const float4*)&kr[rowoff + i];
        *(float4*)&vt[i] = *(const float4*)&vhb[rowoff + i];
        *(float4*)&ot[i] = *(const float4*)&o1b[rowoff + i];
    }
    if (tid < 128) csr[tid] = dacs[((b*128+h)*4+n)*128 + tid];
    __syncthreads();
    int i = tid >> 1, dh = tid & 1, jb = dh*64;
    float q[16];
    #pragma unroll
    for (int d4 = 0; d4 < 4; ++d4) {
        float4 t = *(const float4*)&qt[i*16 + d4*4];
        q[d4*4+0]=t.x; q[d4*4+1]=t.y; q[d4*4+2]=t.z; q[d4*4+3]=t.w;
    }
    float ci = csr[i];
    float l = 0.f;
    float acc[16];
    #pragma unroll
    for (int d = 0; d < 16; ++d) acc[d] = 0.f;
    for (int jj = 0; jj < 64; ++jj) {
        int j = jb + jj;
        float s = dot16_lds(q, kt, j) - fabsf(ci - csr[j]);
        float e = expf(s);
        l += e;
        acc16(acc, e, vt, j);
    }
    l += __shfl_xor(l, 1, 64);
    #pragma unroll
    for (int d = 0; d < 16; ++d) acc[d] += __shfl_xor(acc[d], 1, 64);
    float inv = 1.f/l;
    int p = h*128 + i;
    // lepe is head-planar (b,n,p,d)
    size_t lbase = ((size_t)((b*4+n))*HWSZ + p)*16 + dh*8;
    float4 lp0 = *(const float4*)&lepe[lbase];
    float4 lp1 = *(const float4*)&lepe[lbase+4];
    float lpv[8] = {lp0.x,lp0.y,lp0.z,lp0.w,lp1.x,lp1.y,lp1.z,lp1.w};
    size_t obase = ((size_t)(b*16384 + p))*64 + n*16 + dh*8;
    float o[8];
    #pragma unroll
    for (int u = 0; u < 8; ++u) {
        float o2 = (dh ? acc[8+u] : acc[u])*inv;
        o[u] = 0.5f*(ot[i*16 + dh*8 + u] + o2) + lpv[u];
    }
    *(float4*)&attn[obase]   = make_float4(o[0],o[1],o[2],o[3]);
    *(float4*)&attn[obase+4] = make_float4(o[4],o[5],o[6],o[7]);
}

// ---------------- Kernel 7: out-proj + residual + LN1 (register-tiled) ----------------
__global__ __launch_bounds__(256) void k_proj_ln(
    const float* __restrict__ attn, const float* __restrict__ x,
    const float* __restrict__ ow, const float* __restrict__ ob,
    const float* __restrict__ g1, const float* __restrict__ b1,
    float* __restrict__ t1)
{
    __shared__ float As[64*132];     // [k][p], reused as outT [c][p] after compute
    __shared__ float Bs[4096];       // ow [k][c]
    int tid = threadIdx.x;
    int pbase = blockIdx.x*128;
    int b = pbase >> 14, p0 = pbase & 16383;
    for (int i = tid*4; i < 4096; i += 1024)
        *(float4*)&Bs[i] = *(const float4*)&ow[i];
    for (int vi = tid; vi < 2048; vi += 256) {
        int kk = vi & 15, p = vi >> 4;
        float4 av = *(const float4*)&attn[((size_t)(pbase+p))*64 + kk*4];
        As[(kk*4+0)*132 + p] = av.x;
        As[(kk*4+1)*132 + p] = av.y;
        As[(kk*4+2)*132 + p] = av.z;
        As[(kk*4+3)*132 + p] = av.w;
    }
    __syncthreads();
    int tc = tid & 15, tp = tid >> 4;
    float acc[8][4];
    #pragma unroll
    for (int pp = 0; pp < 8; ++pp)
        #pragma unroll
        for (int u = 0; u < 4; ++u) acc[pp][u] = 0.f;
    #pragma unroll 4
    for (int k = 0; k < 64; ++k) {
        float4 a0 = *(const float4*)&As[k*132 + tp*8];
        float4 a1 = *(const float4*)&As[k*132 + tp*8 + 4];
        float4 bv = *(const float4*)&Bs[k*64 + tc*4];
        float av8[8] = {a0.x,a0.y,a0.z,a0.w,a1.x,a1.y,a1.z,a1.w};
        float bv4[4] = {bv.x,bv.y,bv.z,bv.w};
        #pragma unroll
        for (int pp = 0; pp < 8; ++pp)
            #pragma unroll
            for (int u = 0; u < 4; ++u)
                acc[pp][u] += av8[pp]*bv4[u];
    }
    __syncthreads();
    float* outT = As;   // reuse
    #pragma unroll
    for (int u = 0; u < 4; ++u)
        #pragma unroll
        for (int pp = 0; pp < 8; ++pp)
            outT[(tc*4+u)*132 + tp*8 + pp] = acc[pp][u] + ob[tc*4+u];
    __syncthreads();
    int lane = tid & 63, wv = tid >> 6;
    float gg = g1[lane], bbv = b1[lane];
    for (int it = 0; it < 32; ++it) {
        int pos = wv*32 + it;
        int P = pbase + pos;
        float r = x[((size_t)(b*64 + lane))*HWSZ + p0 + pos] + outT[lane*132 + pos];
        float s = r;
        #pragma unroll
        for (int d = 1; d < 64; d <<= 1) s += __shfl_xor(s, d, 64);
        float mean = s*(1.f/64.f);
        float df = r - mean;
        float vv = df*df;
        #pragma unroll
        for (int d = 1; d < 64; d <<= 1) vv += __shfl_xor(vv, d, 64);
        float res = df*rsqrtf(vv*(1.f/64.f) + 1e-5f)*gg + bbv;
        t1[(size_t)P*64 + lane] = res;
    }
}

// ---------------- Kernel 8a: FFN up (gelu), register-tiled ----------------
__global__ __launch_bounds__(256) void k_ffn1(
    const float* __restrict__ t1, const float* __restrict__ w1,
    const float* __restrict__ b1, float* __restrict__ hid)
{
    __shared__ float As[64*132];     // t1 tile [k][p]
    __shared__ float Bs[4096];       // w1 chunk [k][j] (64x64)
    int tid = threadIdx.x;
    int jq = blockIdx.x & 3;
    int pbase = (blockIdx.x >> 2)*128;
    for (int i = tid*4; i < 4096; i += 1024) {
        int k = i >> 6, j4 = i & 63;
        *(float4*)&Bs[i] = *(const float4*)&w1[k*256 + jq*64 + j4];
    }
    for (int vi = tid; vi < 2048; vi += 256) {
        int kk = vi & 15, p = vi >> 4;
        float4 av = *(const float4*)&t1[((size_t)(pbase+p))*64 + kk*4];
        As[(kk*4+0)*132 + p] = av.x;
        As[(kk*4+1)*132 + p] = av.y;
        As[(kk*4+2)*132 + p] = av.z;
        As[(kk*4+3)*132 + p] = av.w;
    }
    __syncthreads();
    int tc = tid & 15, tp = tid >> 4;
    float acc[8][4];
    #pragma unroll
    for (int pp = 0; pp < 8; ++pp)
        #pragma unroll
        for (int u = 0; u < 4; ++u) acc[pp][u] = 0.f;
    #pragma unroll 4
    for (int k = 0; k < 64; ++k) {
        float4 a0 = *(const float4*)&As[k*132 + tp*8];
        float4 a1 = *(const float4*)&As[k*132 + tp*8 + 4];
        float4 bv = *(const float4*)&Bs[k*64 + tc*4];
        float av8[8] = {a0.x,a0.y,a0.z,a0.w,a1.x,a1.y,a1.z,a1.w};
        float bv4[4] = {bv.x,bv.y,bv.z,bv.w};
        #pragma unroll
        for (int pp = 0; pp < 8; ++pp)
            #pragma unroll
            for (int u = 0; u < 4; ++u)
                acc[pp][u] += av8[pp]*bv4[u];
    }
    float bb[4];
    #pragma unroll
    for (int u = 0; u < 4; ++u) bb[u] = b1[jq*64 + tc*4 + u];
    #pragma unroll
    for (int pp = 0; pp < 8; ++pp) {
        float4 o;
        o.x = gelu_f(acc[pp][0] + bb[0]);
        o.y = gelu_f(acc[pp][1] + bb[1]);
        o.z = gelu_f(acc[pp][2] + bb[2]);
        o.w = gelu_f(acc[pp][3] + bb[3]);
        *(float4*)&hid[((size_t)(pbase + tp*8 + pp))*256 + jq*64 + tc*4] = o;
    }
}

// ---------------- Kernel 8b: FFN down + residual + LN2 + transpose, register-tiled ----------------
__global__ __launch_bounds__(256) void k_ffn2(
    const float* __restrict__ hid, const float* __restrict__ t1,
    const float* __restrict__ w2, const float* __restrict__ b2,
    const float* __restrict__ g2, const float* __restrict__ bb2,
    float* __restrict__ outp)
{
    __shared__ float As[64*132];     // hid chunk [k][p], reused as outT [c][p]
    __shared__ float Bs[4096];       // w2 chunk [k][c]
    int tid = threadIdx.x;
    int pbase = blockIdx.x*128;
    int b = pbase >> 14, p0 = pbase & 16383;
    int tc = tid & 15, tp = tid >> 4;
    float acc[8][4];
    #pragma unroll
    for (int pp = 0; pp < 8; ++pp)
        #pragma unroll
        for (int u = 0; u < 4; ++u) acc[pp][u] = 0.f;
    for (int kc = 0; kc < 4; ++kc) {
        __syncthreads();
        for (int i = tid*4; i < 4096; i += 1024)
            *(float4*)&Bs[i] = *(const float4*)&w2[kc*4096 + i];
        for (int vi = tid; vi < 2048; vi += 256) {
            int kk = vi & 15, p = vi >> 4;
            float4 av = *(const float4*)&hid[((size_t)(pbase+p))*256 + kc*64 + kk*4];
            As[(kk*4+0)*132 + p] = av.x;
            As[(kk*4+1)*132 + p] = av.y;
            As[(kk*4+2)*132 + p] = av.z;
            As[(kk*4+3)*132 + p] = av.w;
        }
        __syncthreads();
        #pragma unroll 4
        for (int k = 0; k < 64; ++k) {
            float4 a0 = *(const float4*)&As[k*132 + tp*8];
            float4 a1 = *(const float4*)&As[k*132 + tp*8 + 4];
            float4 bv = *(const float4*)&Bs[k*64 + tc*4];
            float av8[8] = {a0.x,a0.y,a0.z,a0.w,a1.x,a1.y,a1.z,a1.w};
            float bv4[4] = {bv.x,bv.y,bv.z,bv.w};
            #pragma unroll
            for (int pp = 0; pp < 8; ++pp)
                #pragma unroll
                for (int u = 0; u < 4; ++u)
                    acc[pp][u] += av8[pp]*bv4[u];
        }
    }
    __syncthreads();
    float* outT = As;
    #pragma unroll
    for (int u = 0; u < 4; ++u)
        #pragma unroll
        for (int pp = 0; pp < 8; ++pp)
            outT[(tc*4+u)*132 + tp*8 + pp] = acc[pp][u] + b2[tc*4+u];
    __syncthreads();
    int lane = tid & 63, wv = tid >> 6;
    {
        float gg = g2[lane], bbv = bb2[lane];
        for (int it = 0; it < 32; ++it) {
            int pos = wv*32 + it;
            int P = pbase + pos;
            float r = t1[(size_t)P*64 + lane] + outT[lane*132 + pos];
            float s = r;
            #pragma unroll
            for (int d = 1; d < 64; d <<= 1) s += __shfl_xor(s, d, 64);
            float mean = s*(1.f/64.f);
            float df = r - mean;
            float vv = df*df;
            #pragma unroll
            for (int d = 1; d < 64; d <<= 1) vv += __shfl_xor(vv, d, 64);
            float res = df*rsqrtf(vv*(1.f/64.f) + 1e-5f)*gg + bbv;
            outT[lane*132 + pos] = res;
        }
    }
    __syncthreads();
    for (int vi = tid; vi < 2048; vi += 256) {
        int c = vi >> 5, p4 = (vi & 31)*4;
        float4 ov = *(const float4*)&outT[c*132 + p4];
        *(float4*)&outp[((size_t)(b*64 + c))*HWSZ + p0 + p4] = ov;
    }
}

extern "C" void kernel_launch(void* const* d_in, const int* in_sizes, int n_in,
                              void* d_out, int out_size, void* d_ws, size_t ws_size,
                              hipStream_t stream) {
    const float* x      = (const float*)d_in[0];
    const float* y      = (const float*)d_in[1];
    const float* th     = (const float*)d_in[2];
    const float* dw1_w  = (const float*)d_in[3];
    const float* dw1_b  = (const float*)d_in[4];
    const float* dw2_w  = (const float*)d_in[5];
    const float* dw2_b  = (const float*)d_in[6];
    const float* qw     = (const float*)d_in[7];
    const float* qb     = (const float*)d_in[8];
    const float* kw     = (const float*)d_in[9];
    const float* kb     = (const float*)d_in[10];
    const float* vw     = (const float*)d_in[11];
    const float* vb     = (const float*)d_in[12];
    const float* lepe_w = (const float*)d_in[13];
    const float* lepe_b = (const float*)d_in[14];
    const float* dt_w   = (const float*)d_in[15];
    const float* dt_bias= (const float*)d_in[16];
    const float* A_log  = (const float*)d_in[17];
    const float* ow     = (const float*)d_in[18];
    const float* ob     = (const float*)d_in[19];
    const float* n1_g   = (const float*)d_in[20];
    const float* n1_b   = (const float*)d_in[21];
    const float* ffn_w1 = (const float*)d_in[22];
    const float* ffn_b1 = (const float*)d_in[23];
    const float* ffn_w2 = (const float*)d_in[24];
    const float* ffn_b2 = (const float*)d_in[25];
    const float* n2_g   = (const float*)d_in[26];
    const float* n2_b   = (const float*)d_in[27];
    float* out = (float*)d_out;

    const size_t SZ = 4194304;   // B*C*H*W elements
    float* ws    = (float*)d_ws;
    float* fused = ws + 0*SZ;    // reused as v_w after kernel 4
    float* qrb   = ws + 1*SZ;
    float* krb   = ws + 2*SZ;
    float* v5b   = ws + 3*SZ;
    float* lepeb = ws + 4*SZ;
    float* vhb   = ws + 5*SZ;
    float* o1b   = ws + 6*SZ;
    float* attnb = ws + 7*SZ;
    float* t1b   = ws + 8*SZ;
    float* dacs  = ws + 9*SZ;               // 262144
    float* dbcs  = ws + 9*SZ + 262144;      // 262144
    float* hidb  = ws + 1*SZ;               // reuse qr..lepe region (4*SZ)

    k_fuse<<<256, 256, 0, stream>>>(y, th, dw1_w, dw1_b, dw2_w, dw2_b, fused);
    k_qkv<<<1024, 256, 0, stream>>>(x, fused, qw, qb, kw, kb, vw, vb,
                                    dt_w, dt_bias, A_log, qrb, krb, v5b, dacs, dbcs);
    k_cumsum<<<1024, 256, 0, stream>>>(dacs, dbcs);
    k_lepe<<<512, 256, 0, stream>>>(v5b, lepe_w, lepe_b, lepeb);
    k_attn_w1<<<2048, 256, 0, stream>>>(qrb, krb, v5b, dacs, fused);
    k_attn_h<<<2048, 256, 0, stream>>>(qrb, krb, v5b, fused, dbcs, vhb, o1b);
    k_attn_w2<<<2048, 256, 0, stream>>>(qrb, krb, vhb, o1b, dacs, lepeb, attnb);
    k_proj_ln<<<512, 256, 0, stream>>>(attnb, x, ow, ob, n1_g, n1_b, t1b);
    k_ffn1<<<2048, 256, 0, stream>>>(t1b, ffn_w1, ffn_b1, hidb);
    k_ffn2<<<512, 256, 0, stream>>>(hidb, t1b, ffn_w2, ffn_b2, n2_g, n2_b, out);
}

// Round 4
// 476.529 us; speedup vs baseline: 2.2891x; 1.3628x over previous
//
#include <hip/hip_runtime.h>
#include <math.h>

#define HWSZ 16384

typedef __attribute__((ext_vector_type(8))) short bf16x8;
typedef __attribute__((ext_vector_type(4))) float f32x4;

__device__ __forceinline__ float gelu_f(float v) {
    return 0.5f * v * (1.0f + erff(v * 0.70710678118654752f));
}
__device__ __forceinline__ float splus_f(float v) {
    return (v > 20.f) ? v : log1pf(expf(v));
}
__device__ __forceinline__ unsigned short f2bf(float f) {
    union { float f; unsigned u; } v; v.f = f;
    unsigned r = (v.u + 0x7FFF + ((v.u >> 16) & 1)) >> 16;
    return (unsigned short)r;
}
__device__ __forceinline__ unsigned pk2(float a, float b) {
    return (unsigned)f2bf(a) | ((unsigned)f2bf(b) << 16);
}

// ---------------- Kernel 1: fusion gate ----------------
__global__ __launch_bounds__(256) void k_fuse(
    const float* __restrict__ y, const float* __restrict__ th,
    const float* __restrict__ w1, const float* __restrict__ b1,
    const float* __restrict__ w2, const float* __restrict__ b2,
    float* __restrict__ fused)
{
    __shared__ float w1t[8192];          // [c][o]
    int tid = threadIdx.x;
    for (int i = tid; i < 8192; i += 256) {
        int o = i >> 7, c = i & 127;
        w1t[c*64 + o] = w1[i];
    }
    __syncthreads();
    int g = blockIdx.x*256 + tid;
    int b = g >> 14;
    int p = g & 16383;
    const float* yb = y  + (size_t)b*64*HWSZ + p;
    const float* tb = th + (size_t)b*64*HWSZ + p;
    float acc[64];
    #pragma unroll
    for (int o = 0; o < 64; ++o) acc[o] = b1[o];
    for (int c = 0; c < 64; ++c) {
        float f = yb[(size_t)c*HWSZ];
        #pragma unroll
        for (int o4 = 0; o4 < 16; ++o4) {
            float4 wv = *(const float4*)&w1t[c*64 + o4*4];
            acc[o4*4+0] += wv.x*f; acc[o4*4+1] += wv.y*f;
            acc[o4*4+2] += wv.z*f; acc[o4*4+3] += wv.w*f;
        }
    }
    for (int c = 0; c < 64; ++c) {
        float f = tb[(size_t)c*HWSZ];
        #pragma unroll
        for (int o4 = 0; o4 < 16; ++o4) {
            float4 wv = *(const float4*)&w1t[(64+c)*64 + o4*4];
            acc[o4*4+0] += wv.x*f; acc[o4*4+1] += wv.y*f;
            acc[o4*4+2] += wv.z*f; acc[o4*4+3] += wv.w*f;
        }
    }
    float l0 = b2[0], l1 = b2[1];
    #pragma unroll
    for (int o = 0; o < 64; ++o) {
        float hh = fmaxf(acc[o], 0.f);
        l0 += w2[o]*hh;
        l1 += w2[64+o]*hh;
    }
    float m = fmaxf(l0, l1);
    float e0 = expf(l0 - m), e1 = expf(l1 - m);
    float inv = 1.f/(e0 + e1);
    float wa = e0*inv, wb = e1*inv;
    float* fb = fused + (size_t)b*64*HWSZ + p;
    for (int c = 0; c < 64; ++c)
        fb[(size_t)c*HWSZ] = yb[(size_t)c*HWSZ]*wa + tb[(size_t)c*HWSZ]*wb;
}

// ---------------- Kernel 2: QKV + RoPE + dt ----------------
__global__ __launch_bounds__(256) void k_qkv(
    const float* __restrict__ x, const float* __restrict__ fused,
    const float* __restrict__ qw, const float* __restrict__ qb,
    const float* __restrict__ kw, const float* __restrict__ kb,
    const float* __restrict__ vw, const float* __restrict__ vb,
    const float* __restrict__ dtw, const float* __restrict__ dtb,
    const float* __restrict__ alog,
    float* __restrict__ qr, float* __restrict__ kr, float* __restrict__ v5,
    float* __restrict__ da, float* __restrict__ db)
{
    __shared__ float sw[12288];          // qw | kw | vw, each [c][o]
    __shared__ float sx[4096];           // [c][pos], 64x64
    int tid = threadIdx.x;
    for (int i = tid*4; i < 4096; i += 1024) {
        *(float4*)&sw[i]      = *(const float4*)&qw[i];
        *(float4*)&sw[4096+i] = *(const float4*)&kw[i];
        *(float4*)&sw[8192+i] = *(const float4*)&vw[i];
    }
    int b  = blockIdx.x >> 8;
    int p0 = (blockIdx.x & 255)*64;
    for (int vi = tid; vi < 1024; vi += 256) {
        int c = vi >> 4, p4 = (vi & 15)*4;
        *(float4*)&sx[c*64 + p4] = *(const float4*)&x[((size_t)(b*64+c))*HWSZ + p0 + p4];
    }
    __syncthreads();
    int lane = tid & 63;
    int n = tid >> 6;
    int p = p0 + lane;
    int h = p >> 7, w = p & 127;
    float sn[8], cn[8];
    #pragma unroll
    for (int t = 0; t < 8; ++t) {
        float ang = exp2f(-1.89824462565f * (float)t);   // 10000^(-t/7)
        sincosf((float)p * ang, &sn[t], &cn[t]);
    }
    float a[16];
    // ---- Q head n ----
    #pragma unroll
    for (int d = 0; d < 16; ++d) a[d] = qb[n*16+d];
    for (int c = 0; c < 64; ++c) {
        float xc = sx[c*64 + lane];
        #pragma unroll
        for (int d4 = 0; d4 < 4; ++d4) {
            float4 wv = *(const float4*)&sw[c*64 + n*16 + d4*4];
            a[d4*4+0] += wv.x*xc; a[d4*4+1] += wv.y*xc;
            a[d4*4+2] += wv.z*xc; a[d4*4+3] += wv.w*xc;
        }
    }
    {
        float r[16];
        #pragma unroll
        for (int t = 0; t < 8; ++t) {
            r[2*t]   = a[2*t]*cn[t]   - a[2*t+1]*sn[t];
            r[2*t+1] = a[2*t+1]*cn[t] + a[2*t]*sn[t];
        }
        float* dst = qr + (((size_t)(b*4+n))*HWSZ + p)*16;
        #pragma unroll
        for (int d4 = 0; d4 < 4; ++d4)
            *(float4*)&dst[d4*4] = make_float4(r[d4*4],r[d4*4+1],r[d4*4+2],r[d4*4+3]);
    }
    // ---- dt / da / db ----
    {
        float dt0 = 0.f, dt1 = 0.f;
        #pragma unroll
        for (int d = 0; d < 16; ++d) {
            float xv = sx[(n*16+d)*64 + lane];
            dt0 += xv*dtw[2*d];
            dt1 += xv*dtw[2*d+1];
        }
        float A  = -expf(alog[n]);
        float bb = dtb[n];
        da[((b*128+h)*4+n)*128 + w] = splus_f(dt0+bb)*A;
        db[((b*128+w)*4+n)*128 + h] = splus_f(dt1+bb)*A;
    }
    __syncthreads();
    for (int vi = tid; vi < 1024; vi += 256) {
        int c = vi >> 4, p4 = (vi & 15)*4;
        *(float4*)&sx[c*64 + p4] = *(const float4*)&fused[((size_t)(b*64+c))*HWSZ + p0 + p4];
    }
    __syncthreads();
    // ---- K head n (scaled 0.25, RoPE) ----
    #pragma unroll
    for (int d = 0; d < 16; ++d) a[d] = kb[n*16+d];
    for (int c = 0; c < 64; ++c) {
        float xc = sx[c*64 + lane];
        #pragma unroll
        for (int d4 = 0; d4 < 4; ++d4) {
            float4 wv = *(const float4*)&sw[4096 + c*64 + n*16 + d4*4];
            a[d4*4+0] += wv.x*xc; a[d4*4+1] += wv.y*xc;
            a[d4*4+2] += wv.z*xc; a[d4*4+3] += wv.w*xc;
        }
    }
    {
        float r[16];
        #pragma unroll
        for (int t = 0; t < 8; ++t) {
            float e = a[2*t]*0.25f, o = a[2*t+1]*0.25f;
            r[2*t]   = e*cn[t] - o*sn[t];
            r[2*t+1] = o*cn[t] + e*sn[t];
        }
        float* dst = kr + (((size_t)(b*4+n))*HWSZ + p)*16;
        #pragma unroll
        for (int d4 = 0; d4 < 4; ++d4)
            *(float4*)&dst[d4*4] = make_float4(r[d4*4],r[d4*4+1],r[d4*4+2],r[d4*4+3]);
    }
    // ---- V head n ----
    #pragma unroll
    for (int d = 0; d < 16; ++d) a[d] = vb[n*16+d];
    for (int c = 0; c < 64; ++c) {
        float xc = sx[c*64 + lane];
        #pragma unroll
        for (int d4 = 0; d4 < 4; ++d4) {
            float4 wv = *(const float4*)&sw[8192 + c*64 + n*16 + d4*4];
            a[d4*4+0] += wv.x*xc; a[d4*4+1] += wv.y*xc;
            a[d4*4+2] += wv.z*xc; a[d4*4+3] += wv.w*xc;
        }
    }
    {
        float* dst = v5 + (((size_t)(b*4+n))*HWSZ + p)*16;
        #pragma unroll
        for (int d4 = 0; d4 < 4; ++d4)
            *(float4*)&dst[d4*4] = make_float4(a[d4*4],a[d4*4+1],a[d4*4+2],a[d4*4+3]);
    }
}

// ---------------- Kernel 2b: cumsums ----------------
__global__ __launch_bounds__(256) void k_cumsum(float* __restrict__ da, float* __restrict__ db)
{
    int gw = (blockIdx.x*256 + threadIdx.x) >> 6;   // 0..4095
    int lane = threadIdx.x & 63;
    float* base = (gw < 2048) ? (da + (size_t)gw*128) : (db + (size_t)(gw-2048)*128);
    float2 e = *(float2*)&base[lane*2];
    float s = e.x + e.y;
    #pragma unroll
    for (int d = 1; d < 64; d <<= 1) {
        float t = __shfl_up(s, d, 64);
        if (lane >= d) s += t;
    }
    float excl = s - (e.x + e.y);
    float2 o;
    o.x = excl + e.x;
    o.y = excl + e.x + e.y;
    *(float2*)&base[lane*2] = o;
}

// ---------------- Kernel 3: LePE depthwise 5x5 conv, LDS-tiled ----------------
#define LROW 328
__global__ __launch_bounds__(256) void k_lepe(
    const float* __restrict__ v5, const float* __restrict__ lw,
    const float* __restrict__ lb, float* __restrict__ lepe)
{
    __shared__ float sv[36*LROW];
    __shared__ float swt[400];
    int tid = threadIdx.x, bid = blockIdx.x;
    int tw = bid & 7, th_ = (bid >> 3) & 3, n = (bid >> 5) & 3, b = bid >> 7;
    int bn = b*4 + n;
    int h0 = th_*32, w0 = tw*16;
    for (int i = tid; i < 400; i += 256) {
        int tap = i >> 4, d = i & 15;
        swt[i] = lw[tap*64 + n*16 + d];
    }
    const float* vb = v5 + (size_t)bn*HWSZ*16;
    for (int vi = tid; vi < 2880; vi += 256) {
        int hh = vi / 80;
        int rem = vi - hh*80;
        int ww = rem >> 2, df = (rem & 3)*4;
        int h = h0 - 2 + hh, w = w0 - 2 + ww;
        float4 val = make_float4(0.f,0.f,0.f,0.f);
        if (h >= 0 && h < 128 && w >= 0 && w < 128)
            val = *(const float4*)&vb[((size_t)(h*128+w))*16 + df];
        *(float4*)&sv[hh*LROW + ww*16 + df] = val;
    }
    __syncthreads();
    int df = (tid & 3)*4;
    int s  = tid >> 2;
    int ph = s >> 1;
    int pw = (s & 1)*8;
    float4 bv = *(const float4*)&lb[n*16 + df];
    float acc[8][4];
    #pragma unroll
    for (int ow = 0; ow < 8; ++ow) {
        acc[ow][0] = bv.x; acc[ow][1] = bv.y; acc[ow][2] = bv.z; acc[ow][3] = bv.w;
    }
    #pragma unroll
    for (int ky = 0; ky < 5; ++ky) {
        float wgt[5][4];
        #pragma unroll
        for (int kx = 0; kx < 5; ++kx) {
            float4 wv = *(const float4*)&swt[(ky*5+kx)*16 + df];
            wgt[kx][0]=wv.x; wgt[kx][1]=wv.y; wgt[kx][2]=wv.z; wgt[kx][3]=wv.w;
        }
        float dat[13][4];
        #pragma unroll
        for (int c = 0; c < 13; ++c) {
            float4 dv = *(const float4*)&sv[(ph+ky)*LROW + (pw+c)*16 + df];
            dat[c][0]=dv.x; dat[c][1]=dv.y; dat[c][2]=dv.z; dat[c][3]=dv.w;
        }
        #pragma unroll
        for (int ow = 0; ow < 8; ++ow)
            #pragma unroll
            for (int kx = 0; kx < 5; ++kx)
                #pragma unroll
                for (int u = 0; u < 4; ++u)
                    acc[ow][u] += dat[ow+kx][u]*wgt[kx][u];
    }
    float* ob = lepe + ((size_t)bn*HWSZ + (size_t)(h0+ph)*128 + w0+pw)*16 + df;
    #pragma unroll
    for (int ow = 0; ow < 8; ++ow)
        *(float4*)&ob[ow*16] = make_float4(acc[ow][0],acc[ow][1],acc[ow][2],acc[ow][3]);
}

// ---------------- Kernel 4: row attention pass 1 -> v_w (MFMA) ----------------
// block = (b,n,h). Q,K zero-padded to K=32 bf16; V transposed [d][j] bf16.
// S = Q.K^T via mfma 16x16x32; P=exp(S+mask) -> LDS bf16; O = P.V via mfma.
__global__ __launch_bounds__(256) void k_attn_w1(
    const float* __restrict__ qr, const float* __restrict__ kr,
    const float* __restrict__ v5, const float* __restrict__ dacs,
    float* __restrict__ vwb)
{
    __shared__ unsigned short Qs[128*40], Ks[128*40], Vt[16*136], Ps[128*136];
    __shared__ float csr[128], linv[128];
    int tid = threadIdx.x, bid = blockIdx.x;
    int h = bid & 127, n = (bid >> 7) & 3, b = bid >> 9;
    size_t rowoff = ((size_t)((b*4+n)*128 + h)) * 2048;
    {   // zero pad k=16..31
        int i = tid >> 1, seg = (tid & 1)*8;
        *(uint4*)&Qs[i*40 + 16 + seg] = make_uint4(0,0,0,0);
        *(uint4*)&Ks[i*40 + 16 + seg] = make_uint4(0,0,0,0);
    }
    for (int vi = tid; vi < 512; vi += 256) {
        int i = vi >> 2, d4 = (vi & 3)*4;
        float4 q = *(const float4*)&qr[rowoff + i*16 + d4];
        float4 k = *(const float4*)&kr[rowoff + i*16 + d4];
        *(uint2*)&Qs[i*40 + d4] = make_uint2(pk2(q.x,q.y), pk2(q.z,q.w));
        *(uint2*)&Ks[i*40 + d4] = make_uint2(pk2(k.x,k.y), pk2(k.z,k.w));
    }
    {   // V^T staging: pairs of rows
        int jp = tid >> 2, d4 = (tid & 3)*4;
        float4 a = *(const float4*)&v5[rowoff + (2*jp)*16 + d4];
        float4 c = *(const float4*)&v5[rowoff + (2*jp+1)*16 + d4];
        *(unsigned*)&Vt[(d4+0)*136 + 2*jp] = pk2(a.x, c.x);
        *(unsigned*)&Vt[(d4+1)*136 + 2*jp] = pk2(a.y, c.y);
        *(unsigned*)&Vt[(d4+2)*136 + 2*jp] = pk2(a.z, c.z);
        *(unsigned*)&Vt[(d4+3)*136 + 2*jp] = pk2(a.w, c.w);
    }
    if (tid < 128) csr[tid] = dacs[((b*128+h)*4+n)*128 + tid];
    __syncthreads();
    int lane = tid & 63, wv = tid >> 6;
    int quad = lane >> 4, lm = lane & 15;
    int r0 = wv*32, r1 = wv*32 + 16;
    bf16x8 aQ0 = *(bf16x8*)&Qs[(r0+lm)*40 + quad*8];
    bf16x8 aQ1 = *(bf16x8*)&Qs[(r1+lm)*40 + quad*8];
    float csj[8], csi0[4], csi1[4];
    #pragma unroll
    for (int jt = 0; jt < 8; ++jt) csj[jt] = csr[jt*16+lm];
    #pragma unroll
    for (int r = 0; r < 4; ++r) { csi0[r] = csr[r0+quad*4+r]; csi1[r] = csr[r1+quad*4+r]; }
    float ls0[4]={0,0,0,0}, ls1[4]={0,0,0,0};
    f32x4 z = {0.f,0.f,0.f,0.f};
    #pragma unroll
    for (int jt = 0; jt < 8; ++jt) {
        bf16x8 bK = *(bf16x8*)&Ks[(jt*16+lm)*40 + quad*8];
        f32x4 s0 = __builtin_amdgcn_mfma_f32_16x16x32_bf16(aQ0, bK, z, 0,0,0);
        f32x4 s1 = __builtin_amdgcn_mfma_f32_16x16x32_bf16(aQ1, bK, z, 0,0,0);
        #pragma unroll
        for (int r = 0; r < 4; ++r) {
            float e0 = __expf(s0[r] - fabsf(csi0[r]-csj[jt])); ls0[r] += e0;
            float e1 = __expf(s1[r] - fabsf(csi1[r]-csj[jt])); ls1[r] += e1;
            Ps[(r0+quad*4+r)*136 + jt*16+lm] = f2bf(e0);
            Ps[(r1+quad*4+r)*136 + jt*16+lm] = f2bf(e1);
        }
    }
    #pragma unroll
    for (int r = 0; r < 4; ++r) {
        #pragma unroll
        for (int m = 1; m < 16; m <<= 1) {
            ls0[r] += __shfl_xor(ls0[r], m, 64);
            ls1[r] += __shfl_xor(ls1[r], m, 64);
        }
        if (lm == 0) { linv[r0+quad*4+r] = 1.f/ls0[r]; linv[r1+quad*4+r] = 1.f/ls1[r]; }
    }
    __syncthreads();
    f32x4 acc0 = z, acc1 = z;
    #pragma unroll
    for (int c = 0; c < 4; ++c) {
        bf16x8 bV  = *(bf16x8*)&Vt[lm*136 + c*32 + quad*8];
        bf16x8 aP0 = *(bf16x8*)&Ps[(r0+lm)*136 + c*32 + quad*8];
        bf16x8 aP1 = *(bf16x8*)&Ps[(r1+lm)*136 + c*32 + quad*8];
        acc0 = __builtin_amdgcn_mfma_f32_16x16x32_bf16(aP0, bV, acc0, 0,0,0);
        acc1 = __builtin_amdgcn_mfma_f32_16x16x32_bf16(aP1, bV, acc1, 0,0,0);
    }
    #pragma unroll
    for (int r = 0; r < 4; ++r) {
        int i0 = r0+quad*4+r, i1 = r1+quad*4+r;
        vwb[rowoff + (size_t)i0*16 + lm] = acc0[r]*linv[i0];
        vwb[rowoff + (size_t)i1*16 + lm] = acc1[r]*linv[i1];
    }
}

// ---------------- Kernel 5: column attention -> v_h and out1 (MFMA) ----------------
// block = (b,n,w). Inputs gathered (stride 8KB). Outputs in [w][h][d] layout (contiguous).
__global__ __launch_bounds__(256) void k_attn_h(
    const float* __restrict__ qr, const float* __restrict__ kr,
    const float* __restrict__ v5, const float* __restrict__ vwb,
    const float* __restrict__ dbcs,
    float* __restrict__ vhb, float* __restrict__ o1b)
{
    __shared__ unsigned short Qs[128*40], Ks[128*40], Vt[16*136], Wt[16*136], Ps[128*136];
    __shared__ float csr[128], linv[128];
    int tid = threadIdx.x, bid = blockIdx.x;
    int w = bid & 127, n = (bid >> 7) & 3, b = bid >> 9;
    int bn = b*4 + n;
    size_t base = ((size_t)bn*16384 + w)*16;     // element (h=0, d=0); h-stride 2048
    {
        int i = tid >> 1, seg = (tid & 1)*8;
        *(uint4*)&Qs[i*40 + 16 + seg] = make_uint4(0,0,0,0);
        *(uint4*)&Ks[i*40 + 16 + seg] = make_uint4(0,0,0,0);
    }
    for (int vi = tid; vi < 512; vi += 256) {
        int i = vi >> 2, d4 = (vi & 3)*4;
        float4 q = *(const float4*)&qr[base + (size_t)i*2048 + d4];
        float4 k = *(const float4*)&kr[base + (size_t)i*2048 + d4];
        *(uint2*)&Qs[i*40 + d4] = make_uint2(pk2(q.x,q.y), pk2(q.z,q.w));
        *(uint2*)&Ks[i*40 + d4] = make_uint2(pk2(k.x,k.y), pk2(k.z,k.w));
    }
    {
        int jp = tid >> 2, d4 = (tid & 3)*4;
        float4 a = *(const float4*)&v5[base + (size_t)(2*jp)*2048 + d4];
        float4 c = *(const float4*)&v5[base + (size_t)(2*jp+1)*2048 + d4];
        *(unsigned*)&Vt[(d4+0)*136 + 2*jp] = pk2(a.x, c.x);
        *(unsigned*)&Vt[(d4+1)*136 + 2*jp] = pk2(a.y, c.y);
        *(unsigned*)&Vt[(d4+2)*136 + 2*jp] = pk2(a.z, c.z);
        *(unsigned*)&Vt[(d4+3)*136 + 2*jp] = pk2(a.w, c.w);
        float4 e = *(const float4*)&vwb[base + (size_t)(2*jp)*2048 + d4];
        float4 f = *(const float4*)&vwb[base + (size_t)(2*jp+1)*2048 + d4];
        *(unsigned*)&Wt[(d4+0)*136 + 2*jp] = pk2(e.x, f.x);
        *(unsigned*)&Wt[(d4+1)*136 + 2*jp] = pk2(e.y, f.y);
        *(unsigned*)&Wt[(d4+2)*136 + 2*jp] = pk2(e.z, f.z);
        *(unsigned*)&Wt[(d4+3)*136 + 2*jp] = pk2(e.w, f.w);
    }
    if (tid < 128) csr[tid] = dbcs[((b*128+w)*4+n)*128 + tid];
    __syncthreads();
    int lane = tid & 63, wv = tid >> 6;
    int quad = lane >> 4, lm = lane & 15;
    int r0 = wv*32, r1 = wv*32 + 16;
    bf16x8 aQ0 = *(bf16x8*)&Qs[(r0+lm)*40 + quad*8];
    bf16x8 aQ1 = *(bf16x8*)&Qs[(r1+lm)*40 + quad*8];
    float csj[8], csi0[4], csi1[4];
    #pragma unroll
    for (int jt = 0; jt < 8; ++jt) csj[jt] = csr[jt*16+lm];
    #pragma unroll
    for (int r = 0; r < 4; ++r) { csi0[r] = csr[r0+quad*4+r]; csi1[r] = csr[r1+quad*4+r]; }
    float ls0[4]={0,0,0,0}, ls1[4]={0,0,0,0};
    f32x4 z = {0.f,0.f,0.f,0.f};
    #pragma unroll
    for (int jt = 0; jt < 8; ++jt) {
        bf16x8 bK = *(bf16x8*)&Ks[(jt*16+lm)*40 + quad*8];
        f32x4 s0 = __builtin_amdgcn_mfma_f32_16x16x32_bf16(aQ0, bK, z, 0,0,0);
        f32x4 s1 = __builtin_amdgcn_mfma_f32_16x16x32_bf16(aQ1, bK, z, 0,0,0);
        #pragma unroll
        for (int r = 0; r < 4; ++r) {
            float e0 = __expf(s0[r] - fabsf(csi0[r]-csj[jt])); ls0[r] += e0;
            float e1 = __expf(s1[r] - fabsf(csi1[r]-csj[jt])); ls1[r] += e1;
            Ps[(r0+quad*4+r)*136 + jt*16+lm] = f2bf(e0);
            Ps[(r1+quad*4+r)*136 + jt*16+lm] = f2bf(e1);
        }
    }
    #pragma unroll
    for (int r = 0; r < 4; ++r) {
        #pragma unroll
        for (int m = 1; m < 16; m <<= 1) {
            ls0[r] += __shfl_xor(ls0[r], m, 64);
            ls1[r] += __shfl_xor(ls1[r], m, 64);
        }
        if (lm == 0) { linv[r0+quad*4+r] = 1.f/ls0[r]; linv[r1+quad*4+r] = 1.f/ls1[r]; }
    }
    __syncthreads();
    f32x4 aV0 = z, aV1 = z, aW0 = z, aW1 = z;
    #pragma unroll
    for (int c = 0; c < 4; ++c) {
        bf16x8 bV  = *(bf16x8*)&Vt[lm*136 + c*32 + quad*8];
        bf16x8 bW  = *(bf16x8*)&Wt[lm*136 + c*32 + quad*8];
        bf16x8 aP0 = *(bf16x8*)&Ps[(r0+lm)*136 + c*32 + quad*8];
        bf16x8 aP1 = *(bf16x8*)&Ps[(r1+lm)*136 + c*32 + quad*8];
        aV0 = __builtin_amdgcn_mfma_f32_16x16x32_bf16(aP0, bV, aV0, 0,0,0);
        aV1 = __builtin_amdgcn_mfma_f32_16x16x32_bf16(aP1, bV, aV1, 0,0,0);
        aW0 = __builtin_amdgcn_mfma_f32_16x16x32_bf16(aP0, bW, aW0, 0,0,0);
        aW1 = __builtin_amdgcn_mfma_f32_16x16x32_bf16(aP1, bW, aW1, 0,0,0);
    }
    size_t obase = ((size_t)bn*16384 + (size_t)w*128)*16;   // [w][h][d]
    #pragma unroll
    for (int r = 0; r < 4; ++r) {
        int i0 = r0+quad*4+r, i1 = r1+quad*4+r;
        float v0 = linv[i0], v1 = linv[i1];
        vhb[obase + (size_t)i0*16 + lm] = aV0[r]*v0;
        vhb[obase + (size_t)i1*16 + lm] = aV1[r]*v1;
        o1b[obase + (size_t)i0*16 + lm] = aW0[r]*v0;
        o1b[obase + (size_t)i1*16 + lm] = aW1[r]*v1;
    }
}

// ---------------- Kernel 6: row attention pass 2 -> out2, combine + lepe (MFMA) ----------------
// block = (b,n,h). Q,K rows contiguous; V = v_h gathered from [w][h][d]; o1 gathered.
__global__ __launch_bounds__(256) void k_attn_w2(
    const float* __restrict__ qr, const float* __restrict__ kr,
    const float* __restrict__ vhb, const float* __restrict__ o1b,
    const float* __restrict__ dacs, const float* __restrict__ lepe,
    float* __restrict__ attn)
{
    __shared__ unsigned short Qs[128*40], Ks[128*40], Vt[16*136], Ps[128*136];
    __shared__ float csr[128], linv[128];
    int tid = threadIdx.x, bid = blockIdx.x;
    int h = bid & 127, n = (bid >> 7) & 3, b = bid >> 9;
    int bn = b*4 + n;
    size_t rowoff = ((size_t)(bn*128 + h)) * 2048;
    size_t vbase  = (size_t)bn*262144 + (size_t)h*16;   // vhb/o1b [w][h][d]: + j*2048 + d
    {
        int i = tid >> 1, seg = (tid & 1)*8;
        *(uint4*)&Qs[i*40 + 16 + seg] = make_uint4(0,0,0,0);
        *(uint4*)&Ks[i*40 + 16 + seg] = make_uint4(0,0,0,0);
    }
    for (int vi = tid; vi < 512; vi += 256) {
        int i = vi >> 2, d4 = (vi & 3)*4;
        float4 q = *(const float4*)&qr[rowoff + i*16 + d4];
        float4 k = *(const float4*)&kr[rowoff + i*16 + d4];
        *(uint2*)&Qs[i*40 + d4] = make_uint2(pk2(q.x,q.y), pk2(q.z,q.w));
        *(uint2*)&Ks[i*40 + d4] = make_uint2(pk2(k.x,k.y), pk2(k.z,k.w));
    }
    {
        int jp = tid >> 2, d4 = (tid & 3)*4;
        float4 a = *(const float4*)&vhb[vbase + (size_t)(2*jp)*2048 + d4];
        float4 c = *(const float4*)&vhb[vbase + (size_t)(2*jp+1)*2048 + d4];
        *(unsigned*)&Vt[(d4+0)*136 + 2*jp] = pk2(a.x, c.x);
        *(unsigned*)&Vt[(d4+1)*136 + 2*jp] = pk2(a.y, c.y);
        *(unsigned*)&Vt[(d4+2)*136 + 2*jp] = pk2(a.z, c.z);
        *(unsigned*)&Vt[(d4+3)*136 + 2*jp] = pk2(a.w, c.w);
    }
    if (tid < 128) csr[tid] = dacs[((b*128+h)*4+n)*128 + tid];
    __syncthreads();
    int lane = tid & 63, wv = tid >> 6;
    int quad = lane >> 4, lm = lane & 15;
    int r0 = wv*32, r1 = wv*32 + 16;
    bf16x8 aQ0 = *(bf16x8*)&Qs[(r0+lm)*40 + quad*8];
    bf16x8 aQ1 = *(bf16x8*)&Qs[(r1+lm)*40 + quad*8];
    float csj[8], csi0[4], csi1[4];
    #pragma unroll
    for (int jt = 0; jt < 8; ++jt) csj[jt] = csr[jt*16+lm];
    #pragma unroll
    for (int r = 0; r < 4; ++r) { csi0[r] = csr[r0+quad*4+r]; csi1[r] = csr[r1+quad*4+r]; }
    float ls0[4]={0,0,0,0}, ls1[4]={0,0,0,0};
    f32x4 z = {0.f,0.f,0.f,0.f};
    #pragma unroll
    for (int jt = 0; jt < 8; ++jt) {
        bf16x8 bK = *(bf16x8*)&Ks[(jt*16+lm)*40 + quad*8];
        f32x4 s0 = __builtin_amdgcn_mfma_f32_16x16x32_bf16(aQ0, bK, z, 0,0,0);
        f32x4 s1 = __builtin_amdgcn_mfma_f32_16x16x32_bf16(aQ1, bK, z, 0,0,0);
        #pragma unroll
        for (int r = 0; r < 4; ++r) {
            float e0 = __expf(s0[r] - fabsf(csi0[r]-csj[jt])); ls0[r] += e0;
            float e1 = __expf(s1[r] - fabsf(csi1[r]-csj[jt])); ls1[r] += e1;
            Ps[(r0+quad*4+r)*136 + jt*16+lm] = f2bf(e0);
            Ps[(r1+quad*4+r)*136 + jt*16+lm] = f2bf(e1);
        }
    }
    #pragma unroll
    for (int r = 0; r < 4; ++r) {
        #pragma unroll
        for (int m = 1; m < 16; m <<= 1) {
            ls0[r] += __shfl_xor(ls0[r], m, 64);
            ls1[r] += __shfl_xor(ls1[r], m, 64);
        }
        if (lm == 0) { linv[r0+quad*4+r] = 1.f/ls0[r]; linv[r1+quad*4+r] = 1.f/ls1[r]; }
    }
    __syncthreads();
    f32x4 acc0 = z, acc1 = z;
    #pragma unroll
    for (int c = 0; c < 4; ++c) {
        bf16x8 bV  = *(bf16x8*)&Vt[lm*136 + c*32 + quad*8];
        bf16x8 aP0 = *(bf16x8*)&Ps[(r0+lm)*136 + c*32 + quad*8];
        bf16x8 aP1 = *(bf16x8*)&Ps[(r1+lm)*136 + c*32 + quad*8];
        acc0 = __builtin_amdgcn_mfma_f32_16x16x32_bf16(aP0, bV, acc0, 0,0,0);
        acc1 = __builtin_amdgcn_mfma_f32_16x16x32_bf16(aP1, bV, acc1, 0,0,0);
    }
    size_t lpb = (size_t)bn*262144 + (size_t)h*2048;       // lepe [bn][p][d], p=h*128+i
    size_t oab = (size_t)b*1048576 + (size_t)h*8192 + n*16; // attn (b,p,c)
    #pragma unroll
    for (int r = 0; r < 4; ++r) {
        int i0 = r0+quad*4+r, i1 = r1+quad*4+r;
        float o2a = acc0[r]*linv[i0];
        float o2b = acc1[r]*linv[i1];
        float o1a = o1b[vbase + (size_t)i0*2048 + lm];
        float o1c = o1b[vbase + (size_t)i1*2048 + lm];
        float la  = lepe[lpb + (size_t)i0*16 + lm];
        float lc  = lepe[lpb + (size_t)i1*16 + lm];
        attn[oab + (size_t)i0*64 + lm] = 0.5f*(o1a + o2a) + la;
        attn[oab + (size_t)i1*64 + lm] = 0.5f*(o1c + o2b) + lc;
    }
}

// ---------------- Kernel 7: out-proj + residual + LN1 (register-tiled) ----------------
__global__ __launch_bounds__(256) void k_proj_ln(
    const float* __restrict__ attn, const float* __restrict__ x,
    const float* __restrict__ ow, const float* __restrict__ ob,
    const float* __restrict__ g1, const float* __restrict__ b1,
    float* __restrict__ t1)
{
    __shared__ float As[64*132];
    __shared__ float Bs[4096];
    int tid = threadIdx.x;
    int pbase = blockIdx.x*128;
    int b = pbase >> 14, p0 = pbase & 16383;
    for (int i = tid*4; i < 4096; i += 1024)
        *(float4*)&Bs[i] = *(const float4*)&ow[i];
    for (int vi = tid; vi < 2048; vi += 256) {
        int kk = vi & 15, p = vi >> 4;
        float4 av = *(const float4*)&attn[((size_t)(pbase+p))*64 + kk*4];
        As[(kk*4+0)*132 + p] = av.x;
        As[(kk*4+1)*132 + p] = av.y;
        As[(kk*4+2)*132 + p] = av.z;
        As[(kk*4+3)*132 + p] = av.w;
    }
    __syncthreads();
    int tc = tid & 15, tp = tid >> 4;
    float acc[8][4];
    #pragma unroll
    for (int pp = 0; pp < 8; ++pp)
        #pragma unroll
        for (int u = 0; u < 4; ++u) acc[pp][u] = 0.f;
    #pragma unroll 4
    for (int k = 0; k < 64; ++k) {
        float4 a0 = *(const float4*)&As[k*132 + tp*8];
        float4 a1 = *(const float4*)&As[k*132 + tp*8 + 4];
        float4 bv = *(const float4*)&Bs[k*64 + tc*4];
        float av8[8] = {a0.x,a0.y,a0.z,a0.w,a1.x,a1.y,a1.z,a1.w};
        float bv4[4] = {bv.x,bv.y,bv.z,bv.w};
        #pragma unroll
        for (int pp = 0; pp < 8; ++pp)
            #pragma unroll
            for (int u = 0; u < 4; ++u)
                acc[pp][u] += av8[pp]*bv4[u];
    }
    __syncthreads();
    float* outT = As;
    #pragma unroll
    for (int u = 0; u < 4; ++u)
        #pragma unroll
        for (int pp = 0; pp < 8; ++pp)
            outT[(tc*4+u)*132 + tp*8 + pp] = acc[pp][u] + ob[tc*4+u];
    __syncthreads();
    int lane = tid & 63, wv = tid >> 6;
    float gg = g1[lane], bbv = b1[lane];
    for (int it = 0; it < 32; ++it) {
        int pos = wv*32 + it;
        int P = pbase + pos;
        float r = x[((size_t)(b*64 + lane))*HWSZ + p0 + pos] + outT[lane*132 + pos];
        float s = r;
        #pragma unroll
        for (int d = 1; d < 64; d <<= 1) s += __shfl_xor(s, d, 64);
        float mean = s*(1.f/64.f);
        float df = r - mean;
        float vv = df*df;
        #pragma unroll
        for (int d = 1; d < 64; d <<= 1) vv += __shfl_xor(vv, d, 64);
        float res = df*rsqrtf(vv*(1.f/64.f) + 1e-5f)*gg + bbv;
        t1[(size_t)P*64 + lane] = res;
    }
}

// ---------------- Kernel 8a: FFN up (gelu), register-tiled ----------------
__global__ __launch_bounds__(256) void k_ffn1(
    const float* __restrict__ t1, const float* __restrict__ w1,
    const float* __restrict__ b1, float* __restrict__ hid)
{
    __shared__ float As[64*132];
    __shared__ float Bs[4096];
    int tid = threadIdx.x;
    int jq = blockIdx.x & 3;
    int pbase = (blockIdx.x >> 2)*128;
    for (int i = tid*4; i < 4096; i += 1024) {
        int k = i >> 6, j4 = i & 63;
        *(float4*)&Bs[i] = *(const float4*)&w1[k*256 + jq*64 + j4];
    }
    for (int vi = tid; vi < 2048; vi += 256) {
        int kk = vi & 15, p = vi >> 4;
        float4 av = *(const float4*)&t1[((size_t)(pbase+p))*64 + kk*4];
        As[(kk*4+0)*132 + p] = av.x;
        As[(kk*4+1)*132 + p] = av.y;
        As[(kk*4+2)*132 + p] = av.z;
        As[(kk*4+3)*132 + p] = av.w;
    }
    __syncthreads();
    int tc = tid & 15, tp = tid >> 4;
    float acc[8][4];
    #pragma unroll
    for (int pp = 0; pp < 8; ++pp)
        #pragma unroll
        for (int u = 0; u < 4; ++u) acc[pp][u] = 0.f;
    #pragma unroll 4
    for (int k = 0; k < 64; ++k) {
        float4 a0 = *(const float4*)&As[k*132 + tp*8];
        float4 a1 = *(const float4*)&As[k*132 + tp*8 + 4];
        float4 bv = *(const float4*)&Bs[k*64 + tc*4];
        float av8[8] = {a0.x,a0.y,a0.z,a0.w,a1.x,a1.y,a1.z,a1.w};
        float bv4[4] = {bv.x,bv.y,bv.z,bv.w};
        #pragma unroll
        for (int pp = 0; pp < 8; ++pp)
            #pragma unroll
            for (int u = 0; u < 4; ++u)
                acc[pp][u] += av8[pp]*bv4[u];
    }
    float bb[4];
    #pragma unroll
    for (int u = 0; u < 4; ++u) bb[u] = b1[jq*64 + tc*4 + u];
    #pragma unroll
    for (int pp = 0; pp < 8; ++pp) {
        float4 o;
        o.x = gelu_f(acc[pp][0] + bb[0]);
        o.y = gelu_f(acc[pp][1] + bb[1]);
        o.z = gelu_f(acc[pp][2] + bb[2]);
        o.w = gelu_f(acc[pp][3] + bb[3]);
        *(float4*)&hid[((size_t)(pbase + tp*8 + pp))*256 + jq*64 + tc*4] = o;
    }
}

// ---------------- Kernel 8b: FFN down + residual + LN2 + transpose ----------------
__global__ __launch_bounds__(256) void k_ffn2(
    const float* __restrict__ hid, const float* __restrict__ t1,
    const float* __restrict__ w2, const float* __restrict__ b2,
    const float* __restrict__ g2, const float* __restrict__ bb2,
    float* __restrict__ outp)
{
    __shared__ float As[64*132];
    __shared__ float Bs[4096];
    int tid = threadIdx.x;
    int pbase = blockIdx.x*128;
    int b = pbase >> 14, p0 = pbase & 16383;
    int tc = tid & 15, tp = tid >> 4;
    float acc[8][4];
    #pragma unroll
    for (int pp = 0; pp < 8; ++pp)
        #pragma unroll
        for (int u = 0; u < 4; ++u) acc[pp][u] = 0.f;
    for (int kc = 0; kc < 4; ++kc) {
        __syncthreads();
        for (int i = tid*4; i < 4096; i += 1024)
            *(float4*)&Bs[i] = *(const float4*)&w2[kc*4096 + i];
        for (int vi = tid; vi < 2048; vi += 256) {
            int kk = vi & 15, p = vi >> 4;
            float4 av = *(const float4*)&hid[((size_t)(pbase+p))*256 + kc*64 + kk*4];
            As[(kk*4+0)*132 + p] = av.x;
            As[(kk*4+1)*132 + p] = av.y;
            As[(kk*4+2)*132 + p] = av.z;
            As[(kk*4+3)*132 + p] = av.w;
        }
        __syncthreads();
        #pragma unroll 4
        for (int k = 0; k < 64; ++k) {
            float4 a0 = *(const float4*)&As[k*132 + tp*8];
            float4 a1 = *(const float4*)&As[k*132 + tp*8 + 4];
            float4 bv = *(const float4*)&Bs[k*64 + tc*4];
            float av8[8] = {a0.x,a0.y,a0.z,a0.w,a1.x,a1.y,a1.z,a1.w};
            float bv4[4] = {bv.x,bv.y,bv.z,bv.w};
            #pragma unroll
            for (int pp = 0; pp < 8; ++pp)
                #pragma unroll
                for (int u = 0; u < 4; ++u)
                    acc[pp][u] += av8[pp]*bv4[u];
        }
    }
    __syncthreads();
    float* outT = As;
    #pragma unroll
    for (int u = 0; u < 4; ++u)
        #pragma unroll
        for (int pp = 0; pp < 8; ++pp)
            outT[(tc*4+u)*132 + tp*8 + pp] = acc[pp][u] + b2[tc*4+u];
    __syncthreads();
    int lane = tid & 63, wv = tid >> 6;
    {
        float gg = g2[lane], bbv = bb2[lane];
        for (int it = 0; it < 8; ++it) {
            int pos = wv*8 + it;
            // spread: 4 waves x 32 pos handled as wv*32.. but keep original mapping
        }
        for (int it = 0; it < 32; ++it) {
            int pos = wv*32 + it;
            int P = pbase + pos;
            float r = t1[(size_t)P*64 + lane] + outT[lane*132 + pos];
            float s = r;
            #pragma unroll
            for (int d = 1; d < 64; d <<= 1) s += __shfl_xor(s, d, 64);
            float mean = s*(1.f/64.f);
            float df = r - mean;
            float vv = df*df;
            #pragma unroll
            for (int d = 1; d < 64; d <<= 1) vv += __shfl_xor(vv, d, 64);
            float res = df*rsqrtf(vv*(1.f/64.f) + 1e-5f)*gg + bbv;
            outT[lane*132 + pos] = res;
        }
    }
    __syncthreads();
    for (int vi = tid; vi < 2048; vi += 256) {
        int c = vi >> 5, p4 = (vi & 31)*4;
        float4 ov = *(const float4*)&outT[c*132 + p4];
        *(float4*)&outp[((size_t)(b*64 + c))*HWSZ + p0 + p4] = ov;
    }
}

extern "C" void kernel_launch(void* const* d_in, const int* in_sizes, int n_in,
                              void* d_out, int out_size, void* d_ws, size_t ws_size,
                              hipStream_t stream) {
    const float* x      = (const float*)d_in[0];
    const float* y      = (const float*)d_in[1];
    const float* th     = (const float*)d_in[2];
    const float* dw1_w  = (const float*)d_in[3];
    const float* dw1_b  = (const float*)d_in[4];
    const float* dw2_w  = (const float*)d_in[5];
    const float* dw2_b  = (const float*)d_in[6];
    const float* qw     = (const float*)d_in[7];
    const float* qb     = (const float*)d_in[8];
    const float* kw     = (const float*)d_in[9];
    const float* kb     = (const float*)d_in[10];
    const float* vw     = (const float*)d_in[11];
    const float* vb     = (const float*)d_in[12];
    const float* lepe_w = (const float*)d_in[13];
    const float* lepe_b = (const float*)d_in[14];
    const float* dt_w   = (const float*)d_in[15];
    const float* dt_bias= (const float*)d_in[16];
    const float* A_log  = (const float*)d_in[17];
    const float* ow     = (const float*)d_in[18];
    const float* ob     = (const float*)d_in[19];
    const float* n1_g   = (const float*)d_in[20];
    const float* n1_b   = (const float*)d_in[21];
    const float* ffn_w1 = (const float*)d_in[22];
    const float* ffn_b1 = (const float*)d_in[23];
    const float* ffn_w2 = (const float*)d_in[24];
    const float* ffn_b2 = (const float*)d_in[25];
    const float* n2_g   = (const float*)d_in[26];
    const float* n2_b   = (const float*)d_in[27];
    float* out = (float*)d_out;

    const size_t SZ = 4194304;   // B*C*H*W elements
    float* ws    = (float*)d_ws;
    float* fused = ws + 0*SZ;    // reused as v_w after kernel 4
    float* qrb   = ws + 1*SZ;
    float* krb   = ws + 2*SZ;
    float* v5b   = ws + 3*SZ;
    float* lepeb = ws + 4*SZ;
    float* vhb   = ws + 5*SZ;
    float* o1b   = ws + 6*SZ;
    float* attnb = ws + 7*SZ;
    float* t1b   = ws + 8*SZ;
    float* dacs  = ws + 9*SZ;               // 262144
    float* dbcs  = ws + 9*SZ + 262144;      // 262144
    float* hidb  = ws + 1*SZ;               // reuse qr..lepe region (4*SZ)

    k_fuse<<<256, 256, 0, stream>>>(y, th, dw1_w, dw1_b, dw2_w, dw2_b, fused);
    k_qkv<<<1024, 256, 0, stream>>>(x, fused, qw, qb, kw, kb, vw, vb,
                                    dt_w, dt_bias, A_log, qrb, krb, v5b, dacs, dbcs);
    k_cumsum<<<1024, 256, 0, stream>>>(dacs, dbcs);
    k_lepe<<<512, 256, 0, stream>>>(v5b, lepe_w, lepe_b, lepeb);
    k_attn_w1<<<2048, 256, 0, stream>>>(qrb, krb, v5b, dacs, fused);
    k_attn_h<<<2048, 256, 0, stream>>>(qrb, krb, v5b, fused, dbcs, vhb, o1b);
    k_attn_w2<<<2048, 256, 0, stream>>>(qrb, krb, vhb, o1b, dacs, lepeb, attnb);
    k_proj_ln<<<512, 256, 0, stream>>>(attnb, x, ow, ob, n1_g, n1_b, t1b);
    k_ffn1<<<2048, 256, 0, stream>>>(t1b, ffn_w1, ffn_b1, hidb);
    k_ffn2<<<512, 256, 0, stream>>>(hidb, t1b, ffn_w2, ffn_b2, n2_g, n2_b, out);
}

// Round 5
// 424.175 us; speedup vs baseline: 2.5716x; 1.1234x over previous
//
#include <hip/hip_runtime.h>
#include <math.h>

#define HWSZ 16384

typedef __attribute__((ext_vector_type(8))) short bf16x8;
typedef __attribute__((ext_vector_type(4))) float f32x4;

__device__ __forceinline__ float gelu_f(float v) {
    return 0.5f * v * (1.0f + erff(v * 0.70710678118654752f));
}
__device__ __forceinline__ float splus_f(float v) {
    return (v > 20.f) ? v : log1pf(expf(v));
}
__device__ __forceinline__ unsigned short f2bf(float f) {
    union { float f; unsigned u; } v; v.f = f;
    unsigned r = (v.u + 0x7FFF + ((v.u >> 16) & 1)) >> 16;
    return (unsigned short)r;
}
__device__ __forceinline__ unsigned pk2(float a, float b) {
    return (unsigned)f2bf(a) | ((unsigned)f2bf(b) << 16);
}
__device__ __forceinline__ float bf2f(unsigned short s) {
    union { unsigned u; float f; } v; v.u = ((unsigned)s) << 16; return v.f;
}

// ---------------- Kernel 1: fusion gate (LDS-tiled, 64 pos/block) ----------------
// grid 1024. lane = oc*16+po handles 16 hidden ch for pos = wv*16+po.
#define W1S 68
__global__ __launch_bounds__(256) void k_fuse(
    const float* __restrict__ y, const float* __restrict__ th,
    const float* __restrict__ w1, const float* __restrict__ b1,
    const float* __restrict__ w2, const float* __restrict__ b2,
    float* __restrict__ fused)
{
    __shared__ unsigned short fsh[8192];   // [c][pos] bf16, c 0..63=y, 64..127=th
    __shared__ float w1t[128*W1S];         // [c][o], stride 68 (16B-aligned)
    int tid = threadIdx.x;
    int g = blockIdx.x;
    int b = g >> 8;
    int p0 = (g & 255)*64;
    for (int i = tid; i < 8192; i += 256) {
        int o = i >> 7, c = i & 127;
        w1t[c*W1S + o] = w1[i];            // global coalesced; LDS 8-way (128 instrs, cheap)
    }
    for (int vi = tid; vi < 1024; vi += 256) {
        int c = vi >> 4, p4 = (vi & 15)*4;
        float4 yv = *(const float4*)&y [((size_t)(b*64+c))*HWSZ + p0 + p4];
        float4 tv = *(const float4*)&th[((size_t)(b*64+c))*HWSZ + p0 + p4];
        *(uint2*)&fsh[c*64 + p4]      = make_uint2(pk2(yv.x,yv.y), pk2(yv.z,yv.w));
        *(uint2*)&fsh[(64+c)*64 + p4] = make_uint2(pk2(tv.x,tv.y), pk2(tv.z,tv.w));
    }
    __syncthreads();
    int lane = tid & 63, wv = tid >> 6;
    int po = lane & 15, oc = lane >> 4;
    int pos = wv*16 + po;
    float acc[16];
    #pragma unroll
    for (int d4 = 0; d4 < 4; ++d4) {
        float4 bv = *(const float4*)&b1[oc*16 + d4*4];
        acc[d4*4+0]=bv.x; acc[d4*4+1]=bv.y; acc[d4*4+2]=bv.z; acc[d4*4+3]=bv.w;
    }
    for (int c = 0; c < 128; ++c) {
        float xc = bf2f(fsh[c*64 + pos]);
        #pragma unroll
        for (int d4 = 0; d4 < 4; ++d4) {
            float4 wv4 = *(const float4*)&w1t[c*W1S + oc*16 + d4*4];
            acc[d4*4+0] += wv4.x*xc; acc[d4*4+1] += wv4.y*xc;
            acc[d4*4+2] += wv4.z*xc; acc[d4*4+3] += wv4.w*xc;
        }
    }
    float l0 = 0.f, l1 = 0.f;
    #pragma unroll
    for (int d4 = 0; d4 < 4; ++d4) {
        float4 wa4 = *(const float4*)&w2[oc*16 + d4*4];
        float4 wb4 = *(const float4*)&w2[64 + oc*16 + d4*4];
        float h0 = fmaxf(acc[d4*4+0],0.f), h1 = fmaxf(acc[d4*4+1],0.f);
        float h2 = fmaxf(acc[d4*4+2],0.f), h3 = fmaxf(acc[d4*4+3],0.f);
        l0 += wa4.x*h0 + wa4.y*h1 + wa4.z*h2 + wa4.w*h3;
        l1 += wb4.x*h0 + wb4.y*h1 + wb4.z*h2 + wb4.w*h3;
    }
    l0 += __shfl_xor(l0, 16, 64); l0 += __shfl_xor(l0, 32, 64);
    l1 += __shfl_xor(l1, 16, 64); l1 += __shfl_xor(l1, 32, 64);
    l0 += b2[0]; l1 += b2[1];
    float m = fmaxf(l0, l1);
    float e0 = __expf(l0 - m), e1 = __expf(l1 - m);
    float inv = 1.f/(e0 + e1);
    float wa = e0*inv, wb = e1*inv;
    float* fb = fused + (size_t)b*64*HWSZ + p0 + pos;
    #pragma unroll
    for (int u = 0; u < 16; ++u) {
        int c = oc*16 + u;
        float fv = bf2f(fsh[c*64 + pos])*wa + bf2f(fsh[(64+c)*64 + pos])*wb;
        fb[(size_t)c*HWSZ] = fv;
    }
}

// ---------------- Kernel 2: QKV + RoPE + dt ----------------
__global__ __launch_bounds__(256) void k_qkv(
    const float* __restrict__ x, const float* __restrict__ fused,
    const float* __restrict__ qw, const float* __restrict__ qb,
    const float* __restrict__ kw, const float* __restrict__ kb,
    const float* __restrict__ vw, const float* __restrict__ vb,
    const float* __restrict__ dtw, const float* __restrict__ dtb,
    const float* __restrict__ alog,
    float* __restrict__ qr, float* __restrict__ kr, float* __restrict__ v5,
    float* __restrict__ da, float* __restrict__ db)
{
    __shared__ float sw[12288];          // qw | kw | vw, each [c][o]
    __shared__ float sx[4096];           // [c][pos], 64x64
    int tid = threadIdx.x;
    for (int i = tid*4; i < 4096; i += 1024) {
        *(float4*)&sw[i]      = *(const float4*)&qw[i];
        *(float4*)&sw[4096+i] = *(const float4*)&kw[i];
        *(float4*)&sw[8192+i] = *(const float4*)&vw[i];
    }
    int b  = blockIdx.x >> 8;
    int p0 = (blockIdx.x & 255)*64;
    for (int vi = tid; vi < 1024; vi += 256) {
        int c = vi >> 4, p4 = (vi & 15)*4;
        *(float4*)&sx[c*64 + p4] = *(const float4*)&x[((size_t)(b*64+c))*HWSZ + p0 + p4];
    }
    __syncthreads();
    int lane = tid & 63;
    int n = tid >> 6;
    int p = p0 + lane;
    int h = p >> 7, w = p & 127;
    float sn[8], cn[8];
    #pragma unroll
    for (int t = 0; t < 8; ++t) {
        float ang = exp2f(-1.89824462565f * (float)t);   // 10000^(-t/7)
        sincosf((float)p * ang, &sn[t], &cn[t]);
    }
    float a[16];
    // ---- Q head n ----
    #pragma unroll
    for (int d = 0; d < 16; ++d) a[d] = qb[n*16+d];
    for (int c = 0; c < 64; ++c) {
        float xc = sx[c*64 + lane];
        #pragma unroll
        for (int d4 = 0; d4 < 4; ++d4) {
            float4 wv = *(const float4*)&sw[c*64 + n*16 + d4*4];
            a[d4*4+0] += wv.x*xc; a[d4*4+1] += wv.y*xc;
            a[d4*4+2] += wv.z*xc; a[d4*4+3] += wv.w*xc;
        }
    }
    {
        float r[16];
        #pragma unroll
        for (int t = 0; t < 8; ++t) {
            r[2*t]   = a[2*t]*cn[t]   - a[2*t+1]*sn[t];
            r[2*t+1] = a[2*t+1]*cn[t] + a[2*t]*sn[t];
        }
        float* dst = qr + (((size_t)(b*4+n))*HWSZ + p)*16;
        #pragma unroll
        for (int d4 = 0; d4 < 4; ++d4)
            *(float4*)&dst[d4*4] = make_float4(r[d4*4],r[d4*4+1],r[d4*4+2],r[d4*4+3]);
    }
    // ---- dt / da / db ----
    {
        float dt0 = 0.f, dt1 = 0.f;
        #pragma unroll
        for (int d = 0; d < 16; ++d) {
            float xv = sx[(n*16+d)*64 + lane];
            dt0 += xv*dtw[2*d];
            dt1 += xv*dtw[2*d+1];
        }
        float A  = -expf(alog[n]);
        float bb = dtb[n];
        da[((b*128+h)*4+n)*128 + w] = splus_f(dt0+bb)*A;
        db[((b*128+w)*4+n)*128 + h] = splus_f(dt1+bb)*A;
    }
    __syncthreads();
    for (int vi = tid; vi < 1024; vi += 256) {
        int c = vi >> 4, p4 = (vi & 15)*4;
        *(float4*)&sx[c*64 + p4] = *(const float4*)&fused[((size_t)(b*64+c))*HWSZ + p0 + p4];
    }
    __syncthreads();
    // ---- K head n (scaled 0.25, RoPE) ----
    #pragma unroll
    for (int d = 0; d < 16; ++d) a[d] = kb[n*16+d];
    for (int c = 0; c < 64; ++c) {
        float xc = sx[c*64 + lane];
        #pragma unroll
        for (int d4 = 0; d4 < 4; ++d4) {
            float4 wv = *(const float4*)&sw[4096 + c*64 + n*16 + d4*4];
            a[d4*4+0] += wv.x*xc; a[d4*4+1] += wv.y*xc;
            a[d4*4+2] += wv.z*xc; a[d4*4+3] += wv.w*xc;
        }
    }
    {
        float r[16];
        #pragma unroll
        for (int t = 0; t < 8; ++t) {
            float e = a[2*t]*0.25f, o = a[2*t+1]*0.25f;
            r[2*t]   = e*cn[t] - o*sn[t];
            r[2*t+1] = o*cn[t] + e*sn[t];
        }
        float* dst = kr + (((size_t)(b*4+n))*HWSZ + p)*16;
        #pragma unroll
        for (int d4 = 0; d4 < 4; ++d4)
            *(float4*)&dst[d4*4] = make_float4(r[d4*4],r[d4*4+1],r[d4*4+2],r[d4*4+3]);
    }
    // ---- V head n ----
    #pragma unroll
    for (int d = 0; d < 16; ++d) a[d] = vb[n*16+d];
    for (int c = 0; c < 64; ++c) {
        float xc = sx[c*64 + lane];
        #pragma unroll
        for (int d4 = 0; d4 < 4; ++d4) {
            float4 wv = *(const float4*)&sw[8192 + c*64 + n*16 + d4*4];
            a[d4*4+0] += wv.x*xc; a[d4*4+1] += wv.y*xc;
            a[d4*4+2] += wv.z*xc; a[d4*4+3] += wv.w*xc;
        }
    }
    {
        float* dst = v5 + (((size_t)(b*4+n))*HWSZ + p)*16;
        #pragma unroll
        for (int d4 = 0; d4 < 4; ++d4)
            *(float4*)&dst[d4*4] = make_float4(a[d4*4],a[d4*4+1],a[d4*4+2],a[d4*4+3]);
    }
}

// ---------------- Kernel 2b: cumsums ----------------
__global__ __launch_bounds__(256) void k_cumsum(float* __restrict__ da, float* __restrict__ db)
{
    int gw = (blockIdx.x*256 + threadIdx.x) >> 6;   // 0..4095
    int lane = threadIdx.x & 63;
    float* base = (gw < 2048) ? (da + (size_t)gw*128) : (db + (size_t)(gw-2048)*128);
    float2 e = *(float2*)&base[lane*2];
    float s = e.x + e.y;
    #pragma unroll
    for (int d = 1; d < 64; d <<= 1) {
        float t = __shfl_up(s, d, 64);
        if (lane >= d) s += t;
    }
    float excl = s - (e.x + e.y);
    float2 o;
    o.x = excl + e.x;
    o.y = excl + e.x + e.y;
    *(float2*)&base[lane*2] = o;
}

// ---------------- Kernel 3: LePE depthwise 5x5 conv, LDS-tiled ----------------
#define LROW 328
__global__ __launch_bounds__(256) void k_lepe(
    const float* __restrict__ v5, const float* __restrict__ lw,
    const float* __restrict__ lb, float* __restrict__ lepe)
{
    __shared__ float sv[36*LROW];
    __shared__ float swt[400];
    int tid = threadIdx.x, bid = blockIdx.x;
    int tw = bid & 7, th_ = (bid >> 3) & 3, n = (bid >> 5) & 3, b = bid >> 7;
    int bn = b*4 + n;
    int h0 = th_*32, w0 = tw*16;
    for (int i = tid; i < 400; i += 256) {
        int tap = i >> 4, d = i & 15;
        swt[i] = lw[tap*64 + n*16 + d];
    }
    const float* vb = v5 + (size_t)bn*HWSZ*16;
    for (int vi = tid; vi < 2880; vi += 256) {
        int hh = vi / 80;
        int rem = vi - hh*80;
        int ww = rem >> 2, df = (rem & 3)*4;
        int h = h0 - 2 + hh, w = w0 - 2 + ww;
        float4 val = make_float4(0.f,0.f,0.f,0.f);
        if (h >= 0 && h < 128 && w >= 0 && w < 128)
            val = *(const float4*)&vb[((size_t)(h*128+w))*16 + df];
        *(float4*)&sv[hh*LROW + ww*16 + df] = val;
    }
    __syncthreads();
    int df = (tid & 3)*4;
    int s  = tid >> 2;
    int ph = s >> 1;
    int pw = (s & 1)*8;
    float4 bv = *(const float4*)&lb[n*16 + df];
    float acc[8][4];
    #pragma unroll
    for (int ow = 0; ow < 8; ++ow) {
        acc[ow][0] = bv.x; acc[ow][1] = bv.y; acc[ow][2] = bv.z; acc[ow][3] = bv.w;
    }
    #pragma unroll
    for (int ky = 0; ky < 5; ++ky) {
        float wgt[5][4];
        #pragma unroll
        for (int kx = 0; kx < 5; ++kx) {
            float4 wv = *(const float4*)&swt[(ky*5+kx)*16 + df];
            wgt[kx][0]=wv.x; wgt[kx][1]=wv.y; wgt[kx][2]=wv.z; wgt[kx][3]=wv.w;
        }
        float dat[13][4];
        #pragma unroll
        for (int c = 0; c < 13; ++c) {
            float4 dv = *(const float4*)&sv[(ph+ky)*LROW + (pw+c)*16 + df];
            dat[c][0]=dv.x; dat[c][1]=dv.y; dat[c][2]=dv.z; dat[c][3]=dv.w;
        }
        #pragma unroll
        for (int ow = 0; ow < 8; ++ow)
            #pragma unroll
            for (int kx = 0; kx < 5; ++kx)
                #pragma unroll
                for (int u = 0; u < 4; ++u)
                    acc[ow][u] += dat[ow+kx][u]*wgt[kx][u];
    }
    float* ob = lepe + ((size_t)bn*HWSZ + (size_t)(h0+ph)*128 + w0+pw)*16 + df;
    #pragma unroll
    for (int ow = 0; ow < 8; ++ow)
        *(float4*)&ob[ow*16] = make_float4(acc[ow][0],acc[ow][1],acc[ow][2],acc[ow][3]);
}

// ---------------- Kernel 4: row attention pass 1 -> v_w (MFMA) ----------------
__global__ __launch_bounds__(256) void k_attn_w1(
    const float* __restrict__ qr, const float* __restrict__ kr,
    const float* __restrict__ v5, const float* __restrict__ dacs,
    float* __restrict__ vwb)
{
    __shared__ unsigned short Qs[128*40], Ks[128*40], Vt[16*136], Ps[128*136];
    __shared__ float csr[128], linv[128];
    int tid = threadIdx.x, bid = blockIdx.x;
    int h = bid & 127, n = (bid >> 7) & 3, b = bid >> 9;
    size_t rowoff = ((size_t)((b*4+n)*128 + h)) * 2048;
    {   // zero pad k=16..31
        int i = tid >> 1, seg = (tid & 1)*8;
        *(uint4*)&Qs[i*40 + 16 + seg] = make_uint4(0,0,0,0);
        *(uint4*)&Ks[i*40 + 16 + seg] = make_uint4(0,0,0,0);
    }
    for (int vi = tid; vi < 512; vi += 256) {
        int i = vi >> 2, d4 = (vi & 3)*4;
        float4 q = *(const float4*)&qr[rowoff + i*16 + d4];
        float4 k = *(const float4*)&kr[rowoff + i*16 + d4];
        *(uint2*)&Qs[i*40 + d4] = make_uint2(pk2(q.x,q.y), pk2(q.z,q.w));
        *(uint2*)&Ks[i*40 + d4] = make_uint2(pk2(k.x,k.y), pk2(k.z,k.w));
    }
    {   // V^T staging: pairs of rows
        int jp = tid >> 2, d4 = (tid & 3)*4;
        float4 a = *(const float4*)&v5[rowoff + (2*jp)*16 + d4];
        float4 c = *(const float4*)&v5[rowoff + (2*jp+1)*16 + d4];
        *(unsigned*)&Vt[(d4+0)*136 + 2*jp] = pk2(a.x, c.x);
        *(unsigned*)&Vt[(d4+1)*136 + 2*jp] = pk2(a.y, c.y);
        *(unsigned*)&Vt[(d4+2)*136 + 2*jp] = pk2(a.z, c.z);
        *(unsigned*)&Vt[(d4+3)*136 + 2*jp] = pk2(a.w, c.w);
    }
    if (tid < 128) csr[tid] = dacs[((b*128+h)*4+n)*128 + tid];
    __syncthreads();
    int lane = tid & 63, wv = tid >> 6;
    int quad = lane >> 4, lm = lane & 15;
    int r0 = wv*32, r1 = wv*32 + 16;
    bf16x8 aQ0 = *(bf16x8*)&Qs[(r0+lm)*40 + quad*8];
    bf16x8 aQ1 = *(bf16x8*)&Qs[(r1+lm)*40 + quad*8];
    float csj[8], csi0[4], csi1[4];
    #pragma unroll
    for (int jt = 0; jt < 8; ++jt) csj[jt] = csr[jt*16+lm];
    #pragma unroll
    for (int r = 0; r < 4; ++r) { csi0[r] = csr[r0+quad*4+r]; csi1[r] = csr[r1+quad*4+r]; }
    float ls0[4]={0,0,0,0}, ls1[4]={0,0,0,0};
    f32x4 z = {0.f,0.f,0.f,0.f};
    #pragma unroll
    for (int jt = 0; jt < 8; ++jt) {
        bf16x8 bK = *(bf16x8*)&Ks[(jt*16+lm)*40 + quad*8];
        f32x4 s0 = __builtin_amdgcn_mfma_f32_16x16x32_bf16(aQ0, bK, z, 0,0,0);
        f32x4 s1 = __builtin_amdgcn_mfma_f32_16x16x32_bf16(aQ1, bK, z, 0,0,0);
        #pragma unroll
        for (int r = 0; r < 4; ++r) {
            float e0 = __expf(s0[r] - fabsf(csi0[r]-csj[jt])); ls0[r] += e0;
            float e1 = __expf(s1[r] - fabsf(csi1[r]-csj[jt])); ls1[r] += e1;
            Ps[(r0+quad*4+r)*136 + jt*16+lm] = f2bf(e0);
            Ps[(r1+quad*4+r)*136 + jt*16+lm] = f2bf(e1);
        }
    }
    #pragma unroll
    for (int r = 0; r < 4; ++r) {
        #pragma unroll
        for (int m = 1; m < 16; m <<= 1) {
            ls0[r] += __shfl_xor(ls0[r], m, 64);
            ls1[r] += __shfl_xor(ls1[r], m, 64);
        }
        if (lm == 0) { linv[r0+quad*4+r] = 1.f/ls0[r]; linv[r1+quad*4+r] = 1.f/ls1[r]; }
    }
    __syncthreads();
    f32x4 acc0 = z, acc1 = z;
    #pragma unroll
    for (int c = 0; c < 4; ++c) {
        bf16x8 bV  = *(bf16x8*)&Vt[lm*136 + c*32 + quad*8];
        bf16x8 aP0 = *(bf16x8*)&Ps[(r0+lm)*136 + c*32 + quad*8];
        bf16x8 aP1 = *(bf16x8*)&Ps[(r1+lm)*136 + c*32 + quad*8];
        acc0 = __builtin_amdgcn_mfma_f32_16x16x32_bf16(aP0, bV, acc0, 0,0,0);
        acc1 = __builtin_amdgcn_mfma_f32_16x16x32_bf16(aP1, bV, acc1, 0,0,0);
    }
    #pragma unroll
    for (int r = 0; r < 4; ++r) {
        int i0 = r0+quad*4+r, i1 = r1+quad*4+r;
        vwb[rowoff + (size_t)i0*16 + lm] = acc0[r]*linv[i0];
        vwb[rowoff + (size_t)i1*16 + lm] = acc1[r]*linv[i1];
    }
}

// ---------------- Kernel 5: column attention -> v_h and out1 (MFMA) ----------------
__global__ __launch_bounds__(256) void k_attn_h(
    const float* __restrict__ qr, const float* __restrict__ kr,
    const float* __restrict__ v5, const float* __restrict__ vwb,
    const float* __restrict__ dbcs,
    float* __restrict__ vhb, float* __restrict__ o1b)
{
    __shared__ unsigned short Qs[128*40], Ks[128*40], Vt[16*136], Wt[16*136], Ps[128*136];
    __shared__ float csr[128], linv[128];
    int tid = threadIdx.x, bid = blockIdx.x;
    int w = bid & 127, n = (bid >> 7) & 3, b = bid >> 9;
    int bn = b*4 + n;
    size_t base = ((size_t)bn*16384 + w)*16;     // element (h=0, d=0); h-stride 2048
    {
        int i = tid >> 1, seg = (tid & 1)*8;
        *(uint4*)&Qs[i*40 + 16 + seg] = make_uint4(0,0,0,0);
        *(uint4*)&Ks[i*40 + 16 + seg] = make_uint4(0,0,0,0);
    }
    for (int vi = tid; vi < 512; vi += 256) {
        int i = vi >> 2, d4 = (vi & 3)*4;
        float4 q = *(const float4*)&qr[base + (size_t)i*2048 + d4];
        float4 k = *(const float4*)&kr[base + (size_t)i*2048 + d4];
        *(uint2*)&Qs[i*40 + d4] = make_uint2(pk2(q.x,q.y), pk2(q.z,q.w));
        *(uint2*)&Ks[i*40 + d4] = make_uint2(pk2(k.x,k.y), pk2(k.z,k.w));
    }
    {
        int jp = tid >> 2, d4 = (tid & 3)*4;
        float4 a = *(const float4*)&v5[base + (size_t)(2*jp)*2048 + d4];
        float4 c = *(const float4*)&v5[base + (size_t)(2*jp+1)*2048 + d4];
        *(unsigned*)&Vt[(d4+0)*136 + 2*jp] = pk2(a.x, c.x);
        *(unsigned*)&Vt[(d4+1)*136 + 2*jp] = pk2(a.y, c.y);
        *(unsigned*)&Vt[(d4+2)*136 + 2*jp] = pk2(a.z, c.z);
        *(unsigned*)&Vt[(d4+3)*136 + 2*jp] = pk2(a.w, c.w);
        float4 e = *(const float4*)&vwb[base + (size_t)(2*jp)*2048 + d4];
        float4 f = *(const float4*)&vwb[base + (size_t)(2*jp+1)*2048 + d4];
        *(unsigned*)&Wt[(d4+0)*136 + 2*jp] = pk2(e.x, f.x);
        *(unsigned*)&Wt[(d4+1)*136 + 2*jp] = pk2(e.y, f.y);
        *(unsigned*)&Wt[(d4+2)*136 + 2*jp] = pk2(e.z, f.z);
        *(unsigned*)&Wt[(d4+3)*136 + 2*jp] = pk2(e.w, f.w);
    }
    if (tid < 128) csr[tid] = dbcs[((b*128+w)*4+n)*128 + tid];
    __syncthreads();
    int lane = tid & 63, wv = tid >> 6;
    int quad = lane >> 4, lm = lane & 15;
    int r0 = wv*32, r1 = wv*32 + 16;
    bf16x8 aQ0 = *(bf16x8*)&Qs[(r0+lm)*40 + quad*8];
    bf16x8 aQ1 = *(bf16x8*)&Qs[(r1+lm)*40 + quad*8];
    float csj[8], csi0[4], csi1[4];
    #pragma unroll
    for (int jt = 0; jt < 8; ++jt) csj[jt] = csr[jt*16+lm];
    #pragma unroll
    for (int r = 0; r < 4; ++r) { csi0[r] = csr[r0+quad*4+r]; csi1[r] = csr[r1+quad*4+r]; }
    float ls0[4]={0,0,0,0}, ls1[4]={0,0,0,0};
    f32x4 z = {0.f,0.f,0.f,0.f};
    #pragma unroll
    for (int jt = 0; jt < 8; ++jt) {
        bf16x8 bK = *(bf16x8*)&Ks[(jt*16+lm)*40 + quad*8];
        f32x4 s0 = __builtin_amdgcn_mfma_f32_16x16x32_bf16(aQ0, bK, z, 0,0,0);
        f32x4 s1 = __builtin_amdgcn_mfma_f32_16x16x32_bf16(aQ1, bK, z, 0,0,0);
        #pragma unroll
        for (int r = 0; r < 4; ++r) {
            float e0 = __expf(s0[r] - fabsf(csi0[r]-csj[jt])); ls0[r] += e0;
            float e1 = __expf(s1[r] - fabsf(csi1[r]-csj[jt])); ls1[r] += e1;
            Ps[(r0+quad*4+r)*136 + jt*16+lm] = f2bf(e0);
            Ps[(r1+quad*4+r)*136 + jt*16+lm] = f2bf(e1);
        }
    }
    #pragma unroll
    for (int r = 0; r < 4; ++r) {
        #pragma unroll
        for (int m = 1; m < 16; m <<= 1) {
            ls0[r] += __shfl_xor(ls0[r], m, 64);
            ls1[r] += __shfl_xor(ls1[r], m, 64);
        }
        if (lm == 0) { linv[r0+quad*4+r] = 1.f/ls0[r]; linv[r1+quad*4+r] = 1.f/ls1[r]; }
    }
    __syncthreads();
    f32x4 aV0 = z, aV1 = z, aW0 = z, aW1 = z;
    #pragma unroll
    for (int c = 0; c < 4; ++c) {
        bf16x8 bV  = *(bf16x8*)&Vt[lm*136 + c*32 + quad*8];
        bf16x8 bW  = *(bf16x8*)&Wt[lm*136 + c*32 + quad*8];
        bf16x8 aP0 = *(bf16x8*)&Ps[(r0+lm)*136 + c*32 + quad*8];
        bf16x8 aP1 = *(bf16x8*)&Ps[(r1+lm)*136 + c*32 + quad*8];
        aV0 = __builtin_amdgcn_mfma_f32_16x16x32_bf16(aP0, bV, aV0, 0,0,0);
        aV1 = __builtin_amdgcn_mfma_f32_16x16x32_bf16(aP1, bV, aV1, 0,0,0);
        aW0 = __builtin_amdgcn_mfma_f32_16x16x32_bf16(aP0, bW, aW0, 0,0,0);
        aW1 = __builtin_amdgcn_mfma_f32_16x16x32_bf16(aP1, bW, aW1, 0,0,0);
    }
    size_t obase = ((size_t)bn*16384 + (size_t)w*128)*16;   // [w][h][d]
    #pragma unroll
    for (int r = 0; r < 4; ++r) {
        int i0 = r0+quad*4+r, i1 = r1+quad*4+r;
        float v0 = linv[i0], v1 = linv[i1];
        vhb[obase + (size_t)i0*16 + lm] = aV0[r]*v0;
        vhb[obase + (size_t)i1*16 + lm] = aV1[r]*v1;
        o1b[obase + (size_t)i0*16 + lm] = aW0[r]*v0;
        o1b[obase + (size_t)i1*16 + lm] = aW1[r]*v1;
    }
}

// ---------------- Kernel 6: row attention pass 2 -> out2, combine + lepe (MFMA) ----------------
__global__ __launch_bounds__(256) void k_attn_w2(
    const float* __restrict__ qr, const float* __restrict__ kr,
    const float* __restrict__ vhb, const float* __restrict__ o1b,
    const float* __restrict__ dacs, const float* __restrict__ lepe,
    float* __restrict__ attn)
{
    __shared__ unsigned short Qs[128*40], Ks[128*40], Vt[16*136], Ps[128*136];
    __shared__ float csr[128], linv[128];
    int tid = threadIdx.x, bid = blockIdx.x;
    int h = bid & 127, n = (bid >> 7) & 3, b = bid >> 9;
    int bn = b*4 + n;
    size_t rowoff = ((size_t)(bn*128 + h)) * 2048;
    size_t vbase  = (size_t)bn*262144 + (size_t)h*16;   // vhb/o1b [w][h][d]: + j*2048 + d
    {
        int i = tid >> 1, seg = (tid & 1)*8;
        *(uint4*)&Qs[i*40 + 16 + seg] = make_uint4(0,0,0,0);
        *(uint4*)&Ks[i*40 + 16 + seg] = make_uint4(0,0,0,0);
    }
    for (int vi = tid; vi < 512; vi += 256) {
        int i = vi >> 2, d4 = (vi & 3)*4;
        float4 q = *(const float4*)&qr[rowoff + i*16 + d4];
        float4 k = *(const float4*)&kr[rowoff + i*16 + d4];
        *(uint2*)&Qs[i*40 + d4] = make_uint2(pk2(q.x,q.y), pk2(q.z,q.w));
        *(uint2*)&Ks[i*40 + d4] = make_uint2(pk2(k.x,k.y), pk2(k.z,k.w));
    }
    {
        int jp = tid >> 2, d4 = (tid & 3)*4;
        float4 a = *(const float4*)&vhb[vbase + (size_t)(2*jp)*2048 + d4];
        float4 c = *(const float4*)&vhb[vbase + (size_t)(2*jp+1)*2048 + d4];
        *(unsigned*)&Vt[(d4+0)*136 + 2*jp] = pk2(a.x, c.x);
        *(unsigned*)&Vt[(d4+1)*136 + 2*jp] = pk2(a.y, c.y);
        *(unsigned*)&Vt[(d4+2)*136 + 2*jp] = pk2(a.z, c.z);
        *(unsigned*)&Vt[(d4+3)*136 + 2*jp] = pk2(a.w, c.w);
    }
    if (tid < 128) csr[tid] = dacs[((b*128+h)*4+n)*128 + tid];
    __syncthreads();
    int lane = tid & 63, wv = tid >> 6;
    int quad = lane >> 4, lm = lane & 15;
    int r0 = wv*32, r1 = wv*32 + 16;
    bf16x8 aQ0 = *(bf16x8*)&Qs[(r0+lm)*40 + quad*8];
    bf16x8 aQ1 = *(bf16x8*)&Qs[(r1+lm)*40 + quad*8];
    float csj[8], csi0[4], csi1[4];
    #pragma unroll
    for (int jt = 0; jt < 8; ++jt) csj[jt] = csr[jt*16+lm];
    #pragma unroll
    for (int r = 0; r < 4; ++r) { csi0[r] = csr[r0+quad*4+r]; csi1[r] = csr[r1+quad*4+r]; }
    float ls0[4]={0,0,0,0}, ls1[4]={0,0,0,0};
    f32x4 z = {0.f,0.f,0.f,0.f};
    #pragma unroll
    for (int jt = 0; jt < 8; ++jt) {
        bf16x8 bK = *(bf16x8*)&Ks[(jt*16+lm)*40 + quad*8];
        f32x4 s0 = __builtin_amdgcn_mfma_f32_16x16x32_bf16(aQ0, bK, z, 0,0,0);
        f32x4 s1 = __builtin_amdgcn_mfma_f32_16x16x32_bf16(aQ1, bK, z, 0,0,0);
        #pragma unroll
        for (int r = 0; r < 4; ++r) {
            float e0 = __expf(s0[r] - fabsf(csi0[r]-csj[jt])); ls0[r] += e0;
            float e1 = __expf(s1[r] - fabsf(csi1[r]-csj[jt])); ls1[r] += e1;
            Ps[(r0+quad*4+r)*136 + jt*16+lm] = f2bf(e0);
            Ps[(r1+quad*4+r)*136 + jt*16+lm] = f2bf(e1);
        }
    }
    #pragma unroll
    for (int r = 0; r < 4; ++r) {
        #pragma unroll
        for (int m = 1; m < 16; m <<= 1) {
            ls0[r] += __shfl_xor(ls0[r], m, 64);
            ls1[r] += __shfl_xor(ls1[r], m, 64);
        }
        if (lm == 0) { linv[r0+quad*4+r] = 1.f/ls0[r]; linv[r1+quad*4+r] = 1.f/ls1[r]; }
    }
    __syncthreads();
    f32x4 acc0 = z, acc1 = z;
    #pragma unroll
    for (int c = 0; c < 4; ++c) {
        bf16x8 bV  = *(bf16x8*)&Vt[lm*136 + c*32 + quad*8];
        bf16x8 aP0 = *(bf16x8*)&Ps[(r0+lm)*136 + c*32 + quad*8];
        bf16x8 aP1 = *(bf16x8*)&Ps[(r1+lm)*136 + c*32 + quad*8];
        acc0 = __builtin_amdgcn_mfma_f32_16x16x32_bf16(aP0, bV, acc0, 0,0,0);
        acc1 = __builtin_amdgcn_mfma_f32_16x16x32_bf16(aP1, bV, acc1, 0,0,0);
    }
    size_t lpb = (size_t)bn*262144 + (size_t)h*2048;       // lepe [bn][p][d], p=h*128+i
    size_t oab = (size_t)b*1048576 + (size_t)h*8192 + n*16; // attn (b,p,c)
    #pragma unroll
    for (int r = 0; r < 4; ++r) {
        int i0 = r0+quad*4+r, i1 = r1+quad*4+r;
        float o2a = acc0[r]*linv[i0];
        float o2b = acc1[r]*linv[i1];
        float o1a = o1b[vbase + (size_t)i0*2048 + lm];
        float o1c = o1b[vbase + (size_t)i1*2048 + lm];
        float la  = lepe[lpb + (size_t)i0*16 + lm];
        float lc  = lepe[lpb + (size_t)i1*16 + lm];
        attn[oab + (size_t)i0*64 + lm] = 0.5f*(o1a + o2a) + la;
        attn[oab + (size_t)i1*64 + lm] = 0.5f*(o1c + o2b) + lc;
    }
}

// ---------------- Kernel 7: out-proj + residual + LN1 (register-tiled) ----------------
__global__ __launch_bounds__(256) void k_proj_ln(
    const float* __restrict__ attn, const float* __restrict__ x,
    const float* __restrict__ ow, const float* __restrict__ ob,
    const float* __restrict__ g1, const float* __restrict__ b1,
    float* __restrict__ t1)
{
    __shared__ float As[64*132];
    __shared__ float Bs[4096];
    int tid = threadIdx.x;
    int pbase = blockIdx.x*128;
    int b = pbase >> 14, p0 = pbase & 16383;
    for (int i = tid*4; i < 4096; i += 1024)
        *(float4*)&Bs[i] = *(const float4*)&ow[i];
    for (int vi = tid; vi < 2048; vi += 256) {
        int kk = vi & 15, p = vi >> 4;
        float4 av = *(const float4*)&attn[((size_t)(pbase+p))*64 + kk*4];
        As[(kk*4+0)*132 + p] = av.x;
        As[(kk*4+1)*132 + p] = av.y;
        As[(kk*4+2)*132 + p] = av.z;
        As[(kk*4+3)*132 + p] = av.w;
    }
    __syncthreads();
    int tc = tid & 15, tp = tid >> 4;
    float acc[8][4];
    #pragma unroll
    for (int pp = 0; pp < 8; ++pp)
        #pragma unroll
        for (int u = 0; u < 4; ++u) acc[pp][u] = 0.f;
    #pragma unroll 4
    for (int k = 0; k < 64; ++k) {
        float4 a0 = *(const float4*)&As[k*132 + tp*8];
        float4 a1 = *(const float4*)&As[k*132 + tp*8 + 4];
        float4 bv = *(const float4*)&Bs[k*64 + tc*4];
        float av8[8] = {a0.x,a0.y,a0.z,a0.w,a1.x,a1.y,a1.z,a1.w};
        float bv4[4] = {bv.x,bv.y,bv.z,bv.w};
        #pragma unroll
        for (int pp = 0; pp < 8; ++pp)
            #pragma unroll
            for (int u = 0; u < 4; ++u)
                acc[pp][u] += av8[pp]*bv4[u];
    }
    __syncthreads();
    float* outT = As;
    #pragma unroll
    for (int u = 0; u < 4; ++u)
        #pragma unroll
        for (int pp = 0; pp < 8; ++pp)
            outT[(tc*4+u)*132 + tp*8 + pp] = acc[pp][u] + ob[tc*4+u];
    __syncthreads();
    int lane = tid & 63, wv = tid >> 6;
    float gg = g1[lane], bbv = b1[lane];
    for (int it = 0; it < 32; ++it) {
        int pos = wv*32 + it;
        int P = pbase + pos;
        float r = x[((size_t)(b*64 + lane))*HWSZ + p0 + pos] + outT[lane*132 + pos];
        float s = r;
        #pragma unroll
        for (int d = 1; d < 64; d <<= 1) s += __shfl_xor(s, d, 64);
        float mean = s*(1.f/64.f);
        float df = r - mean;
        float vv = df*df;
        #pragma unroll
        for (int d = 1; d < 64; d <<= 1) vv += __shfl_xor(vv, d, 64);
        float res = df*rsqrtf(vv*(1.f/64.f) + 1e-5f)*gg + bbv;
        t1[(size_t)P*64 + lane] = res;
    }
}

// ---------------- Kernel 8a: FFN up (gelu), register-tiled ----------------
__global__ __launch_bounds__(256) void k_ffn1(
    const float* __restrict__ t1, const float* __restrict__ w1,
    const float* __restrict__ b1, float* __restrict__ hid)
{
    __shared__ float As[64*132];
    __shared__ float Bs[4096];
    int tid = threadIdx.x;
    int jq = blockIdx.x & 3;
    int pbase = (blockIdx.x >> 2)*128;
    for (int i = tid*4; i < 4096; i += 1024) {
        int k = i >> 6, j4 = i & 63;
        *(float4*)&Bs[i] = *(const float4*)&w1[k*256 + jq*64 + j4];
    }
    for (int vi = tid; vi < 2048; vi += 256) {
        int kk = vi & 15, p = vi >> 4;
        float4 av = *(const float4*)&t1[((size_t)(pbase+p))*64 + kk*4];
        As[(kk*4+0)*132 + p] = av.x;
        As[(kk*4+1)*132 + p] = av.y;
        As[(kk*4+2)*132 + p] = av.z;
        As[(kk*4+3)*132 + p] = av.w;
    }
    __syncthreads();
    int tc = tid & 15, tp = tid >> 4;
    float acc[8][4];
    #pragma unroll
    for (int pp = 0; pp < 8; ++pp)
        #pragma unroll
        for (int u = 0; u < 4; ++u) acc[pp][u] = 0.f;
    #pragma unroll 4
    for (int k = 0; k < 64; ++k) {
        float4 a0 = *(const float4*)&As[k*132 + tp*8];
        float4 a1 = *(const float4*)&As[k*132 + tp*8 + 4];
        float4 bv = *(const float4*)&Bs[k*64 + tc*4];
        float av8[8] = {a0.x,a0.y,a0.z,a0.w,a1.x,a1.y,a1.z,a1.w};
        float bv4[4] = {bv.x,bv.y,bv.z,bv.w};
        #pragma unroll
        for (int pp = 0; pp < 8; ++pp)
            #pragma unroll
            for (int u = 0; u < 4; ++u)
                acc[pp][u] += av8[pp]*bv4[u];
    }
    float bb[4];
    #pragma unroll
    for (int u = 0; u < 4; ++u) bb[u] = b1[jq*64 + tc*4 + u];
    #pragma unroll
    for (int pp = 0; pp < 8; ++pp) {
        float4 o;
        o.x = gelu_f(acc[pp][0] + bb[0]);
        o.y = gelu_f(acc[pp][1] + bb[1]);
        o.z = gelu_f(acc[pp][2] + bb[2]);
        o.w = gelu_f(acc[pp][3] + bb[3]);
        *(float4*)&hid[((size_t)(pbase + tp*8 + pp))*256 + jq*64 + tc*4] = o;
    }
}

// ---------------- Kernel 8b: FFN down + residual + LN2 + transpose ----------------
__global__ __launch_bounds__(256) void k_ffn2(
    const float* __restrict__ hid, const float* __restrict__ t1,
    const float* __restrict__ w2, const float* __restrict__ b2,
    const float* __restrict__ g2, const float* __restrict__ bb2,
    float* __restrict__ outp)
{
    __shared__ float As[64*132];
    __shared__ float Bs[4096];
    int tid = threadIdx.x;
    int pbase = blockIdx.x*128;
    int b = pbase >> 14, p0 = pbase & 16383;
    int tc = tid & 15, tp = tid >> 4;
    float acc[8][4];
    #pragma unroll
    for (int pp = 0; pp < 8; ++pp)
        #pragma unroll
        for (int u = 0; u < 4; ++u) acc[pp][u] = 0.f;
    for (int kc = 0; kc < 4; ++kc) {
        __syncthreads();
        for (int i = tid*4; i < 4096; i += 1024)
            *(float4*)&Bs[i] = *(const float4*)&w2[kc*4096 + i];
        for (int vi = tid; vi < 2048; vi += 256) {
            int kk = vi & 15, p = vi >> 4;
            float4 av = *(const float4*)&hid[((size_t)(pbase+p))*256 + kc*64 + kk*4];
            As[(kk*4+0)*132 + p] = av.x;
            As[(kk*4+1)*132 + p] = av.y;
            As[(kk*4+2)*132 + p] = av.z;
            As[(kk*4+3)*132 + p] = av.w;
        }
        __syncthreads();
        #pragma unroll 4
        for (int k = 0; k < 64; ++k) {
            float4 a0 = *(const float4*)&As[k*132 + tp*8];
            float4 a1 = *(const float4*)&As[k*132 + tp*8 + 4];
            float4 bv = *(const float4*)&Bs[k*64 + tc*4];
            float av8[8] = {a0.x,a0.y,a0.z,a0.w,a1.x,a1.y,a1.z,a1.w};
            float bv4[4] = {bv.x,bv.y,bv.z,bv.w};
            #pragma unroll
            for (int pp = 0; pp < 8; ++pp)
                #pragma unroll
                for (int u = 0; u < 4; ++u)
                    acc[pp][u] += av8[pp]*bv4[u];
        }
    }
    __syncthreads();
    float* outT = As;
    #pragma unroll
    for (int u = 0; u < 4; ++u)
        #pragma unroll
        for (int pp = 0; pp < 8; ++pp)
            outT[(tc*4+u)*132 + tp*8 + pp] = acc[pp][u] + b2[tc*4+u];
    __syncthreads();
    int lane = tid & 63, wv = tid >> 6;
    {
        float gg = g2[lane], bbv = bb2[lane];
        for (int it = 0; it < 32; ++it) {
            int pos = wv*32 + it;
            int P = pbase + pos;
            float r = t1[(size_t)P*64 + lane] + outT[lane*132 + pos];
            float s = r;
            #pragma unroll
            for (int d = 1; d < 64; d <<= 1) s += __shfl_xor(s, d, 64);
            float mean = s*(1.f/64.f);
            float df = r - mean;
            float vv = df*df;
            #pragma unroll
            for (int d = 1; d < 64; d <<= 1) vv += __shfl_xor(vv, d, 64);
            float res = df*rsqrtf(vv*(1.f/64.f) + 1e-5f)*gg + bbv;
            outT[lane*132 + pos] = res;
        }
    }
    __syncthreads();
    for (int vi = tid; vi < 2048; vi += 256) {
        int c = vi >> 5, p4 = (vi & 31)*4;
        float4 ov = *(const float4*)&outT[c*132 + p4];
        *(float4*)&outp[((size_t)(b*64 + c))*HWSZ + p0 + p4] = ov;
    }
}

extern "C" void kernel_launch(void* const* d_in, const int* in_sizes, int n_in,
                              void* d_out, int out_size, void* d_ws, size_t ws_size,
                              hipStream_t stream) {
    const float* x      = (const float*)d_in[0];
    const float* y      = (const float*)d_in[1];
    const float* th     = (const float*)d_in[2];
    const float* dw1_w  = (const float*)d_in[3];
    const float* dw1_b  = (const float*)d_in[4];
    const float* dw2_w  = (const float*)d_in[5];
    const float* dw2_b  = (const float*)d_in[6];
    const float* qw     = (const float*)d_in[7];
    const float* qb     = (const float*)d_in[8];
    const float* kw     = (const float*)d_in[9];
    const float* kb     = (const float*)d_in[10];
    const float* vw     = (const float*)d_in[11];
    const float* vb     = (const float*)d_in[12];
    const float* lepe_w = (const float*)d_in[13];
    const float* lepe_b = (const float*)d_in[14];
    const float* dt_w   = (const float*)d_in[15];
    const float* dt_bias= (const float*)d_in[16];
    const float* A_log  = (const float*)d_in[17];
    const float* ow     = (const float*)d_in[18];
    const float* ob     = (const float*)d_in[19];
    const float* n1_g   = (const float*)d_in[20];
    const float* n1_b   = (const float*)d_in[21];
    const float* ffn_w1 = (const float*)d_in[22];
    const float* ffn_b1 = (const float*)d_in[23];
    const float* ffn_w2 = (const float*)d_in[24];
    const float* ffn_b2 = (const float*)d_in[25];
    const float* n2_g   = (const float*)d_in[26];
    const float* n2_b   = (const float*)d_in[27];
    float* out = (float*)d_out;

    const size_t SZ = 4194304;   // B*C*H*W elements
    float* ws    = (float*)d_ws;
    float* fused = ws + 0*SZ;    // reused as v_w after kernel 4
    float* qrb   = ws + 1*SZ;
    float* krb   = ws + 2*SZ;
    float* v5b   = ws + 3*SZ;
    float* lepeb = ws + 4*SZ;
    float* vhb   = ws + 5*SZ;
    float* o1b   = ws + 6*SZ;
    float* attnb = ws + 7*SZ;
    float* t1b   = ws + 8*SZ;
    float* dacs  = ws + 9*SZ;               // 262144
    float* dbcs  = ws + 9*SZ + 262144;      // 262144
    float* hidb  = ws + 1*SZ;               // reuse qr..lepe region (4*SZ)

    k_fuse<<<1024, 256, 0, stream>>>(y, th, dw1_w, dw1_b, dw2_w, dw2_b, fused);
    k_qkv<<<1024, 256, 0, stream>>>(x, fused, qw, qb, kw, kb, vw, vb,
                                    dt_w, dt_bias, A_log, qrb, krb, v5b, dacs, dbcs);
    k_cumsum<<<1024, 256, 0, stream>>>(dacs, dbcs);
    k_lepe<<<512, 256, 0, stream>>>(v5b, lepe_w, lepe_b, lepeb);
    k_attn_w1<<<2048, 256, 0, stream>>>(qrb, krb, v5b, dacs, fused);
    k_attn_h<<<2048, 256, 0, stream>>>(qrb, krb, v5b, fused, dbcs, vhb, o1b);
    k_attn_w2<<<2048, 256, 0, stream>>>(qrb, krb, vhb, o1b, dacs, lepeb, attnb);
    k_proj_ln<<<512, 256, 0, stream>>>(attnb, x, ow, ob, n1_g, n1_b, t1b);
    k_ffn1<<<2048, 256, 0, stream>>>(t1b, ffn_w1, ffn_b1, hidb);
    k_ffn2<<<512, 256, 0, stream>>>(hidb, t1b, ffn_w2, ffn_b2, n2_g, n2_b, out);
}

// Round 6
// 354.301 us; speedup vs baseline: 3.0788x; 1.1972x over previous
//
#include <hip/hip_runtime.h>
#include <math.h>

#define HWSZ 16384

typedef __attribute__((ext_vector_type(8))) short bf16x8;
typedef __attribute__((ext_vector_type(4))) float f32x4;

__device__ __forceinline__ float gelu_f(float v) {
    return 0.5f * v * (1.0f + erff(v * 0.70710678118654752f));
}
__device__ __forceinline__ float splus_f(float v) {
    return (v > 20.f) ? v : log1pf(expf(v));
}
__device__ __forceinline__ unsigned short f2bf(float f) {
    union { float f; unsigned u; } v; v.f = f;
    unsigned r = (v.u + 0x7FFF + ((v.u >> 16) & 1)) >> 16;
    return (unsigned short)r;
}
__device__ __forceinline__ unsigned pk2(float a, float b) {
    return (unsigned)f2bf(a) | ((unsigned)f2bf(b) << 16);
}
__device__ __forceinline__ float bf2f(unsigned short s) {
    union { unsigned u; float f; } v; v.u = ((unsigned)s) << 16; return v.f;
}

// ---------------- Kernel 1: fusion gate (LDS-tiled, 64 pos/block) ----------------
#define W1S 68
__global__ __launch_bounds__(256) void k_fuse(
    const float* __restrict__ y, const float* __restrict__ th,
    const float* __restrict__ w1, const float* __restrict__ b1,
    const float* __restrict__ w2, const float* __restrict__ b2,
    float* __restrict__ fused)
{
    __shared__ unsigned short fsh[8192];   // [c][pos] bf16, c 0..63=y, 64..127=th
    __shared__ float w1t[128*W1S];         // [c][o], stride 68
    int tid = threadIdx.x;
    int g = blockIdx.x;
    int b = g >> 8;
    int p0 = (g & 255)*64;
    for (int i = tid; i < 8192; i += 256) {
        int o = i >> 7, c = i & 127;
        w1t[c*W1S + o] = w1[i];
    }
    for (int vi = tid; vi < 1024; vi += 256) {
        int c = vi >> 4, p4 = (vi & 15)*4;
        float4 yv = *(const float4*)&y [((size_t)(b*64+c))*HWSZ + p0 + p4];
        float4 tv = *(const float4*)&th[((size_t)(b*64+c))*HWSZ + p0 + p4];
        *(uint2*)&fsh[c*64 + p4]      = make_uint2(pk2(yv.x,yv.y), pk2(yv.z,yv.w));
        *(uint2*)&fsh[(64+c)*64 + p4] = make_uint2(pk2(tv.x,tv.y), pk2(tv.z,tv.w));
    }
    __syncthreads();
    int lane = tid & 63, wv = tid >> 6;
    int po = lane & 15, oc = lane >> 4;
    int pos = wv*16 + po;
    float acc[16];
    #pragma unroll
    for (int d4 = 0; d4 < 4; ++d4) {
        float4 bv = *(const float4*)&b1[oc*16 + d4*4];
        acc[d4*4+0]=bv.x; acc[d4*4+1]=bv.y; acc[d4*4+2]=bv.z; acc[d4*4+3]=bv.w;
    }
    for (int c = 0; c < 128; ++c) {
        float xc = bf2f(fsh[c*64 + pos]);
        #pragma unroll
        for (int d4 = 0; d4 < 4; ++d4) {
            float4 wv4 = *(const float4*)&w1t[c*W1S + oc*16 + d4*4];
            acc[d4*4+0] += wv4.x*xc; acc[d4*4+1] += wv4.y*xc;
            acc[d4*4+2] += wv4.z*xc; acc[d4*4+3] += wv4.w*xc;
        }
    }
    float l0 = 0.f, l1 = 0.f;
    #pragma unroll
    for (int d4 = 0; d4 < 4; ++d4) {
        float4 wa4 = *(const float4*)&w2[oc*16 + d4*4];
        float4 wb4 = *(const float4*)&w2[64 + oc*16 + d4*4];
        float h0 = fmaxf(acc[d4*4+0],0.f), h1 = fmaxf(acc[d4*4+1],0.f);
        float h2 = fmaxf(acc[d4*4+2],0.f), h3 = fmaxf(acc[d4*4+3],0.f);
        l0 += wa4.x*h0 + wa4.y*h1 + wa4.z*h2 + wa4.w*h3;
        l1 += wb4.x*h0 + wb4.y*h1 + wb4.z*h2 + wb4.w*h3;
    }
    l0 += __shfl_xor(l0, 16, 64); l0 += __shfl_xor(l0, 32, 64);
    l1 += __shfl_xor(l1, 16, 64); l1 += __shfl_xor(l1, 32, 64);
    l0 += b2[0]; l1 += b2[1];
    float m = fmaxf(l0, l1);
    float e0 = __expf(l0 - m), e1 = __expf(l1 - m);
    float inv = 1.f/(e0 + e1);
    float wa = e0*inv, wb = e1*inv;
    float* fb = fused + (size_t)b*64*HWSZ + p0 + pos;
    #pragma unroll
    for (int u = 0; u < 16; ++u) {
        int c = oc*16 + u;
        float fv = bf2f(fsh[c*64 + pos])*wa + bf2f(fsh[(64+c)*64 + pos])*wb;
        fb[(size_t)c*HWSZ] = fv;
    }
}

// ---------------- Kernel 2: QKV + RoPE + dt ----------------
__global__ __launch_bounds__(256) void k_qkv(
    const float* __restrict__ x, const float* __restrict__ fused,
    const float* __restrict__ qw, const float* __restrict__ qb,
    const float* __restrict__ kw, const float* __restrict__ kb,
    const float* __restrict__ vw, const float* __restrict__ vb,
    const float* __restrict__ dtw, const float* __restrict__ dtb,
    const float* __restrict__ alog,
    float* __restrict__ qr, float* __restrict__ kr, float* __restrict__ v5,
    float* __restrict__ da, float* __restrict__ db)
{
    __shared__ float sw[12288];          // qw | kw | vw, each [c][o]
    __shared__ float sx[4096];           // [c][pos], 64x64
    int tid = threadIdx.x;
    for (int i = tid*4; i < 4096; i += 1024) {
        *(float4*)&sw[i]      = *(const float4*)&qw[i];
        *(float4*)&sw[4096+i] = *(const float4*)&kw[i];
        *(float4*)&sw[8192+i] = *(const float4*)&vw[i];
    }
    int b  = blockIdx.x >> 8;
    int p0 = (blockIdx.x & 255)*64;
    for (int vi = tid; vi < 1024; vi += 256) {
        int c = vi >> 4, p4 = (vi & 15)*4;
        *(float4*)&sx[c*64 + p4] = *(const float4*)&x[((size_t)(b*64+c))*HWSZ + p0 + p4];
    }
    __syncthreads();
    int lane = tid & 63;
    int n = tid >> 6;
    int p = p0 + lane;
    int h = p >> 7, w = p & 127;
    float sn[8], cn[8];
    #pragma unroll
    for (int t = 0; t < 8; ++t) {
        float ang = exp2f(-1.89824462565f * (float)t);   // 10000^(-t/7)
        sincosf((float)p * ang, &sn[t], &cn[t]);
    }
    float a[16];
    // ---- Q head n ----
    #pragma unroll
    for (int d = 0; d < 16; ++d) a[d] = qb[n*16+d];
    for (int c = 0; c < 64; ++c) {
        float xc = sx[c*64 + lane];
        #pragma unroll
        for (int d4 = 0; d4 < 4; ++d4) {
            float4 wv = *(const float4*)&sw[c*64 + n*16 + d4*4];
            a[d4*4+0] += wv.x*xc; a[d4*4+1] += wv.y*xc;
            a[d4*4+2] += wv.z*xc; a[d4*4+3] += wv.w*xc;
        }
    }
    {
        float r[16];
        #pragma unroll
        for (int t = 0; t < 8; ++t) {
            r[2*t]   = a[2*t]*cn[t]   - a[2*t+1]*sn[t];
            r[2*t+1] = a[2*t+1]*cn[t] + a[2*t]*sn[t];
        }
        float* dst = qr + (((size_t)(b*4+n))*HWSZ + p)*16;
        #pragma unroll
        for (int d4 = 0; d4 < 4; ++d4)
            *(float4*)&dst[d4*4] = make_float4(r[d4*4],r[d4*4+1],r[d4*4+2],r[d4*4+3]);
    }
    // ---- dt / da / db ----
    {
        float dt0 = 0.f, dt1 = 0.f;
        #pragma unroll
        for (int d = 0; d < 16; ++d) {
            float xv = sx[(n*16+d)*64 + lane];
            dt0 += xv*dtw[2*d];
            dt1 += xv*dtw[2*d+1];
        }
        float A  = -expf(alog[n]);
        float bb = dtb[n];
        da[((b*128+h)*4+n)*128 + w] = splus_f(dt0+bb)*A;
        db[((b*128+w)*4+n)*128 + h] = splus_f(dt1+bb)*A;
    }
    __syncthreads();
    for (int vi = tid; vi < 1024; vi += 256) {
        int c = vi >> 4, p4 = (vi & 15)*4;
        *(float4*)&sx[c*64 + p4] = *(const float4*)&fused[((size_t)(b*64+c))*HWSZ + p0 + p4];
    }
    __syncthreads();
    // ---- K head n (scaled 0.25, RoPE) ----
    #pragma unroll
    for (int d = 0; d < 16; ++d) a[d] = kb[n*16+d];
    for (int c = 0; c < 64; ++c) {
        float xc = sx[c*64 + lane];
        #pragma unroll
        for (int d4 = 0; d4 < 4; ++d4) {
            float4 wv = *(const float4*)&sw[4096 + c*64 + n*16 + d4*4];
            a[d4*4+0] += wv.x*xc; a[d4*4+1] += wv.y*xc;
            a[d4*4+2] += wv.z*xc; a[d4*4+3] += wv.w*xc;
        }
    }
    {
        float r[16];
        #pragma unroll
        for (int t = 0; t < 8; ++t) {
            float e = a[2*t]*0.25f, o = a[2*t+1]*0.25f;
            r[2*t]   = e*cn[t] - o*sn[t];
            r[2*t+1] = o*cn[t] + e*sn[t];
        }
        float* dst = kr + (((size_t)(b*4+n))*HWSZ + p)*16;
        #pragma unroll
        for (int d4 = 0; d4 < 4; ++d4)
            *(float4*)&dst[d4*4] = make_float4(r[d4*4],r[d4*4+1],r[d4*4+2],r[d4*4+3]);
    }
    // ---- V head n ----
    #pragma unroll
    for (int d = 0; d < 16; ++d) a[d] = vb[n*16+d];
    for (int c = 0; c < 64; ++c) {
        float xc = sx[c*64 + lane];
        #pragma unroll
        for (int d4 = 0; d4 < 4; ++d4) {
            float4 wv = *(const float4*)&sw[8192 + c*64 + n*16 + d4*4];
            a[d4*4+0] += wv.x*xc; a[d4*4+1] += wv.y*xc;
            a[d4*4+2] += wv.z*xc; a[d4*4+3] += wv.w*xc;
        }
    }
    {
        float* dst = v5 + (((size_t)(b*4+n))*HWSZ + p)*16;
        #pragma unroll
        for (int d4 = 0; d4 < 4; ++d4)
            *(float4*)&dst[d4*4] = make_float4(a[d4*4],a[d4*4+1],a[d4*4+2],a[d4*4+3]);
    }
}

// ---------------- Kernel 2b: cumsums ----------------
__global__ __launch_bounds__(256) void k_cumsum(float* __restrict__ da, float* __restrict__ db)
{
    int gw = (blockIdx.x*256 + threadIdx.x) >> 6;   // 0..4095
    int lane = threadIdx.x & 63;
    float* base = (gw < 2048) ? (da + (size_t)gw*128) : (db + (size_t)(gw-2048)*128);
    float2 e = *(float2*)&base[lane*2];
    float s = e.x + e.y;
    #pragma unroll
    for (int d = 1; d < 64; d <<= 1) {
        float t = __shfl_up(s, d, 64);
        if (lane >= d) s += t;
    }
    float excl = s - (e.x + e.y);
    float2 o;
    o.x = excl + e.x;
    o.y = excl + e.x + e.y;
    *(float2*)&base[lane*2] = o;
}

// ---------------- Kernel 3: LePE depthwise 5x5 conv, LDS-tiled ----------------
#define LROW 328
__global__ __launch_bounds__(256) void k_lepe(
    const float* __restrict__ v5, const float* __restrict__ lw,
    const float* __restrict__ lb, float* __restrict__ lepe)
{
    __shared__ float sv[36*LROW];
    __shared__ float swt[400];
    int tid = threadIdx.x, bid = blockIdx.x;
    int tw = bid & 7, th_ = (bid >> 3) & 3, n = (bid >> 5) & 3, b = bid >> 7;
    int bn = b*4 + n;
    int h0 = th_*32, w0 = tw*16;
    for (int i = tid; i < 400; i += 256) {
        int tap = i >> 4, d = i & 15;
        swt[i] = lw[tap*64 + n*16 + d];
    }
    const float* vb = v5 + (size_t)bn*HWSZ*16;
    for (int vi = tid; vi < 2880; vi += 256) {
        int hh = vi / 80;
        int rem = vi - hh*80;
        int ww = rem >> 2, df = (rem & 3)*4;
        int h = h0 - 2 + hh, w = w0 - 2 + ww;
        float4 val = make_float4(0.f,0.f,0.f,0.f);
        if (h >= 0 && h < 128 && w >= 0 && w < 128)
            val = *(const float4*)&vb[((size_t)(h*128+w))*16 + df];
        *(float4*)&sv[hh*LROW + ww*16 + df] = val;
    }
    __syncthreads();
    int df = (tid & 3)*4;
    int s  = tid >> 2;
    int ph = s >> 1;
    int pw = (s & 1)*8;
    float4 bv = *(const float4*)&lb[n*16 + df];
    float acc[8][4];
    #pragma unroll
    for (int ow = 0; ow < 8; ++ow) {
        acc[ow][0] = bv.x; acc[ow][1] = bv.y; acc[ow][2] = bv.z; acc[ow][3] = bv.w;
    }
    #pragma unroll
    for (int ky = 0; ky < 5; ++ky) {
        float wgt[5][4];
        #pragma unroll
        for (int kx = 0; kx < 5; ++kx) {
            float4 wv = *(const float4*)&swt[(ky*5+kx)*16 + df];
            wgt[kx][0]=wv.x; wgt[kx][1]=wv.y; wgt[kx][2]=wv.z; wgt[kx][3]=wv.w;
        }
        float dat[13][4];
        #pragma unroll
        for (int c = 0; c < 13; ++c) {
            float4 dv = *(const float4*)&sv[(ph+ky)*LROW + (pw+c)*16 + df];
            dat[c][0]=dv.x; dat[c][1]=dv.y; dat[c][2]=dv.z; dat[c][3]=dv.w;
        }
        #pragma unroll
        for (int ow = 0; ow < 8; ++ow)
            #pragma unroll
            for (int kx = 0; kx < 5; ++kx)
                #pragma unroll
                for (int u = 0; u < 4; ++u)
                    acc[ow][u] += dat[ow+kx][u]*wgt[kx][u];
    }
    float* ob = lepe + ((size_t)bn*HWSZ + (size_t)(h0+ph)*128 + w0+pw)*16 + df;
    #pragma unroll
    for (int ow = 0; ow < 8; ++ow)
        *(float4*)&ob[ow*16] = make_float4(acc[ow][0],acc[ow][1],acc[ow][2],acc[ow][3]);
}

// ---------------- Kernel 4: row attention pass 1 -> v_w (MFMA) ----------------
__global__ __launch_bounds__(256) void k_attn_w1(
    const float* __restrict__ qr, const float* __restrict__ kr,
    const float* __restrict__ v5, const float* __restrict__ dacs,
    float* __restrict__ vwb)
{
    __shared__ unsigned short Qs[128*40], Ks[128*40], Vt[16*136], Ps[128*136];
    __shared__ float csr[128], linv[128];
    int tid = threadIdx.x, bid = blockIdx.x;
    int h = bid & 127, n = (bid >> 7) & 3, b = bid >> 9;
    size_t rowoff = ((size_t)((b*4+n)*128 + h)) * 2048;
    {   // zero pad k=16..31
        int i = tid >> 1, seg = (tid & 1)*8;
        *(uint4*)&Qs[i*40 + 16 + seg] = make_uint4(0,0,0,0);
        *(uint4*)&Ks[i*40 + 16 + seg] = make_uint4(0,0,0,0);
    }
    for (int vi = tid; vi < 512; vi += 256) {
        int i = vi >> 2, d4 = (vi & 3)*4;
        float4 q = *(const float4*)&qr[rowoff + i*16 + d4];
        float4 k = *(const float4*)&kr[rowoff + i*16 + d4];
        *(uint2*)&Qs[i*40 + d4] = make_uint2(pk2(q.x,q.y), pk2(q.z,q.w));
        *(uint2*)&Ks[i*40 + d4] = make_uint2(pk2(k.x,k.y), pk2(k.z,k.w));
    }
    {   // V^T staging: pairs of rows
        int jp = tid >> 2, d4 = (tid & 3)*4;
        float4 a = *(const float4*)&v5[rowoff + (2*jp)*16 + d4];
        float4 c = *(const float4*)&v5[rowoff + (2*jp+1)*16 + d4];
        *(unsigned*)&Vt[(d4+0)*136 + 2*jp] = pk2(a.x, c.x);
        *(unsigned*)&Vt[(d4+1)*136 + 2*jp] = pk2(a.y, c.y);
        *(unsigned*)&Vt[(d4+2)*136 + 2*jp] = pk2(a.z, c.z);
        *(unsigned*)&Vt[(d4+3)*136 + 2*jp] = pk2(a.w, c.w);
    }
    if (tid < 128) csr[tid] = dacs[((b*128+h)*4+n)*128 + tid];
    __syncthreads();
    int lane = tid & 63, wv = tid >> 6;
    int quad = lane >> 4, lm = lane & 15;
    int r0 = wv*32, r1 = wv*32 + 16;
    bf16x8 aQ0 = *(bf16x8*)&Qs[(r0+lm)*40 + quad*8];
    bf16x8 aQ1 = *(bf16x8*)&Qs[(r1+lm)*40 + quad*8];
    float csj[8], csi0[4], csi1[4];
    #pragma unroll
    for (int jt = 0; jt < 8; ++jt) csj[jt] = csr[jt*16+lm];
    #pragma unroll
    for (int r = 0; r < 4; ++r) { csi0[r] = csr[r0+quad*4+r]; csi1[r] = csr[r1+quad*4+r]; }
    float ls0[4]={0,0,0,0}, ls1[4]={0,0,0,0};
    f32x4 z = {0.f,0.f,0.f,0.f};
    #pragma unroll
    for (int jt = 0; jt < 8; ++jt) {
        bf16x8 bK = *(bf16x8*)&Ks[(jt*16+lm)*40 + quad*8];
        f32x4 s0 = __builtin_amdgcn_mfma_f32_16x16x32_bf16(aQ0, bK, z, 0,0,0);
        f32x4 s1 = __builtin_amdgcn_mfma_f32_16x16x32_bf16(aQ1, bK, z, 0,0,0);
        #pragma unroll
        for (int r = 0; r < 4; ++r) {
            float e0 = __expf(s0[r] - fabsf(csi0[r]-csj[jt])); ls0[r] += e0;
            float e1 = __expf(s1[r] - fabsf(csi1[r]-csj[jt])); ls1[r] += e1;
            Ps[(r0+quad*4+r)*136 + jt*16+lm] = f2bf(e0);
            Ps[(r1+quad*4+r)*136 + jt*16+lm] = f2bf(e1);
        }
    }
    #pragma unroll
    for (int r = 0; r < 4; ++r) {
        #pragma unroll
        for (int m = 1; m < 16; m <<= 1) {
            ls0[r] += __shfl_xor(ls0[r], m, 64);
            ls1[r] += __shfl_xor(ls1[r], m, 64);
        }
        if (lm == 0) { linv[r0+quad*4+r] = 1.f/ls0[r]; linv[r1+quad*4+r] = 1.f/ls1[r]; }
    }
    __syncthreads();
    f32x4 acc0 = z, acc1 = z;
    #pragma unroll
    for (int c = 0; c < 4; ++c) {
        bf16x8 bV  = *(bf16x8*)&Vt[lm*136 + c*32 + quad*8];
        bf16x8 aP0 = *(bf16x8*)&Ps[(r0+lm)*136 + c*32 + quad*8];
        bf16x8 aP1 = *(bf16x8*)&Ps[(r1+lm)*136 + c*32 + quad*8];
        acc0 = __builtin_amdgcn_mfma_f32_16x16x32_bf16(aP0, bV, acc0, 0,0,0);
        acc1 = __builtin_amdgcn_mfma_f32_16x16x32_bf16(aP1, bV, acc1, 0,0,0);
    }
    #pragma unroll
    for (int r = 0; r < 4; ++r) {
        int i0 = r0+quad*4+r, i1 = r1+quad*4+r;
        vwb[rowoff + (size_t)i0*16 + lm] = acc0[r]*linv[i0];
        vwb[rowoff + (size_t)i1*16 + lm] = acc1[r]*linv[i1];
    }
}

// ---------------- Kernel 5: column attention -> v_h and out1 (MFMA) ----------------
__global__ __launch_bounds__(256) void k_attn_h(
    const float* __restrict__ qr, const float* __restrict__ kr,
    const float* __restrict__ v5, const float* __restrict__ vwb,
    const float* __restrict__ dbcs,
    float* __restrict__ vhb, float* __restrict__ o1b)
{
    __shared__ unsigned short Qs[128*40], Ks[128*40], Vt[16*136], Wt[16*136], Ps[128*136];
    __shared__ float csr[128], linv[128];
    int tid = threadIdx.x, bid = blockIdx.x;
    int w = bid & 127, n = (bid >> 7) & 3, b = bid >> 9;
    int bn = b*4 + n;
    size_t base = ((size_t)bn*16384 + w)*16;     // element (h=0, d=0); h-stride 2048
    {
        int i = tid >> 1, seg = (tid & 1)*8;
        *(uint4*)&Qs[i*40 + 16 + seg] = make_uint4(0,0,0,0);
        *(uint4*)&Ks[i*40 + 16 + seg] = make_uint4(0,0,0,0);
    }
    for (int vi = tid; vi < 512; vi += 256) {
        int i = vi >> 2, d4 = (vi & 3)*4;
        float4 q = *(const float4*)&qr[base + (size_t)i*2048 + d4];
        float4 k = *(const float4*)&kr[base + (size_t)i*2048 + d4];
        *(uint2*)&Qs[i*40 + d4] = make_uint2(pk2(q.x,q.y), pk2(q.z,q.w));
        *(uint2*)&Ks[i*40 + d4] = make_uint2(pk2(k.x,k.y), pk2(k.z,k.w));
    }
    {
        int jp = tid >> 2, d4 = (tid & 3)*4;
        float4 a = *(const float4*)&v5[base + (size_t)(2*jp)*2048 + d4];
        float4 c = *(const float4*)&v5[base + (size_t)(2*jp+1)*2048 + d4];
        *(unsigned*)&Vt[(d4+0)*136 + 2*jp] = pk2(a.x, c.x);
        *(unsigned*)&Vt[(d4+1)*136 + 2*jp] = pk2(a.y, c.y);
        *(unsigned*)&Vt[(d4+2)*136 + 2*jp] = pk2(a.z, c.z);
        *(unsigned*)&Vt[(d4+3)*136 + 2*jp] = pk2(a.w, c.w);
        float4 e = *(const float4*)&vwb[base + (size_t)(2*jp)*2048 + d4];
        float4 f = *(const float4*)&vwb[base + (size_t)(2*jp+1)*2048 + d4];
        *(unsigned*)&Wt[(d4+0)*136 + 2*jp] = pk2(e.x, f.x);
        *(unsigned*)&Wt[(d4+1)*136 + 2*jp] = pk2(e.y, f.y);
        *(unsigned*)&Wt[(d4+2)*136 + 2*jp] = pk2(e.z, f.z);
        *(unsigned*)&Wt[(d4+3)*136 + 2*jp] = pk2(e.w, f.w);
    }
    if (tid < 128) csr[tid] = dbcs[((b*128+w)*4+n)*128 + tid];
    __syncthreads();
    int lane = tid & 63, wv = tid >> 6;
    int quad = lane >> 4, lm = lane & 15;
    int r0 = wv*32, r1 = wv*32 + 16;
    bf16x8 aQ0 = *(bf16x8*)&Qs[(r0+lm)*40 + quad*8];
    bf16x8 aQ1 = *(bf16x8*)&Qs[(r1+lm)*40 + quad*8];
    float csj[8], csi0[4], csi1[4];
    #pragma unroll
    for (int jt = 0; jt < 8; ++jt) csj[jt] = csr[jt*16+lm];
    #pragma unroll
    for (int r = 0; r < 4; ++r) { csi0[r] = csr[r0+quad*4+r]; csi1[r] = csr[r1+quad*4+r]; }
    float ls0[4]={0,0,0,0}, ls1[4]={0,0,0,0};
    f32x4 z = {0.f,0.f,0.f,0.f};
    #pragma unroll
    for (int jt = 0; jt < 8; ++jt) {
        bf16x8 bK = *(bf16x8*)&Ks[(jt*16+lm)*40 + quad*8];
        f32x4 s0 = __builtin_amdgcn_mfma_f32_16x16x32_bf16(aQ0, bK, z, 0,0,0);
        f32x4 s1 = __builtin_amdgcn_mfma_f32_16x16x32_bf16(aQ1, bK, z, 0,0,0);
        #pragma unroll
        for (int r = 0; r < 4; ++r) {
            float e0 = __expf(s0[r] - fabsf(csi0[r]-csj[jt])); ls0[r] += e0;
            float e1 = __expf(s1[r] - fabsf(csi1[r]-csj[jt])); ls1[r] += e1;
            Ps[(r0+quad*4+r)*136 + jt*16+lm] = f2bf(e0);
            Ps[(r1+quad*4+r)*136 + jt*16+lm] = f2bf(e1);
        }
    }
    #pragma unroll
    for (int r = 0; r < 4; ++r) {
        #pragma unroll
        for (int m = 1; m < 16; m <<= 1) {
            ls0[r] += __shfl_xor(ls0[r], m, 64);
            ls1[r] += __shfl_xor(ls1[r], m, 64);
        }
        if (lm == 0) { linv[r0+quad*4+r] = 1.f/ls0[r]; linv[r1+quad*4+r] = 1.f/ls1[r]; }
    }
    __syncthreads();
    f32x4 aV0 = z, aV1 = z, aW0 = z, aW1 = z;
    #pragma unroll
    for (int c = 0; c < 4; ++c) {
        bf16x8 bV  = *(bf16x8*)&Vt[lm*136 + c*32 + quad*8];
        bf16x8 bW  = *(bf16x8*)&Wt[lm*136 + c*32 + quad*8];
        bf16x8 aP0 = *(bf16x8*)&Ps[(r0+lm)*136 + c*32 + quad*8];
        bf16x8 aP1 = *(bf16x8*)&Ps[(r1+lm)*136 + c*32 + quad*8];
        aV0 = __builtin_amdgcn_mfma_f32_16x16x32_bf16(aP0, bV, aV0, 0,0,0);
        aV1 = __builtin_amdgcn_mfma_f32_16x16x32_bf16(aP1, bV, aV1, 0,0,0);
        aW0 = __builtin_amdgcn_mfma_f32_16x16x32_bf16(aP0, bW, aW0, 0,0,0);
        aW1 = __builtin_amdgcn_mfma_f32_16x16x32_bf16(aP1, bW, aW1, 0,0,0);
    }
    size_t obase = ((size_t)bn*16384 + (size_t)w*128)*16;   // [w][h][d]
    #pragma unroll
    for (int r = 0; r < 4; ++r) {
        int i0 = r0+quad*4+r, i1 = r1+quad*4+r;
        float v0 = linv[i0], v1 = linv[i1];
        vhb[obase + (size_t)i0*16 + lm] = aV0[r]*v0;
        vhb[obase + (size_t)i1*16 + lm] = aV1[r]*v1;
        o1b[obase + (size_t)i0*16 + lm] = aW0[r]*v0;
        o1b[obase + (size_t)i1*16 + lm] = aW1[r]*v1;
    }
}

// ---------------- Kernel 6: row attention pass 2 -> out2, combine + lepe (MFMA) ----------------
__global__ __launch_bounds__(256) void k_attn_w2(
    const float* __restrict__ qr, const float* __restrict__ kr,
    const float* __restrict__ vhb, const float* __restrict__ o1b,
    const float* __restrict__ dacs, const float* __restrict__ lepe,
    float* __restrict__ attn)
{
    __shared__ unsigned short Qs[128*40], Ks[128*40], Vt[16*136], Ps[128*136];
    __shared__ float csr[128], linv[128];
    int tid = threadIdx.x, bid = blockIdx.x;
    int h = bid & 127, n = (bid >> 7) & 3, b = bid >> 9;
    int bn = b*4 + n;
    size_t rowoff = ((size_t)(bn*128 + h)) * 2048;
    size_t vbase  = (size_t)bn*262144 + (size_t)h*16;   // vhb/o1b [w][h][d]: + j*2048 + d
    {
        int i = tid >> 1, seg = (tid & 1)*8;
        *(uint4*)&Qs[i*40 + 16 + seg] = make_uint4(0,0,0,0);
        *(uint4*)&Ks[i*40 + 16 + seg] = make_uint4(0,0,0,0);
    }
    for (int vi = tid; vi < 512; vi += 256) {
        int i = vi >> 2, d4 = (vi & 3)*4;
        float4 q = *(const float4*)&qr[rowoff + i*16 + d4];
        float4 k = *(const float4*)&kr[rowoff + i*16 + d4];
        *(uint2*)&Qs[i*40 + d4] = make_uint2(pk2(q.x,q.y), pk2(q.z,q.w));
        *(uint2*)&Ks[i*40 + d4] = make_uint2(pk2(k.x,k.y), pk2(k.z,k.w));
    }
    {
        int jp = tid >> 2, d4 = (tid & 3)*4;
        float4 a = *(const float4*)&vhb[vbase + (size_t)(2*jp)*2048 + d4];
        float4 c = *(const float4*)&vhb[vbase + (size_t)(2*jp+1)*2048 + d4];
        *(unsigned*)&Vt[(d4+0)*136 + 2*jp] = pk2(a.x, c.x);
        *(unsigned*)&Vt[(d4+1)*136 + 2*jp] = pk2(a.y, c.y);
        *(unsigned*)&Vt[(d4+2)*136 + 2*jp] = pk2(a.z, c.z);
        *(unsigned*)&Vt[(d4+3)*136 + 2*jp] = pk2(a.w, c.w);
    }
    if (tid < 128) csr[tid] = dacs[((b*128+h)*4+n)*128 + tid];
    __syncthreads();
    int lane = tid & 63, wv = tid >> 6;
    int quad = lane >> 4, lm = lane & 15;
    int r0 = wv*32, r1 = wv*32 + 16;
    bf16x8 aQ0 = *(bf16x8*)&Qs[(r0+lm)*40 + quad*8];
    bf16x8 aQ1 = *(bf16x8*)&Qs[(r1+lm)*40 + quad*8];
    float csj[8], csi0[4], csi1[4];
    #pragma unroll
    for (int jt = 0; jt < 8; ++jt) csj[jt] = csr[jt*16+lm];
    #pragma unroll
    for (int r = 0; r < 4; ++r) { csi0[r] = csr[r0+quad*4+r]; csi1[r] = csr[r1+quad*4+r]; }
    float ls0[4]={0,0,0,0}, ls1[4]={0,0,0,0};
    f32x4 z = {0.f,0.f,0.f,0.f};
    #pragma unroll
    for (int jt = 0; jt < 8; ++jt) {
        bf16x8 bK = *(bf16x8*)&Ks[(jt*16+lm)*40 + quad*8];
        f32x4 s0 = __builtin_amdgcn_mfma_f32_16x16x32_bf16(aQ0, bK, z, 0,0,0);
        f32x4 s1 = __builtin_amdgcn_mfma_f32_16x16x32_bf16(aQ1, bK, z, 0,0,0);
        #pragma unroll
        for (int r = 0; r < 4; ++r) {
            float e0 = __expf(s0[r] - fabsf(csi0[r]-csj[jt])); ls0[r] += e0;
            float e1 = __expf(s1[r] - fabsf(csi1[r]-csj[jt])); ls1[r] += e1;
            Ps[(r0+quad*4+r)*136 + jt*16+lm] = f2bf(e0);
            Ps[(r1+quad*4+r)*136 + jt*16+lm] = f2bf(e1);
        }
    }
    #pragma unroll
    for (int r = 0; r < 4; ++r) {
        #pragma unroll
        for (int m = 1; m < 16; m <<= 1) {
            ls0[r] += __shfl_xor(ls0[r], m, 64);
            ls1[r] += __shfl_xor(ls1[r], m, 64);
        }
        if (lm == 0) { linv[r0+quad*4+r] = 1.f/ls0[r]; linv[r1+quad*4+r] = 1.f/ls1[r]; }
    }
    __syncthreads();
    f32x4 acc0 = z, acc1 = z;
    #pragma unroll
    for (int c = 0; c < 4; ++c) {
        bf16x8 bV  = *(bf16x8*)&Vt[lm*136 + c*32 + quad*8];
        bf16x8 aP0 = *(bf16x8*)&Ps[(r0+lm)*136 + c*32 + quad*8];
        bf16x8 aP1 = *(bf16x8*)&Ps[(r1+lm)*136 + c*32 + quad*8];
        acc0 = __builtin_amdgcn_mfma_f32_16x16x32_bf16(aP0, bV, acc0, 0,0,0);
        acc1 = __builtin_amdgcn_mfma_f32_16x16x32_bf16(aP1, bV, acc1, 0,0,0);
    }
    size_t lpb = (size_t)bn*262144 + (size_t)h*2048;       // lepe [bn][p][d], p=h*128+i
    size_t oab = (size_t)b*1048576 + (size_t)h*8192 + n*16; // attn (b,p,c)
    #pragma unroll
    for (int r = 0; r < 4; ++r) {
        int i0 = r0+quad*4+r, i1 = r1+quad*4+r;
        float o2a = acc0[r]*linv[i0];
        float o2b = acc1[r]*linv[i1];
        float o1a = o1b[vbase + (size_t)i0*2048 + lm];
        float o1c = o1b[vbase + (size_t)i1*2048 + lm];
        float la  = lepe[lpb + (size_t)i0*16 + lm];
        float lc  = lepe[lpb + (size_t)i1*16 + lm];
        attn[oab + (size_t)i0*64 + lm] = 0.5f*(o1a + o2a) + la;
        attn[oab + (size_t)i1*64 + lm] = 0.5f*(o1c + o2b) + lc;
    }
}

// ---------------- Kernel 7: out-proj + residual + LN1 (MFMA) ----------------
// 128 pos/block, grid 512. A = attn bf16 [p][72], B = ow^T bf16 [c][72].
__global__ __launch_bounds__(256) void k_proj_ln(
    const float* __restrict__ attn, const float* __restrict__ x,
    const float* __restrict__ ow, const float* __restrict__ ob,
    const float* __restrict__ g1, const float* __restrict__ b1,
    float* __restrict__ t1)
{
    __shared__ unsigned short As[128*72];   // 18432 B
    __shared__ unsigned short Bs[64*72];    // 9216 B
    __shared__ float XT[8704];              // x [c][132] (8448 used) / outT [p][68] (8704)
    int tid = threadIdx.x, bid = blockIdx.x;
    int pbase = bid*128;
    int b = pbase >> 14, p0 = pbase & 16383;
    for (int vi = tid; vi < 2048; vi += 256) {
        int p = vi >> 4, c4 = (vi & 15)*4;
        float4 v = *(const float4*)&attn[((size_t)(pbase+p))*64 + c4];
        *(uint2*)&As[p*72 + c4] = make_uint2(pk2(v.x,v.y), pk2(v.z,v.w));
    }
    for (int vi = tid; vi < 512; vi += 256) {
        int kp = vi >> 4, c4 = (vi & 15)*4;
        float4 a = *(const float4*)&ow[(2*kp)*64 + c4];
        float4 c = *(const float4*)&ow[(2*kp+1)*64 + c4];
        *(unsigned*)&Bs[(c4+0)*72 + 2*kp] = pk2(a.x, c.x);
        *(unsigned*)&Bs[(c4+1)*72 + 2*kp] = pk2(a.y, c.y);
        *(unsigned*)&Bs[(c4+2)*72 + 2*kp] = pk2(a.z, c.z);
        *(unsigned*)&Bs[(c4+3)*72 + 2*kp] = pk2(a.w, c.w);
    }
    for (int vi = tid; vi < 2048; vi += 256) {
        int c = vi >> 5, p4 = (vi & 31)*4;
        *(float4*)&XT[c*132 + p4] = *(const float4*)&x[((size_t)(b*64+c))*HWSZ + p0 + p4];
    }
    __syncthreads();
    int lane = tid & 63, wv = tid >> 6;
    int quad = lane >> 4, lm = lane & 15;
    int M0 = wv*32;
    // x residual + params into regs (before XT is overwritten)
    float xv[2][4][4], obv[4], g1v[4], b1v[4];
    #pragma unroll
    for (int nt = 0; nt < 4; ++nt) {
        int c = nt*16 + lm;
        obv[nt] = ob[c]; g1v[nt] = g1[c]; b1v[nt] = b1[c];
        #pragma unroll
        for (int mt = 0; mt < 2; ++mt)
            #pragma unroll
            for (int r = 0; r < 4; ++r)
                xv[mt][nt][r] = XT[c*132 + M0 + mt*16 + quad*4 + r];
    }
    f32x4 z = {0.f,0.f,0.f,0.f};
    f32x4 acc[2][4];
    #pragma unroll
    for (int mt = 0; mt < 2; ++mt)
        #pragma unroll
        for (int nt = 0; nt < 4; ++nt) acc[mt][nt] = z;
    #pragma unroll
    for (int ks = 0; ks < 2; ++ks) {
        bf16x8 aF[2];
        #pragma unroll
        for (int mt = 0; mt < 2; ++mt)
            aF[mt] = *(bf16x8*)&As[(M0+mt*16+lm)*72 + ks*32 + quad*8];
        #pragma unroll
        for (int nt = 0; nt < 4; ++nt) {
            bf16x8 bF = *(bf16x8*)&Bs[(nt*16+lm)*72 + ks*32 + quad*8];
            #pragma unroll
            for (int mt = 0; mt < 2; ++mt)
                acc[mt][nt] = __builtin_amdgcn_mfma_f32_16x16x32_bf16(aF[mt], bF, acc[mt][nt], 0,0,0);
        }
    }
    // LN1 in registers
    float val[2][4][4], res[2][4][4];
    #pragma unroll
    for (int mt = 0; mt < 2; ++mt) {
        #pragma unroll
        for (int r = 0; r < 4; ++r) {
            float s = 0.f;
            #pragma unroll
            for (int nt = 0; nt < 4; ++nt) {
                val[mt][nt][r] = acc[mt][nt][r] + obv[nt] + xv[mt][nt][r];
                s += val[mt][nt][r];
            }
            s += __shfl_xor(s, 1, 64); s += __shfl_xor(s, 2, 64);
            s += __shfl_xor(s, 4, 64); s += __shfl_xor(s, 8, 64);
            float mean = s*(1.f/64.f);
            float vv = 0.f;
            #pragma unroll
            for (int nt = 0; nt < 4; ++nt) {
                float d = val[mt][nt][r] - mean;
                vv += d*d;
            }
            vv += __shfl_xor(vv, 1, 64); vv += __shfl_xor(vv, 2, 64);
            vv += __shfl_xor(vv, 4, 64); vv += __shfl_xor(vv, 8, 64);
            float rs = rsqrtf(vv*(1.f/64.f) + 1e-5f);
            #pragma unroll
            for (int nt = 0; nt < 4; ++nt)
                res[mt][nt][r] = (val[mt][nt][r] - mean)*rs*g1v[nt] + b1v[nt];
        }
    }
    __syncthreads();
    float* outT = XT;   // [p][68]
    #pragma unroll
    for (int mt = 0; mt < 2; ++mt)
        #pragma unroll
        for (int r = 0; r < 4; ++r)
            #pragma unroll
            for (int nt = 0; nt < 4; ++nt)
                outT[(M0+mt*16+quad*4+r)*68 + nt*16 + lm] = res[mt][nt][r];
    __syncthreads();
    for (int vi = tid; vi < 2048; vi += 256) {
        int p = vi >> 4, c4 = (vi & 15)*4;
        *(float4*)&t1[((size_t)(pbase+p))*64 + c4] = *(const float4*)&outT[p*68 + c4];
    }
}

// ---------------- Kernel 8: fused FFN (MFMA) + residual + LN2 + transpose ----------------
// 128 pos/block, grid 512. hid never hits global: 4 k-chunks of 64.
__global__ __launch_bounds__(256) void k_ffn(
    const float* __restrict__ t1, const float* __restrict__ w1,
    const float* __restrict__ b1f, const float* __restrict__ w2,
    const float* __restrict__ b2f, const float* __restrict__ g2,
    const float* __restrict__ bb2, float* __restrict__ outp)
{
    __shared__ unsigned short At1[128*72];      // 18432 B (t1 bf16, A + residual)
    __shared__ unsigned short WH[2*64*72 + 128*72];  // W1b | W2b | Hid ; aliased by outT
    __shared__ float sb1[256];
    __shared__ float sb2[64], sg[64], sbb[64];
    unsigned short* W1b = WH;
    unsigned short* W2b = WH + 4608;
    unsigned short* Hid = WH + 9216;
    int tid = threadIdx.x, bid = blockIdx.x;
    int pbase = bid*128;
    int b = pbase >> 14, p0 = pbase & 16383;
    for (int vi = tid; vi < 2048; vi += 256) {
        int p = vi >> 4, c4 = (vi & 15)*4;
        float4 v = *(const float4*)&t1[((size_t)(pbase+p))*64 + c4];
        *(uint2*)&At1[p*72 + c4] = make_uint2(pk2(v.x,v.y), pk2(v.z,v.w));
    }
    if (tid < 256) sb1[tid] = b1f[tid];
    if (tid < 64) { sb2[tid] = b2f[tid]; sg[tid] = g2[tid]; sbb[tid] = bb2[tid]; }
    int lane = tid & 63, wv = tid >> 6;
    int quad = lane >> 4, lm = lane & 15;
    int M0 = wv*32;
    f32x4 z = {0.f,0.f,0.f,0.f};
    f32x4 acc2[2][4];
    #pragma unroll
    for (int mt = 0; mt < 2; ++mt)
        #pragma unroll
        for (int nt = 0; nt < 4; ++nt) acc2[mt][nt] = z;
    for (int jc = 0; jc < 4; ++jc) {
        __syncthreads();
        for (int vi = tid; vi < 512; vi += 256) {
            int kp = vi >> 4, c4 = (vi & 15)*4;
            float4 a = *(const float4*)&w1[(2*kp)*256 + jc*64 + c4];
            float4 c = *(const float4*)&w1[(2*kp+1)*256 + jc*64 + c4];
            *(unsigned*)&W1b[(c4+0)*72 + 2*kp] = pk2(a.x, c.x);
            *(unsigned*)&W1b[(c4+1)*72 + 2*kp] = pk2(a.y, c.y);
            *(unsigned*)&W1b[(c4+2)*72 + 2*kp] = pk2(a.z, c.z);
            *(unsigned*)&W1b[(c4+3)*72 + 2*kp] = pk2(a.w, c.w);
        }
        for (int vi = tid; vi < 512; vi += 256) {
            int kp = vi >> 4, c4 = (vi & 15)*4;
            float4 a = *(const float4*)&w2[(size_t)(jc*64 + 2*kp)*64 + c4];
            float4 c = *(const float4*)&w2[(size_t)(jc*64 + 2*kp+1)*64 + c4];
            *(unsigned*)&W2b[(c4+0)*72 + 2*kp] = pk2(a.x, c.x);
            *(unsigned*)&W2b[(c4+1)*72 + 2*kp] = pk2(a.y, c.y);
            *(unsigned*)&W2b[(c4+2)*72 + 2*kp] = pk2(a.z, c.z);
            *(unsigned*)&W2b[(c4+3)*72 + 2*kp] = pk2(a.w, c.w);
        }
        __syncthreads();
        // ---- FFN1: hid chunk = gelu(t1 @ w1_chunk + b1) ----
        f32x4 h[2][4];
        #pragma unroll
        for (int mt = 0; mt < 2; ++mt)
            #pragma unroll
            for (int nt = 0; nt < 4; ++nt) h[mt][nt] = z;
        #pragma unroll
        for (int ks = 0; ks < 2; ++ks) {
            bf16x8 aF[2];
            #pragma unroll
            for (int mt = 0; mt < 2; ++mt)
                aF[mt] = *(bf16x8*)&At1[(M0+mt*16+lm)*72 + ks*32 + quad*8];
            #pragma unroll
            for (int nt = 0; nt < 4; ++nt) {
                bf16x8 bF = *(bf16x8*)&W1b[(nt*16+lm)*72 + ks*32 + quad*8];
                #pragma unroll
                for (int mt = 0; mt < 2; ++mt)
                    h[mt][nt] = __builtin_amdgcn_mfma_f32_16x16x32_bf16(aF[mt], bF, h[mt][nt], 0,0,0);
            }
        }
        #pragma unroll
        for (int nt = 0; nt < 4; ++nt) {
            float bb = sb1[jc*64 + nt*16 + lm];
            #pragma unroll
            for (int mt = 0; mt < 2; ++mt)
                #pragma unroll
                for (int r = 0; r < 4; ++r) {
                    float hv = gelu_f(h[mt][nt][r] + bb);
                    unsigned u = (unsigned)f2bf(hv);
                    unsigned up = (unsigned)__shfl_xor((int)u, 1, 64);
                    if (!(lm & 1))
                        *(unsigned*)&Hid[(M0+mt*16+quad*4+r)*72 + nt*16 + lm] = (u & 0xffff) | (up << 16);
                }
        }
        // ---- FFN2: out += hid_chunk @ w2_chunk (wave-local Hid rows, no barrier) ----
        #pragma unroll
        for (int ks = 0; ks < 2; ++ks) {
            bf16x8 aH[2];
            #pragma unroll
            for (int mt = 0; mt < 2; ++mt)
                aH[mt] = *(bf16x8*)&Hid[(M0+mt*16+lm)*72 + ks*32 + quad*8];
            #pragma unroll
            for (int nt = 0; nt < 4; ++nt) {
                bf16x8 bF = *(bf16x8*)&W2b[(nt*16+lm)*72 + ks*32 + quad*8];
                #pragma unroll
                for (int mt = 0; mt < 2; ++mt)
                    acc2[mt][nt] = __builtin_amdgcn_mfma_f32_16x16x32_bf16(aH[mt], bF, acc2[mt][nt], 0,0,0);
            }
        }
    }
    // ---- epilogue: residual + b2, LN2, transpose, store ----
    float val[2][4][4], res[2][4][4];
    float sb2v[4], sgv[4], sbbv[4];
    #pragma unroll
    for (int nt = 0; nt < 4; ++nt) {
        int c = nt*16 + lm;
        sb2v[nt] = sb2[c]; sgv[nt] = sg[c]; sbbv[nt] = sbb[c];
    }
    #pragma unroll
    for (int mt = 0; mt < 2; ++mt) {
        #pragma unroll
        for (int r = 0; r < 4; ++r) {
            int pos = M0 + mt*16 + quad*4 + r;
            float s = 0.f;
            #pragma unroll
            for (int nt = 0; nt < 4; ++nt) {
                float tv = bf2f(At1[pos*72 + nt*16 + lm]);
                val[mt][nt][r] = acc2[mt][nt][r] + sb2v[nt] + tv;
                s += val[mt][nt][r];
            }
            s += __shfl_xor(s, 1, 64); s += __shfl_xor(s, 2, 64);
            s += __shfl_xor(s, 4, 64); s += __shfl_xor(s, 8, 64);
            float mean = s*(1.f/64.f);
            float vv = 0.f;
            #pragma unroll
            for (int nt = 0; nt < 4; ++nt) {
                float d = val[mt][nt][r] - mean;
                vv += d*d;
            }
            vv += __shfl_xor(vv, 1, 64); vv += __shfl_xor(vv, 2, 64);
            vv += __shfl_xor(vv, 4, 64); vv += __shfl_xor(vv, 8, 64);
            float rs = rsqrtf(vv*(1.f/64.f) + 1e-5f);
            #pragma unroll
            for (int nt = 0; nt < 4; ++nt)
                res[mt][nt][r] = (val[mt][nt][r] - mean)*rs*sgv[nt] + sbbv[nt];
        }
    }
    __syncthreads();
    float* outT = (float*)WH;   // [c][132], 33792 B <= 36864
    #pragma unroll
    for (int mt = 0; mt < 2; ++mt)
        #pragma unroll
        for (int r = 0; r < 4; ++r)
            #pragma unroll
            for (int nt = 0; nt < 4; ++nt)
                outT[(nt*16+lm)*132 + M0 + mt*16 + quad*4 + r] = res[mt][nt][r];
    __syncthreads();
    for (int vi = tid; vi < 2048; vi += 256) {
        int c = vi >> 5, p4 = (vi & 31)*4;
        *(float4*)&outp[((size_t)(b*64+c))*HWSZ + p0 + p4] = *(const float4*)&outT[c*132 + p4];
    }
}

extern "C" void kernel_launch(void* const* d_in, const int* in_sizes, int n_in,
                              void* d_out, int out_size, void* d_ws, size_t ws_size,
                              hipStream_t stream) {
    const float* x      = (const float*)d_in[0];
    const float* y      = (const float*)d_in[1];
    const float* th     = (const float*)d_in[2];
    const float* dw1_w  = (const float*)d_in[3];
    const float* dw1_b  = (const float*)d_in[4];
    const float* dw2_w  = (const float*)d_in[5];
    const float* dw2_b  = (const float*)d_in[6];
    const float* qw     = (const float*)d_in[7];
    const float* qb     = (const float*)d_in[8];
    const float* kw     = (const float*)d_in[9];
    const float* kb     = (const float*)d_in[10];
    const float* vw     = (const float*)d_in[11];
    const float* vb     = (const float*)d_in[12];
    const float* lepe_w = (const float*)d_in[13];
    const float* lepe_b = (const float*)d_in[14];
    const float* dt_w   = (const float*)d_in[15];
    const float* dt_bias= (const float*)d_in[16];
    const float* A_log  = (const float*)d_in[17];
    const float* ow     = (const float*)d_in[18];
    const float* ob     = (const float*)d_in[19];
    const float* n1_g   = (const float*)d_in[20];
    const float* n1_b   = (const float*)d_in[21];
    const float* ffn_w1 = (const float*)d_in[22];
    const float* ffn_b1 = (const float*)d_in[23];
    const float* ffn_w2 = (const float*)d_in[24];
    const float* ffn_b2 = (const float*)d_in[25];
    const float* n2_g   = (const float*)d_in[26];
    const float* n2_b   = (const float*)d_in[27];
    float* out = (float*)d_out;

    const size_t SZ = 4194304;   // B*C*H*W elements
    float* ws    = (float*)d_ws;
    float* fused = ws + 0*SZ;    // reused as v_w after kernel 4
    float* qrb   = ws + 1*SZ;
    float* krb   = ws + 2*SZ;
    float* v5b   = ws + 3*SZ;
    float* lepeb = ws + 4*SZ;
    float* vhb   = ws + 5*SZ;
    float* o1b   = ws + 6*SZ;
    float* attnb = ws + 7*SZ;
    float* t1b   = ws + 8*SZ;
    float* dacs  = ws + 9*SZ;               // 262144
    float* dbcs  = ws + 9*SZ + 262144;      // 262144

    k_fuse<<<1024, 256, 0, stream>>>(y, th, dw1_w, dw1_b, dw2_w, dw2_b, fused);
    k_qkv<<<1024, 256, 0, stream>>>(x, fused, qw, qb, kw, kb, vw, vb,
                                    dt_w, dt_bias, A_log, qrb, krb, v5b, dacs, dbcs);
    k_cumsum<<<1024, 256, 0, stream>>>(dacs, dbcs);
    k_lepe<<<512, 256, 0, stream>>>(v5b, lepe_w, lepe_b, lepeb);
    k_attn_w1<<<2048, 256, 0, stream>>>(qrb, krb, v5b, dacs, fused);
    k_attn_h<<<2048, 256, 0, stream>>>(qrb, krb, v5b, fused, dbcs, vhb, o1b);
    k_attn_w2<<<2048, 256, 0, stream>>>(qrb, krb, vhb, o1b, dacs, lepeb, attnb);
    k_proj_ln<<<512, 256, 0, stream>>>(attnb, x, ow, ob, n1_g, n1_b, t1b);
    k_ffn<<<512, 256, 0, stream>>>(t1b, ffn_w1, ffn_b1, ffn_w2, ffn_b2, n2_g, n2_b, out);
}

// Round 7
// 330.611 us; speedup vs baseline: 3.2994x; 1.0717x over previous
//
#include <hip/hip_runtime.h>
#include <math.h>

#define HWSZ 16384

typedef __attribute__((ext_vector_type(8))) short bf16x8;
typedef __attribute__((ext_vector_type(4))) float f32x4;
typedef unsigned short u16;

union U4 { uint4 v; u16 s[8]; };
union U2 { uint2 v; u16 s[4]; };

__device__ __forceinline__ float gelu_f(float v) {
    return 0.5f * v * (1.0f + erff(v * 0.70710678118654752f));
}
__device__ __forceinline__ float splus_f(float v) {
    return (v > 20.f) ? v : log1pf(expf(v));
}
__device__ __forceinline__ u16 f2bf(float f) {
    union { float f; unsigned u; } v; v.f = f;
    unsigned r = (v.u + 0x7FFF + ((v.u >> 16) & 1)) >> 16;
    return (u16)r;
}
__device__ __forceinline__ unsigned pk2(float a, float b) {
    return (unsigned)f2bf(a) | ((unsigned)f2bf(b) << 16);
}
__device__ __forceinline__ float bf2f(u16 s) {
    union { unsigned u; float f; } v; v.u = ((unsigned)s) << 16; return v.f;
}

// ---------------- Kernel 1: fusion gate -> fused bf16 [c][p] ----------------
#define W1S 68
__global__ __launch_bounds__(256) void k_fuse(
    const float* __restrict__ y, const float* __restrict__ th,
    const float* __restrict__ w1, const float* __restrict__ b1,
    const float* __restrict__ w2, const float* __restrict__ b2,
    u16* __restrict__ fused)
{
    __shared__ u16 fsh[8192];
    __shared__ float w1t[128*W1S];
    int tid = threadIdx.x;
    int g = blockIdx.x;
    int b = g >> 8;
    int p0 = (g & 255)*64;
    for (int i = tid; i < 8192; i += 256) {
        int o = i >> 7, c = i & 127;
        w1t[c*W1S + o] = w1[i];
    }
    for (int vi = tid; vi < 1024; vi += 256) {
        int c = vi >> 4, p4 = (vi & 15)*4;
        float4 yv = *(const float4*)&y [((size_t)(b*64+c))*HWSZ + p0 + p4];
        float4 tv = *(const float4*)&th[((size_t)(b*64+c))*HWSZ + p0 + p4];
        *(uint2*)&fsh[c*64 + p4]      = make_uint2(pk2(yv.x,yv.y), pk2(yv.z,yv.w));
        *(uint2*)&fsh[(64+c)*64 + p4] = make_uint2(pk2(tv.x,tv.y), pk2(tv.z,tv.w));
    }
    __syncthreads();
    int lane = tid & 63, wv = tid >> 6;
    int po = lane & 15, oc = lane >> 4;
    int pos = wv*16 + po;
    float acc[16];
    #pragma unroll
    for (int d4 = 0; d4 < 4; ++d4) {
        float4 bv = *(const float4*)&b1[oc*16 + d4*4];
        acc[d4*4+0]=bv.x; acc[d4*4+1]=bv.y; acc[d4*4+2]=bv.z; acc[d4*4+3]=bv.w;
    }
    for (int c = 0; c < 128; ++c) {
        float xc = bf2f(fsh[c*64 + pos]);
        #pragma unroll
        for (int d4 = 0; d4 < 4; ++d4) {
            float4 wv4 = *(const float4*)&w1t[c*W1S + oc*16 + d4*4];
            acc[d4*4+0] += wv4.x*xc; acc[d4*4+1] += wv4.y*xc;
            acc[d4*4+2] += wv4.z*xc; acc[d4*4+3] += wv4.w*xc;
        }
    }
    float l0 = 0.f, l1 = 0.f;
    #pragma unroll
    for (int d4 = 0; d4 < 4; ++d4) {
        float4 wa4 = *(const float4*)&w2[oc*16 + d4*4];
        float4 wb4 = *(const float4*)&w2[64 + oc*16 + d4*4];
        float h0 = fmaxf(acc[d4*4+0],0.f), h1 = fmaxf(acc[d4*4+1],0.f);
        float h2 = fmaxf(acc[d4*4+2],0.f), h3 = fmaxf(acc[d4*4+3],0.f);
        l0 += wa4.x*h0 + wa4.y*h1 + wa4.z*h2 + wa4.w*h3;
        l1 += wb4.x*h0 + wb4.y*h1 + wb4.z*h2 + wb4.w*h3;
    }
    l0 += __shfl_xor(l0, 16, 64); l0 += __shfl_xor(l0, 32, 64);
    l1 += __shfl_xor(l1, 16, 64); l1 += __shfl_xor(l1, 32, 64);
    l0 += b2[0]; l1 += b2[1];
    float m = fmaxf(l0, l1);
    float e0 = __expf(l0 - m), e1 = __expf(l1 - m);
    float inv = 1.f/(e0 + e1);
    float wa = e0*inv, wb = e1*inv;
    u16* fb = fused + (size_t)b*64*HWSZ + p0 + pos;
    #pragma unroll
    for (int u = 0; u < 16; ++u) {
        int c = oc*16 + u;
        float fv = bf2f(fsh[c*64 + pos])*wa + bf2f(fsh[(64+c)*64 + pos])*wb;
        fb[(size_t)c*HWSZ] = f2bf(fv);
    }
}

// ---------------- Kernel 2: QKV + RoPE + dt (MFMA) ----------------
// 128 pos/block, grid 512. Q=x@qw, K/V=fused@{kw,vw}; outputs bf16 (b,n,p,d).
__global__ __launch_bounds__(256) void k_qkv(
    const float* __restrict__ x, const u16* __restrict__ fused,
    const float* __restrict__ qw, const float* __restrict__ qb,
    const float* __restrict__ kw, const float* __restrict__ kb,
    const float* __restrict__ vw, const float* __restrict__ vb,
    const float* __restrict__ dtw, const float* __restrict__ dtb,
    const float* __restrict__ alog,
    u16* __restrict__ qr, u16* __restrict__ kr, u16* __restrict__ v5,
    float* __restrict__ da, float* __restrict__ db)
{
    __shared__ u16 Ax[128*72];       // x bf16 [p][c]
    __shared__ u16 Af[128*72];       // fused bf16 [p][c]
    __shared__ u16 Bq[64*72], Bk[64*72], Bv[64*72];  // [o][c]
    int tid = threadIdx.x, bid = blockIdx.x;
    int pbase = bid*128;
    int b = pbase >> 14, p0 = pbase & 16383;
    // stage x (fp32 -> bf16, transpose to [p][c])
    for (int vi = tid; vi < 2048; vi += 256) {
        int c = vi >> 5, pg = (vi & 31)*4;
        float4 xv = *(const float4*)&x[((size_t)(b*64+c))*HWSZ + p0 + pg];
        Ax[(pg+0)*72 + c] = f2bf(xv.x);
        Ax[(pg+1)*72 + c] = f2bf(xv.y);
        Ax[(pg+2)*72 + c] = f2bf(xv.z);
        Ax[(pg+3)*72 + c] = f2bf(xv.w);
    }
    // stage fused (bf16, transpose)
    for (int vi = tid; vi < 1024; vi += 256) {
        int c = vi >> 4, pg = (vi & 15)*8;
        U4 fv; fv.v = *(const uint4*)&fused[((size_t)(b*64+c))*HWSZ + p0 + pg];
        #pragma unroll
        for (int u = 0; u < 8; ++u) Af[(pg+u)*72 + c] = fv.s[u];
    }
    // stage weights transposed [o][c]
    for (int vi = tid; vi < 1024; vi += 256) {
        int c = vi >> 4, o4 = (vi & 15)*4;
        float4 q = *(const float4*)&qw[c*64 + o4];
        float4 k = *(const float4*)&kw[c*64 + o4];
        float4 v = *(const float4*)&vw[c*64 + o4];
        Bq[(o4+0)*72+c]=f2bf(q.x); Bq[(o4+1)*72+c]=f2bf(q.y); Bq[(o4+2)*72+c]=f2bf(q.z); Bq[(o4+3)*72+c]=f2bf(q.w);
        Bk[(o4+0)*72+c]=f2bf(k.x); Bk[(o4+1)*72+c]=f2bf(k.y); Bk[(o4+2)*72+c]=f2bf(k.z); Bk[(o4+3)*72+c]=f2bf(k.w);
        Bv[(o4+0)*72+c]=f2bf(v.x); Bv[(o4+1)*72+c]=f2bf(v.y); Bv[(o4+2)*72+c]=f2bf(v.z); Bv[(o4+3)*72+c]=f2bf(v.w);
    }
    __syncthreads();
    int lane = tid & 63, wv = tid >> 6;
    int quad = lane >> 4, lm = lane & 15;
    int M0 = wv*32;
    f32x4 z = {0.f,0.f,0.f,0.f};
    f32x4 accQ[2][4], accK[2][4], accV[2][4];
    #pragma unroll
    for (int mt = 0; mt < 2; ++mt)
        #pragma unroll
        for (int nt = 0; nt < 4; ++nt) { accQ[mt][nt]=z; accK[mt][nt]=z; accV[mt][nt]=z; }
    #pragma unroll
    for (int ks = 0; ks < 2; ++ks) {
        bf16x8 aX[2], aF[2];
        #pragma unroll
        for (int mt = 0; mt < 2; ++mt) {
            aX[mt] = *(bf16x8*)&Ax[(M0+mt*16+lm)*72 + ks*32 + quad*8];
            aF[mt] = *(bf16x8*)&Af[(M0+mt*16+lm)*72 + ks*32 + quad*8];
        }
        #pragma unroll
        for (int nt = 0; nt < 4; ++nt) {
            bf16x8 bQ = *(bf16x8*)&Bq[(nt*16+lm)*72 + ks*32 + quad*8];
            bf16x8 bK = *(bf16x8*)&Bk[(nt*16+lm)*72 + ks*32 + quad*8];
            bf16x8 bV = *(bf16x8*)&Bv[(nt*16+lm)*72 + ks*32 + quad*8];
            #pragma unroll
            for (int mt = 0; mt < 2; ++mt) {
                accQ[mt][nt] = __builtin_amdgcn_mfma_f32_16x16x32_bf16(aX[mt], bQ, accQ[mt][nt], 0,0,0);
                accK[mt][nt] = __builtin_amdgcn_mfma_f32_16x16x32_bf16(aF[mt], bK, accK[mt][nt], 0,0,0);
                accV[mt][nt] = __builtin_amdgcn_mfma_f32_16x16x32_bf16(aF[mt], bV, accV[mt][nt], 0,0,0);
            }
        }
    }
    // ---- dt / da / db (from Ax) ----
    {
        float dtw_[32];
        #pragma unroll
        for (int i = 0; i < 32; ++i) dtw_[i] = dtw[i];
        #pragma unroll
        for (int rep = 0; rep < 2; ++rep) {
            int pair = tid + rep*256;
            int p = pair >> 2, n = pair & 3;
            float dt0 = 0.f, dt1 = 0.f;
            #pragma unroll
            for (int d = 0; d < 16; ++d) {
                float xv = bf2f(Ax[p*72 + n*16 + d]);
                dt0 += xv*dtw_[2*d];
                dt1 += xv*dtw_[2*d+1];
            }
            float A = -expf(alog[n]);
            float bb = dtb[n];
            int P = p0 + p;
            int h = P >> 7, w = P & 127;
            da[((b*128+h)*4+n)*128 + w] = splus_f(dt0+bb)*A;
            db[((b*128+w)*4+n)*128 + h] = splus_f(dt1+bb)*A;
        }
    }
    // ---- epilogue: bias, RoPE, pack bf16, store ----
    float qbv[4], kbv[4], vbv[4];
    #pragma unroll
    for (int nt = 0; nt < 4; ++nt) {
        qbv[nt] = qb[nt*16+lm]; kbv[nt] = kb[nt*16+lm]; vbv[nt] = vb[nt*16+lm];
    }
    bool evn = !(lm & 1);
    float ang = exp2f(-1.89824462565f * (float)(lm >> 1));
    int bb4 = b*4;
    #pragma unroll
    for (int mt = 0; mt < 2; ++mt) {
        #pragma unroll
        for (int r = 0; r < 4; ++r) {
            int P = p0 + M0 + mt*16 + quad*4 + r;
            float sn_, cs_;
            sincosf((float)P * ang, &sn_, &cs_);
            #pragma unroll
            for (int nt = 0; nt < 4; ++nt) {
                // Q
                float vq = accQ[mt][nt][r] + qbv[nt];
                float pq = __shfl_xor(vq, 1, 64);
                float rq = evn ? vq*cs_ - pq*sn_ : vq*cs_ + pq*sn_;
                unsigned uq = f2bf(rq);
                unsigned upq = (unsigned)__shfl_xor((int)uq, 1, 64);
                // K
                float vk = (accK[mt][nt][r] + kbv[nt])*0.25f;
                float pk = __shfl_xor(vk, 1, 64);
                float rk = evn ? vk*cs_ - pk*sn_ : vk*cs_ + pk*sn_;
                unsigned uk = f2bf(rk);
                unsigned upk = (unsigned)__shfl_xor((int)uk, 1, 64);
                // V
                unsigned uv = f2bf(accV[mt][nt][r] + vbv[nt]);
                unsigned upv = (unsigned)__shfl_xor((int)uv, 1, 64);
                if (evn) {
                    size_t off = ((size_t)(bb4+nt)*HWSZ + P)*16 + lm;
                    *(unsigned*)&qr[off] = (uq & 0xffff) | (upq << 16);
                    *(unsigned*)&kr[off] = (uk & 0xffff) | (upk << 16);
                    *(unsigned*)&v5[off] = (uv & 0xffff) | (upv << 16);
                }
            }
        }
    }
}

// ---------------- Kernel 2b: cumsums ----------------
__global__ __launch_bounds__(256) void k_cumsum(float* __restrict__ da, float* __restrict__ db)
{
    int gw = (blockIdx.x*256 + threadIdx.x) >> 6;
    int lane = threadIdx.x & 63;
    float* base = (gw < 2048) ? (da + (size_t)gw*128) : (db + (size_t)(gw-2048)*128);
    float2 e = *(float2*)&base[lane*2];
    float s = e.x + e.y;
    #pragma unroll
    for (int d = 1; d < 64; d <<= 1) {
        float t = __shfl_up(s, d, 64);
        if (lane >= d) s += t;
    }
    float excl = s - (e.x + e.y);
    float2 o;
    o.x = excl + e.x;
    o.y = excl + e.x + e.y;
    *(float2*)&base[lane*2] = o;
}

// ---------------- Kernel 3: LePE depthwise 5x5 conv (v5 bf16 in, fp32 out) ----------------
#define LROW 328
__global__ __launch_bounds__(256) void k_lepe(
    const u16* __restrict__ v5, const float* __restrict__ lw,
    const float* __restrict__ lb, float* __restrict__ lepe)
{
    __shared__ float sv[36*LROW];
    __shared__ float swt[400];
    int tid = threadIdx.x, bid = blockIdx.x;
    int tw = bid & 7, th_ = (bid >> 3) & 3, n = (bid >> 5) & 3, b = bid >> 7;
    int bn = b*4 + n;
    int h0 = th_*32, w0 = tw*16;
    for (int i = tid; i < 400; i += 256) {
        int tap = i >> 4, d = i & 15;
        swt[i] = lw[tap*64 + n*16 + d];
    }
    const u16* vb = v5 + (size_t)bn*HWSZ*16;
    for (int vi = tid; vi < 1440; vi += 256) {
        int cell = vi >> 1, half = vi & 1;
        int hh = cell/20, ww = cell - hh*20;
        int h = h0 - 2 + hh, w = w0 - 2 + ww;
        U4 val; val.v = make_uint4(0,0,0,0);
        if (h >= 0 && h < 128 && w >= 0 && w < 128)
            val.v = *(const uint4*)&vb[((size_t)(h*128+w))*16 + half*8];
        float* dst = &sv[hh*LROW + ww*16 + half*8];
        #pragma unroll
        for (int u = 0; u < 8; ++u) dst[u] = bf2f(val.s[u]);
    }
    __syncthreads();
    int df = (tid & 3)*4;
    int s  = tid >> 2;
    int ph = s >> 1;
    int pw = (s & 1)*8;
    float4 bv = *(const float4*)&lb[n*16 + df];
    float acc[8][4];
    #pragma unroll
    for (int ow = 0; ow < 8; ++ow) {
        acc[ow][0] = bv.x; acc[ow][1] = bv.y; acc[ow][2] = bv.z; acc[ow][3] = bv.w;
    }
    #pragma unroll
    for (int ky = 0; ky < 5; ++ky) {
        float wgt[5][4];
        #pragma unroll
        for (int kx = 0; kx < 5; ++kx) {
            float4 wv = *(const float4*)&swt[(ky*5+kx)*16 + df];
            wgt[kx][0]=wv.x; wgt[kx][1]=wv.y; wgt[kx][2]=wv.z; wgt[kx][3]=wv.w;
        }
        float dat[13][4];
        #pragma unroll
        for (int c = 0; c < 13; ++c) {
            float4 dv = *(const float4*)&sv[(ph+ky)*LROW + (pw+c)*16 + df];
            dat[c][0]=dv.x; dat[c][1]=dv.y; dat[c][2]=dv.z; dat[c][3]=dv.w;
        }
        #pragma unroll
        for (int ow = 0; ow < 8; ++ow)
            #pragma unroll
            for (int kx = 0; kx < 5; ++kx)
                #pragma unroll
                for (int u = 0; u < 4; ++u)
                    acc[ow][u] += dat[ow+kx][u]*wgt[kx][u];
    }
    float* ob = lepe + ((size_t)bn*HWSZ + (size_t)(h0+ph)*128 + w0+pw)*16 + df;
    #pragma unroll
    for (int ow = 0; ow < 8; ++ow)
        *(float4*)&ob[ow*16] = make_float4(acc[ow][0],acc[ow][1],acc[ow][2],acc[ow][3]);
}

// ---------------- Kernel 4: row attention pass 1 -> v_w (MFMA, bf16 IO) ----------------
__global__ __launch_bounds__(256) void k_attn_w1(
    const u16* __restrict__ qr, const u16* __restrict__ kr,
    const u16* __restrict__ v5, const float* __restrict__ dacs,
    u16* __restrict__ vwb)
{
    __shared__ u16 Qs[128*40], Ks[128*40], Vt[16*136], Ps[128*136];
    __shared__ float csr[128], linv[128];
    int tid = threadIdx.x, bid = blockIdx.x;
    int h = bid & 127, n = (bid >> 7) & 3, b = bid >> 9;
    size_t rowoff = ((size_t)((b*4+n)*128 + h)) * 2048;
    {   // zero pad k=16..31
        int i = tid >> 1, seg = (tid & 1)*8;
        *(uint4*)&Qs[i*40 + 16 + seg] = make_uint4(0,0,0,0);
        *(uint4*)&Ks[i*40 + 16 + seg] = make_uint4(0,0,0,0);
    }
    {   // direct bf16 copy
        int i = tid >> 1, half = tid & 1;
        *(uint4*)&Qs[i*40 + half*8] = *(const uint4*)&qr[rowoff + i*16 + half*8];
        *(uint4*)&Ks[i*40 + half*8] = *(const uint4*)&kr[rowoff + i*16 + half*8];
    }
    {   // V^T
        int jp = tid >> 2, q4 = tid & 3;
        U2 a, c;
        a.v = *(const uint2*)&v5[rowoff + (2*jp)*16 + q4*4];
        c.v = *(const uint2*)&v5[rowoff + (2*jp+1)*16 + q4*4];
        #pragma unroll
        for (int u = 0; u < 4; ++u)
            *(unsigned*)&Vt[(q4*4+u)*136 + 2*jp] = (unsigned)a.s[u] | ((unsigned)c.s[u] << 16);
    }
    if (tid < 128) csr[tid] = dacs[((b*128+h)*4+n)*128 + tid];
    __syncthreads();
    int lane = tid & 63, wv = tid >> 6;
    int quad = lane >> 4, lm = lane & 15;
    int r0 = wv*32, r1 = wv*32 + 16;
    bf16x8 aQ0 = *(bf16x8*)&Qs[(r0+lm)*40 + quad*8];
    bf16x8 aQ1 = *(bf16x8*)&Qs[(r1+lm)*40 + quad*8];
    float csj[8], csi0[4], csi1[4];
    #pragma unroll
    for (int jt = 0; jt < 8; ++jt) csj[jt] = csr[jt*16+lm];
    #pragma unroll
    for (int r = 0; r < 4; ++r) { csi0[r] = csr[r0+quad*4+r]; csi1[r] = csr[r1+quad*4+r]; }
    float ls0[4]={0,0,0,0}, ls1[4]={0,0,0,0};
    f32x4 z = {0.f,0.f,0.f,0.f};
    #pragma unroll
    for (int jt = 0; jt < 8; ++jt) {
        bf16x8 bK = *(bf16x8*)&Ks[(jt*16+lm)*40 + quad*8];
        f32x4 s0 = __builtin_amdgcn_mfma_f32_16x16x32_bf16(aQ0, bK, z, 0,0,0);
        f32x4 s1 = __builtin_amdgcn_mfma_f32_16x16x32_bf16(aQ1, bK, z, 0,0,0);
        #pragma unroll
        for (int r = 0; r < 4; ++r) {
            float e0 = __expf(s0[r] - fabsf(csi0[r]-csj[jt])); ls0[r] += e0;
            float e1 = __expf(s1[r] - fabsf(csi1[r]-csj[jt])); ls1[r] += e1;
            Ps[(r0+quad*4+r)*136 + jt*16+lm] = f2bf(e0);
            Ps[(r1+quad*4+r)*136 + jt*16+lm] = f2bf(e1);
        }
    }
    #pragma unroll
    for (int r = 0; r < 4; ++r) {
        #pragma unroll
        for (int m = 1; m < 16; m <<= 1) {
            ls0[r] += __shfl_xor(ls0[r], m, 64);
            ls1[r] += __shfl_xor(ls1[r], m, 64);
        }
        if (lm == 0) { linv[r0+quad*4+r] = 1.f/ls0[r]; linv[r1+quad*4+r] = 1.f/ls1[r]; }
    }
    __syncthreads();
    f32x4 acc0 = z, acc1 = z;
    #pragma unroll
    for (int c = 0; c < 4; ++c) {
        bf16x8 bV  = *(bf16x8*)&Vt[lm*136 + c*32 + quad*8];
        bf16x8 aP0 = *(bf16x8*)&Ps[(r0+lm)*136 + c*32 + quad*8];
        bf16x8 aP1 = *(bf16x8*)&Ps[(r1+lm)*136 + c*32 + quad*8];
        acc0 = __builtin_amdgcn_mfma_f32_16x16x32_bf16(aP0, bV, acc0, 0,0,0);
        acc1 = __builtin_amdgcn_mfma_f32_16x16x32_bf16(aP1, bV, acc1, 0,0,0);
    }
    bool evn = !(lm & 1);
    #pragma unroll
    for (int r = 0; r < 4; ++r) {
        int i0 = r0+quad*4+r, i1 = r1+quad*4+r;
        unsigned u0 = f2bf(acc0[r]*linv[i0]);
        unsigned u1 = f2bf(acc1[r]*linv[i1]);
        unsigned up0 = (unsigned)__shfl_xor((int)u0, 1, 64);
        unsigned up1 = (unsigned)__shfl_xor((int)u1, 1, 64);
        if (evn) {
            *(unsigned*)&vwb[rowoff + (size_t)i0*16 + lm] = (u0 & 0xffff) | (up0 << 16);
            *(unsigned*)&vwb[rowoff + (size_t)i1*16 + lm] = (u1 & 0xffff) | (up1 << 16);
        }
    }
}

// ---------------- Kernel 5: column attention -> v_h, out1 (MFMA, bf16 IO) ----------------
__global__ __launch_bounds__(256) void k_attn_h(
    const u16* __restrict__ qr, const u16* __restrict__ kr,
    const u16* __restrict__ v5, const u16* __restrict__ vwb,
    const float* __restrict__ dbcs,
    u16* __restrict__ vhb, u16* __restrict__ o1b)
{
    __shared__ u16 Qs[128*40], Ks[128*40], Vt[16*136], Wt[16*136], Ps[128*136];
    __shared__ float csr[128], linv[128];
    int tid = threadIdx.x, bid = blockIdx.x;
    int w = bid & 127, n = (bid >> 7) & 3, b = bid >> 9;
    int bn = b*4 + n;
    size_t base = ((size_t)bn*16384 + w)*16;
    {
        int i = tid >> 1, seg = (tid & 1)*8;
        *(uint4*)&Qs[i*40 + 16 + seg] = make_uint4(0,0,0,0);
        *(uint4*)&Ks[i*40 + 16 + seg] = make_uint4(0,0,0,0);
    }
    {
        int i = tid >> 1, half = tid & 1;
        *(uint4*)&Qs[i*40 + half*8] = *(const uint4*)&qr[base + (size_t)i*2048 + half*8];
        *(uint4*)&Ks[i*40 + half*8] = *(const uint4*)&kr[base + (size_t)i*2048 + half*8];
    }
    {
        int jp = tid >> 2, q4 = tid & 3;
        U2 a, c, e, f;
        a.v = *(const uint2*)&v5 [base + (size_t)(2*jp)*2048 + q4*4];
        c.v = *(const uint2*)&v5 [base + (size_t)(2*jp+1)*2048 + q4*4];
        e.v = *(const uint2*)&vwb[base + (size_t)(2*jp)*2048 + q4*4];
        f.v = *(const uint2*)&vwb[base + (size_t)(2*jp+1)*2048 + q4*4];
        #pragma unroll
        for (int u = 0; u < 4; ++u) {
            *(unsigned*)&Vt[(q4*4+u)*136 + 2*jp] = (unsigned)a.s[u] | ((unsigned)c.s[u] << 16);
            *(unsigned*)&Wt[(q4*4+u)*136 + 2*jp] = (unsigned)e.s[u] | ((unsigned)f.s[u] << 16);
        }
    }
    if (tid < 128) csr[tid] = dbcs[((b*128+w)*4+n)*128 + tid];
    __syncthreads();
    int lane = tid & 63, wv = tid >> 6;
    int quad = lane >> 4, lm = lane & 15;
    int r0 = wv*32, r1 = wv*32 + 16;
    bf16x8 aQ0 = *(bf16x8*)&Qs[(r0+lm)*40 + quad*8];
    bf16x8 aQ1 = *(bf16x8*)&Qs[(r1+lm)*40 + quad*8];
    float csj[8], csi0[4], csi1[4];
    #pragma unroll
    for (int jt = 0; jt < 8; ++jt) csj[jt] = csr[jt*16+lm];
    #pragma unroll
    for (int r = 0; r < 4; ++r) { csi0[r] = csr[r0+quad*4+r]; csi1[r] = csr[r1+quad*4+r]; }
    float ls0[4]={0,0,0,0}, ls1[4]={0,0,0,0};
    f32x4 z = {0.f,0.f,0.f,0.f};
    #pragma unroll
    for (int jt = 0; jt < 8; ++jt) {
        bf16x8 bK = *(bf16x8*)&Ks[(jt*16+lm)*40 + quad*8];
        f32x4 s0 = __builtin_amdgcn_mfma_f32_16x16x32_bf16(aQ0, bK, z, 0,0,0);
        f32x4 s1 = __builtin_amdgcn_mfma_f32_16x16x32_bf16(aQ1, bK, z, 0,0,0);
        #pragma unroll
        for (int r = 0; r < 4; ++r) {
            float e0 = __expf(s0[r] - fabsf(csi0[r]-csj[jt])); ls0[r] += e0;
            float e1 = __expf(s1[r] - fabsf(csi1[r]-csj[jt])); ls1[r] += e1;
            Ps[(r0+quad*4+r)*136 + jt*16+lm] = f2bf(e0);
            Ps[(r1+quad*4+r)*136 + jt*16+lm] = f2bf(e1);
        }
    }
    #pragma unroll
    for (int r = 0; r < 4; ++r) {
        #pragma unroll
        for (int m = 1; m < 16; m <<= 1) {
            ls0[r] += __shfl_xor(ls0[r], m, 64);
            ls1[r] += __shfl_xor(ls1[r], m, 64);
        }
        if (lm == 0) { linv[r0+quad*4+r] = 1.f/ls0[r]; linv[r1+quad*4+r] = 1.f/ls1[r]; }
    }
    __syncthreads();
    f32x4 aV0 = z, aV1 = z, aW0 = z, aW1 = z;
    #pragma unroll
    for (int c = 0; c < 4; ++c) {
        bf16x8 bV  = *(bf16x8*)&Vt[lm*136 + c*32 + quad*8];
        bf16x8 bW  = *(bf16x8*)&Wt[lm*136 + c*32 + quad*8];
        bf16x8 aP0 = *(bf16x8*)&Ps[(r0+lm)*136 + c*32 + quad*8];
        bf16x8 aP1 = *(bf16x8*)&Ps[(r1+lm)*136 + c*32 + quad*8];
        aV0 = __builtin_amdgcn_mfma_f32_16x16x32_bf16(aP0, bV, aV0, 0,0,0);
        aV1 = __builtin_amdgcn_mfma_f32_16x16x32_bf16(aP1, bV, aV1, 0,0,0);
        aW0 = __builtin_amdgcn_mfma_f32_16x16x32_bf16(aP0, bW, aW0, 0,0,0);
        aW1 = __builtin_amdgcn_mfma_f32_16x16x32_bf16(aP1, bW, aW1, 0,0,0);
    }
    size_t obase = ((size_t)bn*16384 + (size_t)w*128)*16;   // [w][h][d]
    bool evn = !(lm & 1);
    #pragma unroll
    for (int r = 0; r < 4; ++r) {
        int i0 = r0+quad*4+r, i1 = r1+quad*4+r;
        float v0 = linv[i0], v1 = linv[i1];
        unsigned a0 = f2bf(aV0[r]*v0), a1 = f2bf(aV1[r]*v1);
        unsigned b0 = f2bf(aW0[r]*v0), b1 = f2bf(aW1[r]*v1);
        unsigned ap0 = (unsigned)__shfl_xor((int)a0,1,64), ap1 = (unsigned)__shfl_xor((int)a1,1,64);
        unsigned bp0 = (unsigned)__shfl_xor((int)b0,1,64), bp1 = (unsigned)__shfl_xor((int)b1,1,64);
        if (evn) {
            *(unsigned*)&vhb[obase + (size_t)i0*16 + lm] = (a0 & 0xffff) | (ap0 << 16);
            *(unsigned*)&vhb[obase + (size_t)i1*16 + lm] = (a1 & 0xffff) | (ap1 << 16);
            *(unsigned*)&o1b[obase + (size_t)i0*16 + lm] = (b0 & 0xffff) | (bp0 << 16);
            *(unsigned*)&o1b[obase + (size_t)i1*16 + lm] = (b1 & 0xffff) | (bp1 << 16);
        }
    }
}

// ---------------- Kernel 6: row attention pass 2 -> out2, combine + lepe ----------------
__global__ __launch_bounds__(256) void k_attn_w2(
    const u16* __restrict__ qr, const u16* __restrict__ kr,
    const u16* __restrict__ vhb, const u16* __restrict__ o1b,
    const float* __restrict__ dacs, const float* __restrict__ lepe,
    u16* __restrict__ attn)
{
    __shared__ u16 Qs[128*40], Ks[128*40], Vt[16*136], Ps[128*136];
    __shared__ float csr[128], linv[128];
    int tid = threadIdx.x, bid = blockIdx.x;
    int h = bid & 127, n = (bid >> 7) & 3, b = bid >> 9;
    int bn = b*4 + n;
    size_t rowoff = ((size_t)(bn*128 + h)) * 2048;
    size_t vbase  = (size_t)bn*262144 + (size_t)h*16;
    {
        int i = tid >> 1, seg = (tid & 1)*8;
        *(uint4*)&Qs[i*40 + 16 + seg] = make_uint4(0,0,0,0);
        *(uint4*)&Ks[i*40 + 16 + seg] = make_uint4(0,0,0,0);
    }
    {
        int i = tid >> 1, half = tid & 1;
        *(uint4*)&Qs[i*40 + half*8] = *(const uint4*)&qr[rowoff + i*16 + half*8];
        *(uint4*)&Ks[i*40 + half*8] = *(const uint4*)&kr[rowoff + i*16 + half*8];
    }
    {
        int jp = tid >> 2, q4 = tid & 3;
        U2 a, c;
        a.v = *(const uint2*)&vhb[vbase + (size_t)(2*jp)*2048 + q4*4];
        c.v = *(const uint2*)&vhb[vbase + (size_t)(2*jp+1)*2048 + q4*4];
        #pragma unroll
        for (int u = 0; u < 4; ++u)
            *(unsigned*)&Vt[(q4*4+u)*136 + 2*jp] = (unsigned)a.s[u] | ((unsigned)c.s[u] << 16);
    }
    if (tid < 128) csr[tid] = dacs[((b*128+h)*4+n)*128 + tid];
    __syncthreads();
    int lane = tid & 63, wv = tid >> 6;
    int quad = lane >> 4, lm = lane & 15;
    int r0 = wv*32, r1 = wv*32 + 16;
    bf16x8 aQ0 = *(bf16x8*)&Qs[(r0+lm)*40 + quad*8];
    bf16x8 aQ1 = *(bf16x8*)&Qs[(r1+lm)*40 + quad*8];
    float csj[8], csi0[4], csi1[4];
    #pragma unroll
    for (int jt = 0; jt < 8; ++jt) csj[jt] = csr[jt*16+lm];
    #pragma unroll
    for (int r = 0; r < 4; ++r) { csi0[r] = csr[r0+quad*4+r]; csi1[r] = csr[r1+quad*4+r]; }
    float ls0[4]={0,0,0,0}, ls1[4]={0,0,0,0};
    f32x4 z = {0.f,0.f,0.f,0.f};
    #pragma unroll
    for (int jt = 0; jt < 8; ++jt) {
        bf16x8 bK = *(bf16x8*)&Ks[(jt*16+lm)*40 + quad*8];
        f32x4 s0 = __builtin_amdgcn_mfma_f32_16x16x32_bf16(aQ0, bK, z, 0,0,0);
        f32x4 s1 = __builtin_amdgcn_mfma_f32_16x16x32_bf16(aQ1, bK, z, 0,0,0);
        #pragma unroll
        for (int r = 0; r < 4; ++r) {
            float e0 = __expf(s0[r] - fabsf(csi0[r]-csj[jt])); ls0[r] += e0;
            float e1 = __expf(s1[r] - fabsf(csi1[r]-csj[jt])); ls1[r] += e1;
            Ps[(r0+quad*4+r)*136 + jt*16+lm] = f2bf(e0);
            Ps[(r1+quad*4+r)*136 + jt*16+lm] = f2bf(e1);
        }
    }
    #pragma unroll
    for (int r = 0; r < 4; ++r) {
        #pragma unroll
        for (int m = 1; m < 16; m <<= 1) {
            ls0[r] += __shfl_xor(ls0[r], m, 64);
            ls1[r] += __shfl_xor(ls1[r], m, 64);
        }
        if (lm == 0) { linv[r0+quad*4+r] = 1.f/ls0[r]; linv[r1+quad*4+r] = 1.f/ls1[r]; }
    }
    __syncthreads();
    f32x4 acc0 = z, acc1 = z;
    #pragma unroll
    for (int c = 0; c < 4; ++c) {
        bf16x8 bV  = *(bf16x8*)&Vt[lm*136 + c*32 + quad*8];
        bf16x8 aP0 = *(bf16x8*)&Ps[(r0+lm)*136 + c*32 + quad*8];
        bf16x8 aP1 = *(bf16x8*)&Ps[(r1+lm)*136 + c*32 + quad*8];
        acc0 = __builtin_amdgcn_mfma_f32_16x16x32_bf16(aP0, bV, acc0, 0,0,0);
        acc1 = __builtin_amdgcn_mfma_f32_16x16x32_bf16(aP1, bV, acc1, 0,0,0);
    }
    size_t lpb = (size_t)bn*262144 + (size_t)h*2048;
    size_t oab = (size_t)b*1048576 + (size_t)h*8192 + n*16;
    bool evn = !(lm & 1);
    #pragma unroll
    for (int r = 0; r < 4; ++r) {
        int i0 = r0+quad*4+r, i1 = r1+quad*4+r;
        float o2a = acc0[r]*linv[i0];
        float o2b = acc1[r]*linv[i1];
        float o1a = bf2f(o1b[vbase + (size_t)i0*2048 + lm]);
        float o1c = bf2f(o1b[vbase + (size_t)i1*2048 + lm]);
        float la  = lepe[lpb + (size_t)i0*16 + lm];
        float lc  = lepe[lpb + (size_t)i1*16 + lm];
        unsigned ua = f2bf(0.5f*(o1a + o2a) + la);
        unsigned uc = f2bf(0.5f*(o1c + o2b) + lc);
        unsigned upa = (unsigned)__shfl_xor((int)ua,1,64);
        unsigned upc = (unsigned)__shfl_xor((int)uc,1,64);
        if (evn) {
            *(unsigned*)&attn[oab + (size_t)i0*64 + lm] = (ua & 0xffff) | (upa << 16);
            *(unsigned*)&attn[oab + (size_t)i1*64 + lm] = (uc & 0xffff) | (upc << 16);
        }
    }
}

// ---------------- Kernel 7: out-proj + residual + LN1 (MFMA) ----------------
__global__ __launch_bounds__(256) void k_proj_ln(
    const u16* __restrict__ attn, const float* __restrict__ x,
    const float* __restrict__ ow, const float* __restrict__ ob,
    const float* __restrict__ g1, const float* __restrict__ b1,
    u16* __restrict__ t1)
{
    __shared__ u16 As[128*72];
    __shared__ u16 Bs[64*72];
    __shared__ float XT[8704];
    int tid = threadIdx.x, bid = blockIdx.x;
    int pbase = bid*128;
    int b = pbase >> 14, p0 = pbase & 16383;
    for (int vi = tid; vi < 1024; vi += 256) {
        int p = vi >> 3, seg = (vi & 7)*8;
        *(uint4*)&As[p*72 + seg] = *(const uint4*)&attn[((size_t)(pbase+p))*64 + seg];
    }
    for (int vi = tid; vi < 512; vi += 256) {
        int kp = vi >> 4, c4 = (vi & 15)*4;
        float4 a = *(const float4*)&ow[(2*kp)*64 + c4];
        float4 c = *(const float4*)&ow[(2*kp+1)*64 + c4];
        *(unsigned*)&Bs[(c4+0)*72 + 2*kp] = pk2(a.x, c.x);
        *(unsigned*)&Bs[(c4+1)*72 + 2*kp] = pk2(a.y, c.y);
        *(unsigned*)&Bs[(c4+2)*72 + 2*kp] = pk2(a.z, c.z);
        *(unsigned*)&Bs[(c4+3)*72 + 2*kp] = pk2(a.w, c.w);
    }
    for (int vi = tid; vi < 2048; vi += 256) {
        int c = vi >> 5, p4 = (vi & 31)*4;
        *(float4*)&XT[c*132 + p4] = *(const float4*)&x[((size_t)(b*64+c))*HWSZ + p0 + p4];
    }
    __syncthreads();
    int lane = tid & 63, wv = tid >> 6;
    int quad = lane >> 4, lm = lane & 15;
    int M0 = wv*32;
    float xv[2][4][4], obv[4], g1v[4], b1v[4];
    #pragma unroll
    for (int nt = 0; nt < 4; ++nt) {
        int c = nt*16 + lm;
        obv[nt] = ob[c]; g1v[nt] = g1[c]; b1v[nt] = b1[c];
        #pragma unroll
        for (int mt = 0; mt < 2; ++mt)
            #pragma unroll
            for (int r = 0; r < 4; ++r)
                xv[mt][nt][r] = XT[c*132 + M0 + mt*16 + quad*4 + r];
    }
    f32x4 z = {0.f,0.f,0.f,0.f};
    f32x4 acc[2][4];
    #pragma unroll
    for (int mt = 0; mt < 2; ++mt)
        #pragma unroll
        for (int nt = 0; nt < 4; ++nt) acc[mt][nt] = z;
    #pragma unroll
    for (int ks = 0; ks < 2; ++ks) {
        bf16x8 aF[2];
        #pragma unroll
        for (int mt = 0; mt < 2; ++mt)
            aF[mt] = *(bf16x8*)&As[(M0+mt*16+lm)*72 + ks*32 + quad*8];
        #pragma unroll
        for (int nt = 0; nt < 4; ++nt) {
            bf16x8 bF = *(bf16x8*)&Bs[(nt*16+lm)*72 + ks*32 + quad*8];
            #pragma unroll
            for (int mt = 0; mt < 2; ++mt)
                acc[mt][nt] = __builtin_amdgcn_mfma_f32_16x16x32_bf16(aF[mt], bF, acc[mt][nt], 0,0,0);
        }
    }
    float val[2][4][4], res[2][4][4];
    #pragma unroll
    for (int mt = 0; mt < 2; ++mt) {
        #pragma unroll
        for (int r = 0; r < 4; ++r) {
            float s = 0.f;
            #pragma unroll
            for (int nt = 0; nt < 4; ++nt) {
                val[mt][nt][r] = acc[mt][nt][r] + obv[nt] + xv[mt][nt][r];
                s += val[mt][nt][r];
            }
            s += __shfl_xor(s, 1, 64); s += __shfl_xor(s, 2, 64);
            s += __shfl_xor(s, 4, 64); s += __shfl_xor(s, 8, 64);
            float mean = s*(1.f/64.f);
            float vv = 0.f;
            #pragma unroll
            for (int nt = 0; nt < 4; ++nt) {
                float d = val[mt][nt][r] - mean;
                vv += d*d;
            }
            vv += __shfl_xor(vv, 1, 64); vv += __shfl_xor(vv, 2, 64);
            vv += __shfl_xor(vv, 4, 64); vv += __shfl_xor(vv, 8, 64);
            float rs = rsqrtf(vv*(1.f/64.f) + 1e-5f);
            #pragma unroll
            for (int nt = 0; nt < 4; ++nt)
                res[mt][nt][r] = (val[mt][nt][r] - mean)*rs*g1v[nt] + b1v[nt];
        }
    }
    __syncthreads();
    float* outT = XT;   // [p][68]
    #pragma unroll
    for (int mt = 0; mt < 2; ++mt)
        #pragma unroll
        for (int r = 0; r < 4; ++r)
            #pragma unroll
            for (int nt = 0; nt < 4; ++nt)
                outT[(M0+mt*16+quad*4+r)*68 + nt*16 + lm] = res[mt][nt][r];
    __syncthreads();
    for (int vi = tid; vi < 1024; vi += 256) {
        int p = vi >> 3, seg = (vi & 7)*8;
        float4 f0 = *(const float4*)&outT[p*68 + seg];
        float4 f1 = *(const float4*)&outT[p*68 + seg + 4];
        uint4 o = make_uint4(pk2(f0.x,f0.y), pk2(f0.z,f0.w), pk2(f1.x,f1.y), pk2(f1.z,f1.w));
        *(uint4*)&t1[((size_t)(pbase+p))*64 + seg] = o;
    }
}

// ---------------- Kernel 8: fused FFN (MFMA) + residual + LN2 + transpose ----------------
__global__ __launch_bounds__(256) void k_ffn(
    const u16* __restrict__ t1, const float* __restrict__ w1,
    const float* __restrict__ b1f, const float* __restrict__ w2,
    const float* __restrict__ b2f, const float* __restrict__ g2,
    const float* __restrict__ bb2, float* __restrict__ outp)
{
    __shared__ u16 At1[128*72];
    __shared__ u16 WH[2*64*72 + 128*72];
    __shared__ float sb1[256];
    __shared__ float sb2[64], sg[64], sbb[64];
    u16* W1b = WH;
    u16* W2b = WH + 4608;
    u16* Hid = WH + 9216;
    int tid = threadIdx.x, bid = blockIdx.x;
    int pbase = bid*128;
    int b = pbase >> 14, p0 = pbase & 16383;
    for (int vi = tid; vi < 1024; vi += 256) {
        int p = vi >> 3, seg = (vi & 7)*8;
        *(uint4*)&At1[p*72 + seg] = *(const uint4*)&t1[((size_t)(pbase+p))*64 + seg];
    }
    if (tid < 256) sb1[tid] = b1f[tid];
    if (tid < 64) { sb2[tid] = b2f[tid]; sg[tid] = g2[tid]; sbb[tid] = bb2[tid]; }
    int lane = tid & 63, wv = tid >> 6;
    int quad = lane >> 4, lm = lane & 15;
    int M0 = wv*32;
    f32x4 z = {0.f,0.f,0.f,0.f};
    f32x4 acc2[2][4];
    #pragma unroll
    for (int mt = 0; mt < 2; ++mt)
        #pragma unroll
        for (int nt = 0; nt < 4; ++nt) acc2[mt][nt] = z;
    for (int jc = 0; jc < 4; ++jc) {
        __syncthreads();
        for (int vi = tid; vi < 512; vi += 256) {
            int kp = vi >> 4, c4 = (vi & 15)*4;
            float4 a = *(const float4*)&w1[(2*kp)*256 + jc*64 + c4];
            float4 c = *(const float4*)&w1[(2*kp+1)*256 + jc*64 + c4];
            *(unsigned*)&W1b[(c4+0)*72 + 2*kp] = pk2(a.x, c.x);
            *(unsigned*)&W1b[(c4+1)*72 + 2*kp] = pk2(a.y, c.y);
            *(unsigned*)&W1b[(c4+2)*72 + 2*kp] = pk2(a.z, c.z);
            *(unsigned*)&W1b[(c4+3)*72 + 2*kp] = pk2(a.w, c.w);
        }
        for (int vi = tid; vi < 512; vi += 256) {
            int kp = vi >> 4, c4 = (vi & 15)*4;
            float4 a = *(const float4*)&w2[(size_t)(jc*64 + 2*kp)*64 + c4];
            float4 c = *(const float4*)&w2[(size_t)(jc*64 + 2*kp+1)*64 + c4];
            *(unsigned*)&W2b[(c4+0)*72 + 2*kp] = pk2(a.x, c.x);
            *(unsigned*)&W2b[(c4+1)*72 + 2*kp] = pk2(a.y, c.y);
            *(unsigned*)&W2b[(c4+2)*72 + 2*kp] = pk2(a.z, c.z);
            *(unsigned*)&W2b[(c4+3)*72 + 2*kp] = pk2(a.w, c.w);
        }
        __syncthreads();
        f32x4 h[2][4];
        #pragma unroll
        for (int mt = 0; mt < 2; ++mt)
            #pragma unroll
            for (int nt = 0; nt < 4; ++nt) h[mt][nt] = z;
        #pragma unroll
        for (int ks = 0; ks < 2; ++ks) {
            bf16x8 aF[2];
            #pragma unroll
            for (int mt = 0; mt < 2; ++mt)
                aF[mt] = *(bf16x8*)&At1[(M0+mt*16+lm)*72 + ks*32 + quad*8];
            #pragma unroll
            for (int nt = 0; nt < 4; ++nt) {
                bf16x8 bF = *(bf16x8*)&W1b[(nt*16+lm)*72 + ks*32 + quad*8];
                #pragma unroll
                for (int mt = 0; mt < 2; ++mt)
                    h[mt][nt] = __builtin_amdgcn_mfma_f32_16x16x32_bf16(aF[mt], bF, h[mt][nt], 0,0,0);
            }
        }
        #pragma unroll
        for (int nt = 0; nt < 4; ++nt) {
            float bb = sb1[jc*64 + nt*16 + lm];
            #pragma unroll
            for (int mt = 0; mt < 2; ++mt)
                #pragma unroll
                for (int r = 0; r < 4; ++r) {
                    float hv = gelu_f(h[mt][nt][r] + bb);
                    unsigned u = (unsigned)f2bf(hv);
                    unsigned up = (unsigned)__shfl_xor((int)u, 1, 64);
                    if (!(lm & 1))
                        *(unsigned*)&Hid[(M0+mt*16+quad*4+r)*72 + nt*16 + lm] = (u & 0xffff) | (up << 16);
                }
        }
        #pragma unroll
        for (int ks = 0; ks < 2; ++ks) {
            bf16x8 aH[2];
            #pragma unroll
            for (int mt = 0; mt < 2; ++mt)
                aH[mt] = *(bf16x8*)&Hid[(M0+mt*16+lm)*72 + ks*32 + quad*8];
            #pragma unroll
            for (int nt = 0; nt < 4; ++nt) {
                bf16x8 bF = *(bf16x8*)&W2b[(nt*16+lm)*72 + ks*32 + quad*8];
                #pragma unroll
                for (int mt = 0; mt < 2; ++mt)
                    acc2[mt][nt] = __builtin_amdgcn_mfma_f32_16x16x32_bf16(aH[mt], bF, acc2[mt][nt], 0,0,0);
            }
        }
    }
    float val[2][4][4], res[2][4][4];
    float sb2v[4], sgv[4], sbbv[4];
    #pragma unroll
    for (int nt = 0; nt < 4; ++nt) {
        int c = nt*16 + lm;
        sb2v[nt] = sb2[c]; sgv[nt] = sg[c]; sbbv[nt] = sbb[c];
    }
    #pragma unroll
    for (int mt = 0; mt < 2; ++mt) {
        #pragma unroll
        for (int r = 0; r < 4; ++r) {
            int pos = M0 + mt*16 + quad*4 + r;
            float s = 0.f;
            #pragma unroll
            for (int nt = 0; nt < 4; ++nt) {
                float tv = bf2f(At1[pos*72 + nt*16 + lm]);
                val[mt][nt][r] = acc2[mt][nt][r] + sb2v[nt] + tv;
                s += val[mt][nt][r];
            }
            s += __shfl_xor(s, 1, 64); s += __shfl_xor(s, 2, 64);
            s += __shfl_xor(s, 4, 64); s += __shfl_xor(s, 8, 64);
            float mean = s*(1.f/64.f);
            float vv = 0.f;
            #pragma unroll
            for (int nt = 0; nt < 4; ++nt) {
                float d = val[mt][nt][r] - mean;
                vv += d*d;
            }
            vv += __shfl_xor(vv, 1, 64); vv += __shfl_xor(vv, 2, 64);
            vv += __shfl_xor(vv, 4, 64); vv += __shfl_xor(vv, 8, 64);
            float rs = rsqrtf(vv*(1.f/64.f) + 1e-5f);
            #pragma unroll
            for (int nt = 0; nt < 4; ++nt)
                res[mt][nt][r] = (val[mt][nt][r] - mean)*rs*sgv[nt] + sbbv[nt];
        }
    }
    __syncthreads();
    float* outT = (float*)WH;   // [c][132]
    #pragma unroll
    for (int mt = 0; mt < 2; ++mt)
        #pragma unroll
        for (int r = 0; r < 4; ++r)
            #pragma unroll
            for (int nt = 0; nt < 4; ++nt)
                outT[(nt*16+lm)*132 + M0 + mt*16 + quad*4 + r] = res[mt][nt][r];
    __syncthreads();
    for (int vi = tid; vi < 2048; vi += 256) {
        int c = vi >> 5, p4 = (vi & 31)*4;
        *(float4*)&outp[((size_t)(b*64+c))*HWSZ + p0 + p4] = *(const float4*)&outT[c*132 + p4];
    }
}

extern "C" void kernel_launch(void* const* d_in, const int* in_sizes, int n_in,
                              void* d_out, int out_size, void* d_ws, size_t ws_size,
                              hipStream_t stream) {
    const float* x      = (const float*)d_in[0];
    const float* y      = (const float*)d_in[1];
    const float* th     = (const float*)d_in[2];
    const float* dw1_w  = (const float*)d_in[3];
    const float* dw1_b  = (const float*)d_in[4];
    const float* dw2_w  = (const float*)d_in[5];
    const float* dw2_b  = (const float*)d_in[6];
    const float* qw     = (const float*)d_in[7];
    const float* qb     = (const float*)d_in[8];
    const float* kw     = (const float*)d_in[9];
    const float* kb     = (const float*)d_in[10];
    const float* vw     = (const float*)d_in[11];
    const float* vb     = (const float*)d_in[12];
    const float* lepe_w = (const float*)d_in[13];
    const float* lepe_b = (const float*)d_in[14];
    const float* dt_w   = (const float*)d_in[15];
    const float* dt_bias= (const float*)d_in[16];
    const float* A_log  = (const float*)d_in[17];
    const float* ow     = (const float*)d_in[18];
    const float* ob     = (const float*)d_in[19];
    const float* n1_g   = (const float*)d_in[20];
    const float* n1_b   = (const float*)d_in[21];
    const float* ffn_w1 = (const float*)d_in[22];
    const float* ffn_b1 = (const float*)d_in[23];
    const float* ffn_w2 = (const float*)d_in[24];
    const float* ffn_b2 = (const float*)d_in[25];
    const float* n2_g   = (const float*)d_in[26];
    const float* n2_b   = (const float*)d_in[27];
    float* out = (float*)d_out;

    const size_t SZ = 4194304;   // B*C*H*W elements (slab granularity: SZ floats)
    float* ws    = (float*)d_ws;
    u16* fused = (u16*)(ws + 0*SZ);    // reused as v_w (vwb) after attn_w1
    u16* qrb   = (u16*)(ws + 1*SZ);
    u16* krb   = (u16*)(ws + 2*SZ);
    u16* v5b   = (u16*)(ws + 3*SZ);
    float* lepeb = ws + 4*SZ;
    u16* vhb   = (u16*)(ws + 5*SZ);
    u16* o1b   = (u16*)(ws + 6*SZ);
    u16* attnb = (u16*)(ws + 7*SZ);
    u16* t1b   = (u16*)(ws + 8*SZ);
    float* dacs  = ws + 9*SZ;
    float* dbcs  = ws + 9*SZ + 262144;

    k_fuse<<<1024, 256, 0, stream>>>(y, th, dw1_w, dw1_b, dw2_w, dw2_b, fused);
    k_qkv<<<512, 256, 0, stream>>>(x, fused, qw, qb, kw, kb, vw, vb,
                                   dt_w, dt_bias, A_log, qrb, krb, v5b, dacs, dbcs);
    k_cumsum<<<1024, 256, 0, stream>>>(dacs, dbcs);
    k_lepe<<<512, 256, 0, stream>>>(v5b, lepe_w, lepe_b, lepeb);
    k_attn_w1<<<2048, 256, 0, stream>>>(qrb, krb, v5b, dacs, fused);
    k_attn_h<<<2048, 256, 0, stream>>>(qrb, krb, v5b, fused, dbcs, vhb, o1b);
    k_attn_w2<<<2048, 256, 0, stream>>>(qrb, krb, vhb, o1b, dacs, lepeb, attnb);
    k_proj_ln<<<512, 256, 0, stream>>>(attnb, x, ow, ob, n1_g, n1_b, t1b);
    k_ffn<<<512, 256, 0, stream>>>(t1b, ffn_w1, ffn_b1, ffn_w2, ffn_b2, n2_g, n2_b, out);
}